// Round 1
// baseline (2633.182 us; speedup 1.0000x reference)
//
#include <hip/hip_runtime.h>
#include <hip/hip_bf16.h>
#include <math.h>

// Problem constants
#define BATCH 4
#define TT 4096
#define HID 512
#define NH 8
#define HD 32
#define NROW (BATCH * TT)       // 16384
#define NCOL 1040               // q(256) k(256) v(256) w(256) beta(8) g(8)
#define QSCALE 0.17677669529663687f  // 32^-0.5

// ---------------------------------------------------------------------------
// Kernel 1: concat weights into stacked [1040][512]; fold q-scale into Wq rows
// ---------------------------------------------------------------------------
__global__ __launch_bounds__(256) void concat_w(
    const float* __restrict__ Wq, const float* __restrict__ Wk,
    const float* __restrict__ Wv, const float* __restrict__ Ww,
    const float* __restrict__ Wbeta, const float* __restrict__ Wg,
    float* __restrict__ dst)
{
    int o = blockIdx.x * 256 + threadIdx.x;   // < 1040*512
    if (o >= NCOL * HID) return;
    int r = o >> 9;                           // /512
    float v;
    if      (r < 256)  v = Wq[o] * QSCALE;
    else if (r < 512)  v = Wk[o - 256 * 512];
    else if (r < 768)  v = Wv[o - 512 * 512];
    else if (r < 1024) v = Ww[o - 768 * 512];
    else if (r < 1032) v = Wbeta[o - 1024 * 512];
    else               v = Wg[o - 1032 * 512];
    dst[o] = v;
}

// ---------------------------------------------------------------------------
// Kernel 2: generic fp32 GEMM  C[M][N] = A[M][K] * B[N][K]^T, 64x64 tile,
// 256 threads, 4x4 per-thread microtile. mode==1 applies projection epilogue:
//   cols [1024,1032): beta = 2*sigmoid(acc + bbeta)
//   cols [1032,1040): g    = logsigmoid(acc + bg)
// ---------------------------------------------------------------------------
__global__ __launch_bounds__(256) void gemm_nt(
    const float* __restrict__ A, const float* __restrict__ B,
    float* __restrict__ C, int M, int N, int K,
    int lda, int ldb, int ldc, int mode,
    const float* __restrict__ bias_beta, const float* __restrict__ bias_g)
{
    __shared__ float As[16][68];
    __shared__ float Bs[16][68];
    const int tid = threadIdx.x;
    const int tx = tid & 15, ty = tid >> 4;
    const int r0 = blockIdx.x * 64, c0 = blockIdx.y * 64;
    const int lr = tid >> 2;            // 0..63
    const int kg = (tid & 3) * 4;       // 0,4,8,12

    float acc[4][4] = {};

    for (int k0 = 0; k0 < K; k0 += 16) {
        float4 av4 = *(const float4*)&A[(size_t)(r0 + lr) * lda + k0 + kg];
        float4 bv4 = make_float4(0.f, 0.f, 0.f, 0.f);
        if (c0 + lr < N)
            bv4 = *(const float4*)&B[(size_t)(c0 + lr) * ldb + k0 + kg];
        __syncthreads();
        As[kg + 0][lr] = av4.x; As[kg + 1][lr] = av4.y;
        As[kg + 2][lr] = av4.z; As[kg + 3][lr] = av4.w;
        Bs[kg + 0][lr] = bv4.x; Bs[kg + 1][lr] = bv4.y;
        Bs[kg + 2][lr] = bv4.z; Bs[kg + 3][lr] = bv4.w;
        __syncthreads();
        #pragma unroll
        for (int kk = 0; kk < 16; ++kk) {
            float4 a = *(const float4*)&As[kk][ty * 4];
            float4 b = *(const float4*)&Bs[kk][tx * 4];
            float ar[4] = {a.x, a.y, a.z, a.w};
            float br[4] = {b.x, b.y, b.z, b.w};
            #pragma unroll
            for (int i = 0; i < 4; ++i)
                #pragma unroll
                for (int j = 0; j < 4; ++j)
                    acc[i][j] = fmaf(ar[i], br[j], acc[i][j]);
        }
    }

    #pragma unroll
    for (int i = 0; i < 4; ++i) {
        int row = r0 + ty * 4 + i;
        #pragma unroll
        for (int j = 0; j < 4; ++j) {
            int col = c0 + tx * 4 + j;
            if (col >= N) continue;
            float v = acc[i][j];
            if (mode == 1 && col >= 1024) {
                if (col < 1032) {
                    float z = v + bias_beta[col - 1024];
                    v = 2.0f / (1.0f + expf(-z));
                } else {
                    float z = v + bias_g[col - 1032];
                    v = fminf(z, 0.0f) - log1pf(expf(-fabsf(z)));
                }
            }
            C[(size_t)row * ldc + col] = v;
        }
    }
}

// ---------------------------------------------------------------------------
// Kernel 3: normalize w rows (cols 768..1023 of Y) per (row, h) group of 32
// ---------------------------------------------------------------------------
__global__ __launch_bounds__(256) void wnorm_kernel(float* __restrict__ Y)
{
    int gid = blockIdx.x * 8 + (threadIdx.x >> 5);  // over NROW*NH
    int m = threadIdx.x & 31;
    int row = gid >> 3, h = gid & 7;
    size_t idx = (size_t)row * NCOL + 768 + h * 32 + m;
    float v = Y[idx];
    float ss = v * v;
    ss += __shfl_xor(ss, 16, 64);
    ss += __shfl_xor(ss, 8, 64);
    ss += __shfl_xor(ss, 4, 64);
    ss += __shfl_xor(ss, 2, 64);
    ss += __shfl_xor(ss, 1, 64);
    float nrm = sqrtf(ss);
    Y[idx] = v / (nrm + 1e-6f);
}

// ---------------------------------------------------------------------------
// Kernel 4: sequential scan. One block (1024 threads) per (b,h).
// Thread (d,m) owns S[d][m] in a register. 64-step LDS staging tiles.
//   S <- S - beta*(S w) w^T + k v^T ;  res = (q^T S) * exp(g)   (q pre-scaled)
// ---------------------------------------------------------------------------
__global__ __launch_bounds__(1024) void scan_kernel(
    const float* __restrict__ Y, float* __restrict__ res)
{
    const int bh = blockIdx.x;          // 0..31
    const int b = bh >> 3, h = bh & 7;
    const int tid = threadIdx.x;
    const int d = tid >> 5, m = tid & 31;
    const int wave = tid >> 6;          // 0..15

    __shared__ float qs[64][32], ks[64][32], vs[64][32], wws[64][32];
    __shared__ float betas[64], gs[64];
    __shared__ float pb[2][16][32];

    float s = 0.0f;
    int buf = 0;
    const size_t rowbase = (size_t)b * TT;

    for (int t0 = 0; t0 < TT; t0 += 64) {
        __syncthreads();
        #pragma unroll
        for (int it = 0; it < 2; ++it) {
            int idx = tid + it * 1024;
            int r = idx >> 5, c = idx & 31;
            size_t base = (rowbase + t0 + r) * NCOL + h * 32;
            qs[r][c]  = Y[base + c];
            ks[r][c]  = Y[base + 256 + c];
            vs[r][c]  = Y[base + 512 + c];
            wws[r][c] = Y[base + 768 + c];
        }
        if (tid < 64) {
            size_t base = (rowbase + t0 + tid) * NCOL;
            betas[tid] = Y[base + 1024 + h];
            gs[tid]    = Y[base + 1032 + h];
        }
        __syncthreads();

        for (int tt = 0; tt < 64; ++tt) {
            float w_m  = wws[tt][m];
            float v_m  = vs[tt][m];
            float k_d  = ks[tt][d];
            float q_d  = qs[tt][d];
            float beta = betas[tt];

            // Sw[d] = sum_m S[d][m] * w[m]  (reduce over 32-lane half-wave)
            float prod = s * w_m;
            prod += __shfl_xor(prod, 16, 64);
            prod += __shfl_xor(prod, 8, 64);
            prod += __shfl_xor(prod, 4, 64);
            prod += __shfl_xor(prod, 2, 64);
            prod += __shfl_xor(prod, 1, 64);

            // S update
            s = fmaf(-beta * prod, w_m, fmaf(k_d, v_m, s));

            // res[m] = sum_d q[d]*S[d][m]
            float p = q_d * s;
            p += __shfl_xor(p, 32, 64);               // sum d-pair within wave
            if ((tid & 32) == 0) pb[buf][wave][m] = p;
            __syncthreads();
            if (tid < 32) {
                float sum = 0.0f;
                #pragma unroll
                for (int wv = 0; wv < 16; ++wv) sum += pb[buf][wv][tid];
                res[((rowbase + t0 + tt) * NH + h) * HD + tid] = sum * expf(gs[tt]);
            }
            buf ^= 1;
        }
    }
}

// ---------------------------------------------------------------------------
extern "C" void kernel_launch(void* const* d_in, const int* in_sizes, int n_in,
                              void* d_out, int out_size, void* d_ws, size_t ws_size,
                              hipStream_t stream)
{
    const float* x     = (const float*)d_in[0];
    const float* Wq    = (const float*)d_in[1];
    const float* Wk    = (const float*)d_in[2];
    const float* Wv    = (const float*)d_in[3];
    const float* Ww    = (const float*)d_in[4];
    const float* Wbeta = (const float*)d_in[5];
    const float* bbeta = (const float*)d_in[6];
    const float* Wg    = (const float*)d_in[7];
    const float* bg    = (const float*)d_in[8];
    const float* Wo    = (const float*)d_in[9];
    float* out = (float*)d_out;

    float* ws      = (float*)d_ws;
    float* stacked = ws;                               // 1040*512      = 532480
    float* Y       = stacked + NCOL * HID;             // 16384*1040    = 17039360
    float* res     = Y + (size_t)NROW * NCOL;          // 16384*256     = 4194304

    // 1. stack weights (fold q scale)
    concat_w<<<(NCOL * HID + 255) / 256, 256, 0, stream>>>(Wq, Wk, Wv, Ww, Wbeta, Wg, stacked);

    // 2. fused projection GEMM + beta/g epilogue
    gemm_nt<<<dim3(NROW / 64, (NCOL + 63) / 64), 256, 0, stream>>>(
        x, stacked, Y, NROW, NCOL, HID, HID, HID, NCOL, 1, bbeta, bg);

    // 3. normalize w
    wnorm_kernel<<<NROW * NH / 8, 256, 0, stream>>>(Y);

    // 4. sequential scan
    scan_kernel<<<BATCH * NH, 1024, 0, stream>>>(Y, res);

    // 5. output GEMM: out = res @ Wo^T
    gemm_nt<<<dim3(NROW / 64, HID / 64), 256, 0, stream>>>(
        res, Wo, out, NROW, HID, NH * HD, NH * HD, NH * HD, HID, 0, nullptr, nullptr);
}

// Round 2
// 1361.811 us; speedup vs baseline: 1.9336x; 1.9336x over previous
//
#include <hip/hip_runtime.h>
#include <hip/hip_bf16.h>
#include <math.h>

// Problem constants
#define BATCH 4
#define TT 4096
#define HID 512
#define NH 8
#define HD 32
#define NROW (BATCH * TT)       // 16384
#define NCOL 1040               // q(256) k(256) v(256) w(256) beta(8) g(8)
#define QSCALE 0.17677669529663687f  // 32^-0.5
#define NCHUNK 64               // chunks per (b,h); chunk length 64

// ---------------------------------------------------------------------------
// Kernel 1: concat weights into stacked [1040][512]; fold q-scale into Wq rows
// ---------------------------------------------------------------------------
__global__ __launch_bounds__(256) void concat_w(
    const float* __restrict__ Wq, const float* __restrict__ Wk,
    const float* __restrict__ Wv, const float* __restrict__ Ww,
    const float* __restrict__ Wbeta, const float* __restrict__ Wg,
    float* __restrict__ dst)
{
    int o = blockIdx.x * 256 + threadIdx.x;   // < 1040*512
    if (o >= NCOL * HID) return;
    int r = o >> 9;                           // /512
    float v;
    if      (r < 256)  v = Wq[o] * QSCALE;
    else if (r < 512)  v = Wk[o - 256 * 512];
    else if (r < 768)  v = Wv[o - 512 * 512];
    else if (r < 1024) v = Ww[o - 768 * 512];
    else if (r < 1032) v = Wbeta[o - 1024 * 512];
    else               v = Wg[o - 1032 * 512];
    dst[o] = v;
}

// ---------------------------------------------------------------------------
// Kernel 2: generic fp32 GEMM  C[M][N] = A[M][K] * B[N][K]^T, 64x64 tile,
// 256 threads, 4x4 per-thread microtile. mode==1 applies projection epilogue.
// ---------------------------------------------------------------------------
__global__ __launch_bounds__(256) void gemm_nt(
    const float* __restrict__ A, const float* __restrict__ B,
    float* __restrict__ C, int M, int N, int K,
    int lda, int ldb, int ldc, int mode,
    const float* __restrict__ bias_beta, const float* __restrict__ bias_g)
{
    __shared__ float As[16][68];
    __shared__ float Bs[16][68];
    const int tid = threadIdx.x;
    const int tx = tid & 15, ty = tid >> 4;
    const int r0 = blockIdx.x * 64, c0 = blockIdx.y * 64;
    const int lr = tid >> 2;            // 0..63
    const int kg = (tid & 3) * 4;       // 0,4,8,12

    float acc[4][4] = {};

    for (int k0 = 0; k0 < K; k0 += 16) {
        float4 av4 = *(const float4*)&A[(size_t)(r0 + lr) * lda + k0 + kg];
        float4 bv4 = make_float4(0.f, 0.f, 0.f, 0.f);
        if (c0 + lr < N)
            bv4 = *(const float4*)&B[(size_t)(c0 + lr) * ldb + k0 + kg];
        __syncthreads();
        As[kg + 0][lr] = av4.x; As[kg + 1][lr] = av4.y;
        As[kg + 2][lr] = av4.z; As[kg + 3][lr] = av4.w;
        Bs[kg + 0][lr] = bv4.x; Bs[kg + 1][lr] = bv4.y;
        Bs[kg + 2][lr] = bv4.z; Bs[kg + 3][lr] = bv4.w;
        __syncthreads();
        #pragma unroll
        for (int kk = 0; kk < 16; ++kk) {
            float4 a = *(const float4*)&As[kk][ty * 4];
            float4 b = *(const float4*)&Bs[kk][tx * 4];
            float ar[4] = {a.x, a.y, a.z, a.w};
            float br[4] = {b.x, b.y, b.z, b.w};
            #pragma unroll
            for (int i = 0; i < 4; ++i)
                #pragma unroll
                for (int j = 0; j < 4; ++j)
                    acc[i][j] = fmaf(ar[i], br[j], acc[i][j]);
        }
    }

    #pragma unroll
    for (int i = 0; i < 4; ++i) {
        int row = r0 + ty * 4 + i;
        #pragma unroll
        for (int j = 0; j < 4; ++j) {
            int col = c0 + tx * 4 + j;
            if (col >= N) continue;
            float v = acc[i][j];
            if (mode == 1 && col >= 1024) {
                if (col < 1032) {
                    float z = v + bias_beta[col - 1024];
                    v = 2.0f / (1.0f + expf(-z));
                } else {
                    float z = v + bias_g[col - 1032];
                    v = fminf(z, 0.0f) - log1pf(expf(-fabsf(z)));
                }
            }
            C[(size_t)row * ldc + col] = v;
        }
    }
}

// ---------------------------------------------------------------------------
// Kernel 3: normalize w rows (cols 768..1023 of Y)
// ---------------------------------------------------------------------------
__global__ __launch_bounds__(256) void wnorm_kernel(float* __restrict__ Y)
{
    int gid = blockIdx.x * 8 + (threadIdx.x >> 5);  // over NROW*NH
    int m = threadIdx.x & 31;
    int row = gid >> 3, h = gid & 7;
    size_t idx = (size_t)row * NCOL + 768 + h * 32 + m;
    float v = Y[idx];
    float ss = v * v;
    ss += __shfl_xor(ss, 16, 64);
    ss += __shfl_xor(ss, 8, 64);
    ss += __shfl_xor(ss, 4, 64);
    ss += __shfl_xor(ss, 2, 64);
    ss += __shfl_xor(ss, 1, 64);
    float nrm = sqrtf(ss);
    Y[idx] = v / (nrm + 1e-6f);
}

// ---------------------------------------------------------------------------
// Kernel A (chunk_pre): per-chunk WY precompute. One block per chunk.
//  Solves (I + tril(B W W^T,-1)) [U | Rt] = [B W | tril(B W V^T,-1) K]
//  Writes:
//   res  <- partial O = tril(QK^T)V - tril(Q Rt^T)W        [64x32] (raw)
//   Ubuf <- U                                              [64x32]
//   D0buf<- V^T K - W^T Rt                                 [32x32]
//   Pbuf <- I - W^T U  (chunk transition on m-index)       [32x32]
// ---------------------------------------------------------------------------
__global__ __launch_bounds__(256) void chunk_pre(
    const float* __restrict__ Y, float* __restrict__ res,
    float* __restrict__ Ubuf, float* __restrict__ D0buf,
    float* __restrict__ Pbuf)
{
    const int chunk = blockIdx.x;          // bh*64 + c
    const int bh = chunk >> 6, c = chunk & 63;
    const int b = bh >> 3, h = bh & 7;
    const int row0 = b * TT + c * 64;
    const int tid = threadIdx.x;

    __shared__ float Wc[64][33], Vc[64][33], Kc[64][33], Qc[64][33];
    __shared__ float G[64][65];   // beta_t * (w_t . w_j), later tril(Q Rt^T)
    __shared__ float P[64][65];   // beta_t * (w_t . v_j), later tril(Q K^T)
    __shared__ float X[64][65];   // solve result [U | Rt]
    __shared__ float betac[64];

    // load chunk tiles
    for (int idx = tid; idx < 2048; idx += 256) {
        int r = idx >> 5, cc = idx & 31;
        size_t base = ((size_t)row0 + r) * NCOL + h * 32;
        Qc[r][cc] = Y[base + cc];
        Kc[r][cc] = Y[base + 256 + cc];
        Vc[r][cc] = Y[base + 512 + cc];
        Wc[r][cc] = Y[base + 768 + cc];
    }
    if (tid < 64) betac[tid] = Y[((size_t)row0 + tid) * NCOL + 1024 + h];
    __syncthreads();

    // G = B W W^T,  P = B W V^T   (full; strict-lower used by construction)
    for (int idx = tid; idx < 4096; idx += 256) {
        int t = idx >> 6, j = idx & 63;
        float a = 0.f, b2 = 0.f;
        #pragma unroll
        for (int kk = 0; kk < 32; ++kk) {
            float wt = Wc[t][kk];
            a  = fmaf(wt, Wc[j][kk], a);
            b2 = fmaf(wt, Vc[j][kk], b2);
        }
        float bt = betac[t];
        G[t][j] = bt * a;
        P[t][j] = bt * b2;
    }
    __syncthreads();

    // RHS: X[:,0:32] = B W ; X[:,32:64] = tril(P,-1) K
    for (int idx = tid; idx < 2048; idx += 256) {
        int t = idx >> 5, dd = idx & 31;
        X[t][dd] = betac[t] * Wc[t][dd];
        float acc = 0.f;
        for (int i = 0; i < t; ++i)
            acc = fmaf(P[t][i], Kc[i][dd], acc);
        X[t][dd + 32] = acc;
    }

    // forward substitution (right-looking): (I + strict_lower(G)) X = RHS
    for (int t = 0; t < 63; ++t) {
        __syncthreads();
        int nelem = (63 - t) * 64;
        for (int idx = tid; idx < nelem; idx += 256) {
            int tp = t + 1 + (idx >> 6);
            int cc = idx & 63;
            X[tp][cc] = fmaf(-G[tp][t], X[t][cc], X[tp][cc]);
        }
    }
    __syncthreads();

    // write U
    for (int idx = tid; idx < 2048; idx += 256)
        Ubuf[(size_t)chunk * 2048 + idx] = X[idx >> 5][idx & 31];

    // P := tril(Q K^T) (incl diag), G := tril(Q Rt^T) (incl diag)
    for (int idx = tid; idx < 4096; idx += 256) {
        int t = idx >> 6, i = idx & 63;
        float a = 0.f, b2 = 0.f;
        if (i <= t) {
            #pragma unroll
            for (int kk = 0; kk < 32; ++kk) {
                float qt = Qc[t][kk];
                a  = fmaf(qt, Kc[i][kk], a);
                b2 = fmaf(qt, X[i][kk + 32], b2);
            }
        }
        P[t][i] = a;
        G[t][i] = b2;
    }
    __syncthreads();

    // partial O -> res (raw, no exp(g) yet)
    for (int idx = tid; idx < 2048; idx += 256) {
        int t = idx >> 5, m = idx & 31;
        float acc = 0.f;
        #pragma unroll 4
        for (int i = 0; i < 64; ++i)
            acc += P[t][i] * Vc[i][m] - G[t][i] * Wc[i][m];
        res[(((size_t)row0 + t) * NH + h) * HD + m] = acc;
    }
    // D0 = V^T K - W^T Rt   [m][d]
    for (int idx = tid; idx < 1024; idx += 256) {
        int m = idx >> 5, dd = idx & 31;
        float acc = 0.f;
        #pragma unroll 4
        for (int i = 0; i < 64; ++i)
            acc += Vc[i][m] * Kc[i][dd] - Wc[i][m] * X[i][dd + 32];
        D0buf[(size_t)chunk * 1024 + idx] = acc;
    }
    // Pmat = I - W^T U   [m][mp]
    for (int idx = tid; idx < 1024; idx += 256) {
        int m = idx >> 5, mp = idx & 31;
        float acc = (m == mp) ? 1.f : 0.f;
        #pragma unroll 4
        for (int j = 0; j < 64; ++j)
            acc -= Wc[j][m] * X[j][mp];
        Pbuf[(size_t)chunk * 1024 + idx] = acc;
    }
}

// ---------------------------------------------------------------------------
// Kernel B1 (scan_states): per (b,h), sequential scan over 64 chunks:
//   Z0buf[c] = Z (state BEFORE chunk c);  Z <- Pmat[c] Z + D0[c]
// ---------------------------------------------------------------------------
__global__ __launch_bounds__(256) void scan_states(
    const float* __restrict__ Pbuf, const float* __restrict__ D0buf,
    float* __restrict__ Z0buf)
{
    const int bh = blockIdx.x;
    const int tid = threadIdx.x;
    __shared__ float Zs[32][33];
    __shared__ float Pms[32][33];
    for (int idx = tid; idx < 1024; idx += 256)
        Zs[idx >> 5][idx & 31] = 0.f;

    for (int c = 0; c < NCHUNK; ++c) {
        size_t cb = ((size_t)bh * 64 + c) * 1024;
        __syncthreads();
        for (int idx = tid; idx < 1024; idx += 256)
            Pms[idx >> 5][idx & 31] = Pbuf[cb + idx];
        __syncthreads();
        float zn[4];
        #pragma unroll
        for (int k = 0; k < 4; ++k) {
            int idx = tid + k * 256;
            int m = idx >> 5, dd = idx & 31;
            float acc = D0buf[cb + idx];
            #pragma unroll 8
            for (int mp = 0; mp < 32; ++mp)
                acc = fmaf(Pms[m][mp], Zs[mp][dd], acc);
            zn[k] = acc;
            Z0buf[cb + idx] = Zs[m][dd];
        }
        __syncthreads();
        #pragma unroll
        for (int k = 0; k < 4; ++k) {
            int idx = tid + k * 256;
            Zs[idx >> 5][idx & 31] = zn[k];
        }
    }
}

// ---------------------------------------------------------------------------
// Kernel B2 (chunk_out): per chunk, add Z-dependent output terms:
//   O = (partial + Q Z0^T - tril(Q (U Z0)^T) W) * exp(g)
// ---------------------------------------------------------------------------
__global__ __launch_bounds__(256) void chunk_out(
    const float* __restrict__ Y, const float* __restrict__ Ubuf,
    const float* __restrict__ Z0buf, float* __restrict__ res)
{
    const int chunk = blockIdx.x;
    const int bh = chunk >> 6, c = chunk & 63;
    const int b = bh >> 3, h = bh & 7;
    const int row0 = b * TT + c * 64;
    const int tid = threadIdx.x;

    __shared__ float Uc[64][33], Qc[64][33], Wc[64][33], Pc[64][33];
    __shared__ float UZ[64][33];
    __shared__ float M2[64][65];
    __shared__ float Zs[32][33];
    __shared__ float gc[64];

    for (int idx = tid; idx < 2048; idx += 256) {
        int r = idx >> 5, cc = idx & 31;
        size_t base = ((size_t)row0 + r) * NCOL + h * 32;
        Qc[r][cc] = Y[base + cc];
        Wc[r][cc] = Y[base + 768 + cc];
        Uc[r][cc] = Ubuf[(size_t)chunk * 2048 + idx];
        Pc[r][cc] = res[(((size_t)row0 + r) * NH + h) * HD + cc];
    }
    for (int idx = tid; idx < 1024; idx += 256)
        Zs[idx >> 5][idx & 31] = Z0buf[(size_t)chunk * 1024 + idx];
    if (tid < 64) gc[tid] = Y[((size_t)row0 + tid) * NCOL + 1032 + h];
    __syncthreads();

    // UZ = U Z0  [j][d];  Pc += Q Z0^T (o_base)
    for (int idx = tid; idx < 2048; idx += 256) {
        int j = idx >> 5, dd = idx & 31;
        float acc = 0.f;
        #pragma unroll 8
        for (int m = 0; m < 32; ++m)
            acc = fmaf(Uc[j][m], Zs[m][dd], acc);
        UZ[j][dd] = acc;
    }
    for (int idx = tid; idx < 2048; idx += 256) {
        int t = idx >> 5, m = idx & 31;
        float acc = Pc[t][m];
        #pragma unroll 8
        for (int dd = 0; dd < 32; ++dd)
            acc = fmaf(Qc[t][dd], Zs[m][dd], acc);
        Pc[t][m] = acc;
    }
    __syncthreads();

    // M2 = tril(Q UZ^T) incl diag
    for (int idx = tid; idx < 4096; idx += 256) {
        int t = idx >> 6, j = idx & 63;
        float acc = 0.f;
        if (j <= t) {
            #pragma unroll 8
            for (int dd = 0; dd < 32; ++dd)
                acc = fmaf(Qc[t][dd], UZ[j][dd], acc);
        }
        M2[t][j] = acc;
    }
    __syncthreads();

    // final: res = (Pc - M2 W) * exp(g)
    for (int idx = tid; idx < 2048; idx += 256) {
        int t = idx >> 5, m = idx & 31;
        float acc = Pc[t][m];
        #pragma unroll 4
        for (int j = 0; j < 64; ++j)
            acc = fmaf(-M2[t][j], Wc[j][m], acc);
        res[(((size_t)row0 + t) * NH + h) * HD + m] = acc * expf(gc[t]);
    }
}

// ---------------------------------------------------------------------------
extern "C" void kernel_launch(void* const* d_in, const int* in_sizes, int n_in,
                              void* d_out, int out_size, void* d_ws, size_t ws_size,
                              hipStream_t stream)
{
    const float* x     = (const float*)d_in[0];
    const float* Wq    = (const float*)d_in[1];
    const float* Wk    = (const float*)d_in[2];
    const float* Wv    = (const float*)d_in[3];
    const float* Ww    = (const float*)d_in[4];
    const float* Wbeta = (const float*)d_in[5];
    const float* bbeta = (const float*)d_in[6];
    const float* Wg    = (const float*)d_in[7];
    const float* bg    = (const float*)d_in[8];
    const float* Wo    = (const float*)d_in[9];
    float* out = (float*)d_out;

    float* ws      = (float*)d_ws;
    float* stacked = ws;                               // 532,480
    float* Y       = stacked + NCOL * HID;             // 17,039,360
    float* res     = Y + (size_t)NROW * NCOL;          // 4,194,304
    float* Ubuf    = res + (size_t)NROW * 256;         // 4,194,304
    float* D0buf   = Ubuf + (size_t)2048 * 2048;       // 2,097,152
    float* Pbuf    = D0buf + (size_t)2048 * 1024;      // 2,097,152
    float* Z0buf   = Pbuf + (size_t)2048 * 1024;       // 2,097,152

    // 1. stack weights (fold q scale)
    concat_w<<<(NCOL * HID + 255) / 256, 256, 0, stream>>>(Wq, Wk, Wv, Ww, Wbeta, Wg, stacked);

    // 2. fused projection GEMM + beta/g epilogue
    gemm_nt<<<dim3(NROW / 64, (NCOL + 63) / 64), 256, 0, stream>>>(
        x, stacked, Y, NROW, NCOL, HID, HID, HID, NCOL, 1, bbeta, bg);

    // 3. normalize w
    wnorm_kernel<<<NROW * NH / 8, 256, 0, stream>>>(Y);

    // 4. chunked delta-rule: precompute (parallel over 2048 chunks)
    chunk_pre<<<2048, 256, 0, stream>>>(Y, res, Ubuf, D0buf, Pbuf);

    // 5. chunk-state scan (parallel over 32 bh, sequential over 64 chunks)
    scan_states<<<32, 256, 0, stream>>>(Pbuf, D0buf, Z0buf);

    // 6. Z-dependent output terms (parallel over 2048 chunks)
    chunk_out<<<2048, 256, 0, stream>>>(Y, Ubuf, Z0buf, res);

    // 7. output GEMM: out = res @ Wo^T
    gemm_nt<<<dim3(NROW / 64, HID / 64), 256, 0, stream>>>(
        res, Wo, out, NROW, HID, NH * HD, NH * HD, NH * HD, HID, 0, nullptr, nullptr);
}

// Round 3
// 931.321 us; speedup vs baseline: 2.8274x; 1.4622x over previous
//
#include <hip/hip_runtime.h>
#include <hip/hip_bf16.h>
#include <math.h>

// Problem constants
#define BATCH 4
#define TT 4096
#define HID 512
#define NH 8
#define HD 32
#define NROW (BATCH * TT)       // 16384
#define NCOL 1040               // q(256) k(256) v(256) w(256) beta(8) g(8)
#define QSCALE 0.17677669529663687f  // 32^-0.5
#define NCHUNK 64               // chunks per (b,h); chunk length 64

__device__ __forceinline__ float dot4(float4 a, float4 b) {
    return a.x * b.x + a.y * b.y + a.z * b.z + a.w * b.w;
}

// ---------------------------------------------------------------------------
// Kernel 1: concat weights into stacked [1040][512]; fold q-scale into Wq rows
// ---------------------------------------------------------------------------
__global__ __launch_bounds__(256) void concat_w(
    const float* __restrict__ Wq, const float* __restrict__ Wk,
    const float* __restrict__ Wv, const float* __restrict__ Ww,
    const float* __restrict__ Wbeta, const float* __restrict__ Wg,
    float* __restrict__ dst)
{
    int o = blockIdx.x * 256 + threadIdx.x;   // < 1040*512
    if (o >= NCOL * HID) return;
    int r = o >> 9;                           // /512
    float v;
    if      (r < 256)  v = Wq[o] * QSCALE;
    else if (r < 512)  v = Wk[o - 256 * 512];
    else if (r < 768)  v = Wv[o - 512 * 512];
    else if (r < 1024) v = Ww[o - 768 * 512];
    else if (r < 1032) v = Wbeta[o - 1024 * 512];
    else               v = Wg[o - 1032 * 512];
    dst[o] = v;
}

// ---------------------------------------------------------------------------
// Kernel 2: generic fp32 GEMM  C[M][N] = A[M][K] * B[N][K]^T, 64x64 tile,
// 256 threads, 4x4 per-thread microtile. mode==1 applies projection epilogue.
// ---------------------------------------------------------------------------
__global__ __launch_bounds__(256) void gemm_nt(
    const float* __restrict__ A, const float* __restrict__ B,
    float* __restrict__ C, int M, int N, int K,
    int lda, int ldb, int ldc, int mode,
    const float* __restrict__ bias_beta, const float* __restrict__ bias_g)
{
    __shared__ float As[16][68];
    __shared__ float Bs[16][68];
    const int tid = threadIdx.x;
    const int tx = tid & 15, ty = tid >> 4;
    const int r0 = blockIdx.x * 64, c0 = blockIdx.y * 64;
    const int lr = tid >> 2;            // 0..63
    const int kg = (tid & 3) * 4;       // 0,4,8,12

    float acc[4][4] = {};

    for (int k0 = 0; k0 < K; k0 += 16) {
        float4 av4 = *(const float4*)&A[(size_t)(r0 + lr) * lda + k0 + kg];
        float4 bv4 = make_float4(0.f, 0.f, 0.f, 0.f);
        if (c0 + lr < N)
            bv4 = *(const float4*)&B[(size_t)(c0 + lr) * ldb + k0 + kg];
        __syncthreads();
        As[kg + 0][lr] = av4.x; As[kg + 1][lr] = av4.y;
        As[kg + 2][lr] = av4.z; As[kg + 3][lr] = av4.w;
        Bs[kg + 0][lr] = bv4.x; Bs[kg + 1][lr] = bv4.y;
        Bs[kg + 2][lr] = bv4.z; Bs[kg + 3][lr] = bv4.w;
        __syncthreads();
        #pragma unroll
        for (int kk = 0; kk < 16; ++kk) {
            float4 a = *(const float4*)&As[kk][ty * 4];
            float4 b = *(const float4*)&Bs[kk][tx * 4];
            float ar[4] = {a.x, a.y, a.z, a.w};
            float br[4] = {b.x, b.y, b.z, b.w};
            #pragma unroll
            for (int i = 0; i < 4; ++i)
                #pragma unroll
                for (int j = 0; j < 4; ++j)
                    acc[i][j] = fmaf(ar[i], br[j], acc[i][j]);
        }
    }

    #pragma unroll
    for (int i = 0; i < 4; ++i) {
        int row = r0 + ty * 4 + i;
        #pragma unroll
        for (int j = 0; j < 4; ++j) {
            int col = c0 + tx * 4 + j;
            if (col >= N) continue;
            float v = acc[i][j];
            if (mode == 1 && col >= 1024) {
                if (col < 1032) {
                    float z = v + bias_beta[col - 1024];
                    v = 2.0f / (1.0f + expf(-z));
                } else {
                    float z = v + bias_g[col - 1032];
                    v = fminf(z, 0.0f) - log1pf(expf(-fabsf(z)));
                }
            }
            C[(size_t)row * ldc + col] = v;
        }
    }
}

// ---------------------------------------------------------------------------
// Kernel A (chunk_pre): per-chunk WY precompute. One block (512 thr) per chunk.
//  Normalizes w in-LDS. Solves (I + tril(BWW^T,-1))[U|Rt] = [BW | tril(BWV^T,-1)K]
//  Writes: res (partial O), Ubuf, D0buf = V^T K - W^T Rt, Pbuf = I - W^T U
// ---------------------------------------------------------------------------
__global__ __launch_bounds__(512) void chunk_pre(
    const float* __restrict__ Y, float* __restrict__ res,
    float* __restrict__ Ubuf, float* __restrict__ D0buf,
    float* __restrict__ Pbuf)
{
    const int chunk = blockIdx.x;          // bh*64 + c
    const int bh = chunk >> 6, c = chunk & 63;
    const int b = bh >> 3, h = bh & 7;
    const int row0 = b * TT + c * 64;
    const int tid = threadIdx.x;

    __shared__ __align__(16) float Qc[64][36], Kc[64][36], Vc[64][36], Wc[64][36];
    __shared__ __align__(16) float G[64][68], P[64][68], X[64][68];
    __shared__ float betac[64], wnrm[64];

    const int lr = tid >> 3;               // 0..63
    const int lc4 = (tid & 7) << 2;        // 0,4,...,28

    // ---- load (each thread one float4 per array) ----
    {
        size_t base = ((size_t)row0 + lr) * NCOL + h * 32 + lc4;
        *(float4*)&Qc[lr][lc4] = *(const float4*)&Y[base];
        *(float4*)&Kc[lr][lc4] = *(const float4*)&Y[base + 256];
        *(float4*)&Vc[lr][lc4] = *(const float4*)&Y[base + 512];
        *(float4*)&Wc[lr][lc4] = *(const float4*)&Y[base + 768];
    }
    if (tid < 64) betac[tid] = Y[((size_t)row0 + tid) * NCOL + 1024 + h];
    __syncthreads();

    // ---- normalize w rows in LDS ----
    if (tid < 64) {
        float ss = 0.f;
        #pragma unroll
        for (int i = 0; i < 32; ++i) ss = fmaf(Wc[tid][i], Wc[tid][i], ss);
        wnrm[tid] = 1.f / (sqrtf(ss) + 1e-6f);
    }
    __syncthreads();
    {
        float s = wnrm[lr];
        float4 w = *(const float4*)&Wc[lr][lc4];
        w.x *= s; w.y *= s; w.z *= s; w.w *= s;
        *(float4*)&Wc[lr][lc4] = w;
    }
    __syncthreads();

    // ---- Phase 2: G = B W W^T, P = B W V^T. 4x2 tiles (512 threads) ----
    {
        const int tr = tid >> 5;           // 0..15 -> t0 = 4*tr
        const int tc = tid & 31;           // 0..31 -> j0 = 2*tc
        const int t0 = tr * 4, j0 = tc * 2;
        float accG[4][2] = {}, accP[4][2] = {};
        #pragma unroll
        for (int k = 0; k < 32; k += 4) {
            float4 a[4];
            #pragma unroll
            for (int i = 0; i < 4; ++i) a[i] = *(const float4*)&Wc[t0 + i][k];
            #pragma unroll
            for (int j = 0; j < 2; ++j) {
                float4 bw = *(const float4*)&Wc[j0 + j][k];
                float4 bv = *(const float4*)&Vc[j0 + j][k];
                #pragma unroll
                for (int i = 0; i < 4; ++i) {
                    accG[i][j] += dot4(a[i], bw);
                    accP[i][j] += dot4(a[i], bv);
                }
            }
        }
        #pragma unroll
        for (int i = 0; i < 4; ++i) {
            float bt = betac[t0 + i];
            #pragma unroll
            for (int j = 0; j < 2; ++j) {
                G[t0 + i][j0 + j] = bt * accG[i][j];
                P[t0 + i][j0 + j] = bt * accP[i][j];
            }
        }
    }
    __syncthreads();

    // ---- Phase 3: RHS. X[:,0:32] = B W ; X[:,32:64] = tril(P,-1) K ----
    {
        float bt = betac[lr];
        float4 w = *(const float4*)&Wc[lr][lc4];
        w.x *= bt; w.y *= bt; w.z *= bt; w.w *= bt;
        *(float4*)&X[lr][lc4] = w;
        float4 acc = make_float4(0.f, 0.f, 0.f, 0.f);
        for (int i = 0; i < lr; ++i) {
            float p = P[lr][i];
            float4 kv = *(const float4*)&Kc[i][lc4];
            acc.x = fmaf(p, kv.x, acc.x);
            acc.y = fmaf(p, kv.y, acc.y);
            acc.z = fmaf(p, kv.z, acc.z);
            acc.w = fmaf(p, kv.w, acc.w);
        }
        *(float4*)&X[lr][32 + lc4] = acc;
    }

    // ---- Phase 4: forward substitution (I + strict_lower(G)) X = RHS ----
    for (int t = 0; t < 63; ++t) {
        __syncthreads();
        int n4 = (63 - t) * 16;
        for (int idx = tid; idx < n4; idx += 512) {
            int tp = t + 1 + (idx >> 4);
            int cc = (idx & 15) << 2;
            float g = G[tp][t];
            float4 xs = *(const float4*)&X[t][cc];
            float4 xd = *(const float4*)&X[tp][cc];
            xd.x = fmaf(-g, xs.x, xd.x);
            xd.y = fmaf(-g, xs.y, xd.y);
            xd.z = fmaf(-g, xs.z, xd.z);
            xd.w = fmaf(-g, xs.w, xd.w);
            *(float4*)&X[tp][cc] = xd;
        }
    }
    __syncthreads();

    // ---- Phase 5: P := tril(Q K^T), G := tril(Q Rt^T) (incl diag), 2x4 tile ----
    {
        const int tr = tid >> 4;           // 0..31 -> t0 = 2*tr
        const int tc = tid & 15;           // 0..15 -> j0 = 4*tc
        const int t0 = tr * 2, j0 = tc * 4;
        float accK[2][4] = {}, accR[2][4] = {};
        if (j0 <= t0 + 1) {
            #pragma unroll
            for (int k = 0; k < 32; k += 4) {
                float4 q0 = *(const float4*)&Qc[t0][k];
                float4 q1 = *(const float4*)&Qc[t0 + 1][k];
                #pragma unroll
                for (int j = 0; j < 4; ++j) {
                    float4 kk = *(const float4*)&Kc[j0 + j][k];
                    float4 rr = *(const float4*)&X[j0 + j][32 + k];
                    accK[0][j] += dot4(q0, kk);
                    accK[1][j] += dot4(q1, kk);
                    accR[0][j] += dot4(q0, rr);
                    accR[1][j] += dot4(q1, rr);
                }
            }
        }
        #pragma unroll
        for (int i = 0; i < 2; ++i)
            #pragma unroll
            for (int j = 0; j < 4; ++j) {
                int t = t0 + i, jj = j0 + j;
                bool keep = (jj <= t);
                P[t][jj] = keep ? accK[i][j] : 0.f;
                G[t][jj] = keep ? accR[i][j] : 0.f;
            }
    }
    __syncthreads();

    // ---- Phase 6: partial O -> res ; write U ----
    {
        float4 acc = make_float4(0.f, 0.f, 0.f, 0.f);
        #pragma unroll 4
        for (int i = 0; i < 64; ++i) {
            float p = P[lr][i], g = G[lr][i];
            float4 vv = *(const float4*)&Vc[i][lc4];
            float4 ww = *(const float4*)&Wc[i][lc4];
            acc.x += p * vv.x - g * ww.x;
            acc.y += p * vv.y - g * ww.y;
            acc.z += p * vv.z - g * ww.z;
            acc.w += p * vv.w - g * ww.w;
        }
        *(float4*)&res[(((size_t)row0 + lr) * NH + h) * HD + lc4] = acc;
        *(float4*)&Ubuf[(size_t)chunk * 2048 + lr * 32 + lc4] = *(const float4*)&X[lr][lc4];
    }

    // ---- Phase 7: D0 (threads 0-255) and Pmat (threads 256-511) ----
    if (tid < 256) {
        int m = tid >> 3, d4 = (tid & 7) << 2;
        float4 acc = make_float4(0.f, 0.f, 0.f, 0.f);
        #pragma unroll 4
        for (int i = 0; i < 64; ++i) {
            float vm = Vc[i][m], wm = Wc[i][m];
            float4 kk = *(const float4*)&Kc[i][d4];
            float4 rr = *(const float4*)&X[i][32 + d4];
            acc.x += vm * kk.x - wm * rr.x;
            acc.y += vm * kk.y - wm * rr.y;
            acc.z += vm * kk.z - wm * rr.z;
            acc.w += vm * kk.w - wm * rr.w;
        }
        *(float4*)&D0buf[(size_t)chunk * 1024 + m * 32 + d4] = acc;
    } else {
        int t2 = tid - 256;
        int m = t2 >> 3, p4 = (t2 & 7) << 2;
        float4 acc = make_float4(0.f, 0.f, 0.f, 0.f);
        #pragma unroll 4
        for (int j = 0; j < 64; ++j) {
            float wm = Wc[j][m];
            float4 uu = *(const float4*)&X[j][p4];
            acc.x = fmaf(-wm, uu.x, acc.x);
            acc.y = fmaf(-wm, uu.y, acc.y);
            acc.z = fmaf(-wm, uu.z, acc.z);
            acc.w = fmaf(-wm, uu.w, acc.w);
        }
        if (m >= p4 && m < p4 + 4) ((float*)&acc)[m - p4] += 1.f;
        *(float4*)&Pbuf[(size_t)chunk * 1024 + m * 32 + p4] = acc;
    }
}

// ---------------------------------------------------------------------------
// Kernel B1 (scan_states): per (b,h), sequential scan over 64 chunks:
//   Z0buf[c] = Z (state BEFORE chunk c);  Z <- Pmat[c] Z + D0[c]
// ---------------------------------------------------------------------------
__global__ __launch_bounds__(256) void scan_states(
    const float* __restrict__ Pbuf, const float* __restrict__ D0buf,
    float* __restrict__ Z0buf)
{
    const int bh = blockIdx.x;
    const int tid = threadIdx.x;
    __shared__ float Zs[32][33];
    __shared__ float Pms[32][33];
    for (int idx = tid; idx < 1024; idx += 256)
        Zs[idx >> 5][idx & 31] = 0.f;

    for (int c = 0; c < NCHUNK; ++c) {
        size_t cb = ((size_t)bh * 64 + c) * 1024;
        __syncthreads();
        for (int idx = tid; idx < 1024; idx += 256)
            Pms[idx >> 5][idx & 31] = Pbuf[cb + idx];
        __syncthreads();
        float zn[4];
        #pragma unroll
        for (int k = 0; k < 4; ++k) {
            int idx = tid + k * 256;
            int m = idx >> 5, dd = idx & 31;
            float acc = D0buf[cb + idx];
            #pragma unroll 8
            for (int mp = 0; mp < 32; ++mp)
                acc = fmaf(Pms[m][mp], Zs[mp][dd], acc);
            zn[k] = acc;
            Z0buf[cb + idx] = Zs[m][dd];
        }
        __syncthreads();
        #pragma unroll
        for (int k = 0; k < 4; ++k) {
            int idx = tid + k * 256;
            Zs[idx >> 5][idx & 31] = zn[k];
        }
    }
}

// ---------------------------------------------------------------------------
// Kernel B2 (chunk_out): per chunk (512 thr), add Z-dependent output terms:
//   O = (partial + Q Z0^T - tril(Q (U Z0)^T) W) * exp(g)
// ---------------------------------------------------------------------------
__global__ __launch_bounds__(512) void chunk_out(
    const float* __restrict__ Y, const float* __restrict__ Ubuf,
    const float* __restrict__ Z0buf, float* __restrict__ res)
{
    const int chunk = blockIdx.x;
    const int bh = chunk >> 6, c = chunk & 63;
    const int b = bh >> 3, h = bh & 7;
    const int row0 = b * TT + c * 64;
    const int tid = threadIdx.x;

    __shared__ __align__(16) float Qc[64][36], Wc[64][36], Uc[64][36], Pc[64][36];
    __shared__ __align__(16) float UZ[64][36], Zs[32][36];
    __shared__ __align__(16) float M2[64][68];
    __shared__ float gc[64], wnrm[64];

    const int lr = tid >> 3;
    const int lc4 = (tid & 7) << 2;

    {
        size_t base = ((size_t)row0 + lr) * NCOL + h * 32 + lc4;
        *(float4*)&Qc[lr][lc4] = *(const float4*)&Y[base];
        *(float4*)&Wc[lr][lc4] = *(const float4*)&Y[base + 768];
        *(float4*)&Uc[lr][lc4] = *(const float4*)&Ubuf[(size_t)chunk * 2048 + lr * 32 + lc4];
        *(float4*)&Pc[lr][lc4] = *(const float4*)&res[(((size_t)row0 + lr) * NH + h) * HD + lc4];
    }
    if (tid < 256) {
        int m = tid >> 3, d4 = (tid & 7) << 2;
        *(float4*)&Zs[m][d4] = *(const float4*)&Z0buf[(size_t)chunk * 1024 + m * 32 + d4];
    }
    if (tid < 64) gc[tid] = Y[((size_t)row0 + tid) * NCOL + 1032 + h];
    __syncthreads();

    // normalize w rows (Y holds unnormalized w)
    if (tid < 64) {
        float ss = 0.f;
        #pragma unroll
        for (int i = 0; i < 32; ++i) ss = fmaf(Wc[tid][i], Wc[tid][i], ss);
        wnrm[tid] = 1.f / (sqrtf(ss) + 1e-6f);
    }
    __syncthreads();
    {
        float s = wnrm[lr];
        float4 w = *(const float4*)&Wc[lr][lc4];
        w.x *= s; w.y *= s; w.z *= s; w.w *= s;
        *(float4*)&Wc[lr][lc4] = w;
    }
    __syncthreads();

    // UZ[j][d] = sum_m Uc[j][m] * Zs[m][d]
    {
        float4 acc = make_float4(0.f, 0.f, 0.f, 0.f);
        #pragma unroll 8
        for (int m = 0; m < 32; ++m) {
            float u = Uc[lr][m];
            float4 z = *(const float4*)&Zs[m][lc4];
            acc.x = fmaf(u, z.x, acc.x);
            acc.y = fmaf(u, z.y, acc.y);
            acc.z = fmaf(u, z.z, acc.z);
            acc.w = fmaf(u, z.w, acc.w);
        }
        *(float4*)&UZ[lr][lc4] = acc;
    }
    // Pc[t][m] += sum_d Qc[t][d] * Zs[m][d]   (m-quad per thread)
    {
        float4 acc = *(const float4*)&Pc[lr][lc4];
        float* accp = (float*)&acc;
        #pragma unroll
        for (int dq = 0; dq < 32; dq += 4) {
            float4 q = *(const float4*)&Qc[lr][dq];
            #pragma unroll
            for (int j = 0; j < 4; ++j) {
                float4 z = *(const float4*)&Zs[lc4 + j][dq];
                accp[j] += dot4(q, z);
            }
        }
        *(float4*)&Pc[lr][lc4] = acc;
    }
    __syncthreads();

    // M2 = tril(Q UZ^T) incl diag, 2x4 tiles
    {
        const int tr = tid >> 4, tc = tid & 15;
        const int t0 = tr * 2, j0 = tc * 4;
        float acc[2][4] = {};
        if (j0 <= t0 + 1) {
            #pragma unroll
            for (int k = 0; k < 32; k += 4) {
                float4 q0 = *(const float4*)&Qc[t0][k];
                float4 q1 = *(const float4*)&Qc[t0 + 1][k];
                #pragma unroll
                for (int j = 0; j < 4; ++j) {
                    float4 u = *(const float4*)&UZ[j0 + j][k];
                    acc[0][j] += dot4(q0, u);
                    acc[1][j] += dot4(q1, u);
                }
            }
        }
        #pragma unroll
        for (int i = 0; i < 2; ++i)
            #pragma unroll
            for (int j = 0; j < 4; ++j) {
                int t = t0 + i, jj = j0 + j;
                M2[t][jj] = (jj <= t) ? acc[i][j] : 0.f;
            }
    }
    __syncthreads();

    // final: res = (Pc - M2 W) * exp(g)
    {
        float4 acc = *(const float4*)&Pc[lr][lc4];
        #pragma unroll 4
        for (int j = 0; j < 64; ++j) {
            float mm = M2[lr][j];
            float4 w = *(const float4*)&Wc[j][lc4];
            acc.x = fmaf(-mm, w.x, acc.x);
            acc.y = fmaf(-mm, w.y, acc.y);
            acc.z = fmaf(-mm, w.z, acc.z);
            acc.w = fmaf(-mm, w.w, acc.w);
        }
        float e = expf(gc[lr]);
        acc.x *= e; acc.y *= e; acc.z *= e; acc.w *= e;
        *(float4*)&res[(((size_t)row0 + lr) * NH + h) * HD + lc4] = acc;
    }
}

// ---------------------------------------------------------------------------
extern "C" void kernel_launch(void* const* d_in, const int* in_sizes, int n_in,
                              void* d_out, int out_size, void* d_ws, size_t ws_size,
                              hipStream_t stream)
{
    const float* x     = (const float*)d_in[0];
    const float* Wq    = (const float*)d_in[1];
    const float* Wk    = (const float*)d_in[2];
    const float* Wv    = (const float*)d_in[3];
    const float* Ww    = (const float*)d_in[4];
    const float* Wbeta = (const float*)d_in[5];
    const float* bbeta = (const float*)d_in[6];
    const float* Wg    = (const float*)d_in[7];
    const float* bg    = (const float*)d_in[8];
    const float* Wo    = (const float*)d_in[9];
    float* out = (float*)d_out;

    float* ws      = (float*)d_ws;
    float* stacked = ws;                               // 532,480
    float* Y       = stacked + NCOL * HID;             // 17,039,360
    float* res     = Y + (size_t)NROW * NCOL;          // 4,194,304
    float* Ubuf    = res + (size_t)NROW * 256;         // 4,194,304
    float* D0buf   = Ubuf + (size_t)2048 * 2048;       // 2,097,152
    float* Pbuf    = D0buf + (size_t)2048 * 1024;      // 2,097,152
    float* Z0buf   = Pbuf + (size_t)2048 * 1024;       // 2,097,152

    // 1. stack weights (fold q scale)
    concat_w<<<(NCOL * HID + 255) / 256, 256, 0, stream>>>(Wq, Wk, Wv, Ww, Wbeta, Wg, stacked);

    // 2. fused projection GEMM + beta/g epilogue
    gemm_nt<<<dim3(NROW / 64, (NCOL + 63) / 64), 256, 0, stream>>>(
        x, stacked, Y, NROW, NCOL, HID, HID, HID, NCOL, 1, bbeta, bg);

    // 3. chunked delta-rule: precompute (parallel over 2048 chunks)
    chunk_pre<<<2048, 512, 0, stream>>>(Y, res, Ubuf, D0buf, Pbuf);

    // 4. chunk-state scan (parallel over 32 bh, sequential over 64 chunks)
    scan_states<<<32, 256, 0, stream>>>(Pbuf, D0buf, Z0buf);

    // 5. Z-dependent output terms (parallel over 2048 chunks)
    chunk_out<<<2048, 512, 0, stream>>>(Y, Ubuf, Z0buf, res);

    // 6. output GEMM: out = res @ Wo^T
    gemm_nt<<<dim3(NROW / 64, HID / 64), 256, 0, stream>>>(
        res, Wo, out, NROW, HID, NH * HD, NH * HD, NH * HD, HID, 0, nullptr, nullptr);
}

// Round 4
// 886.007 us; speedup vs baseline: 2.9720x; 1.0511x over previous
//
#include <hip/hip_runtime.h>
#include <hip/hip_bf16.h>
#include <math.h>

// Problem constants
#define BATCH 4
#define TT 4096
#define HID 512
#define NH 8
#define HD 32
#define NROW (BATCH * TT)       // 16384
#define NCOL 1040               // q(256) k(256) v(256) w(256) beta(8) g(8)
#define NPAD 1152               // padded col count for 128-wide MFMA tiles
#define QSCALE 0.17677669529663687f  // 32^-0.5
#define NCHUNK 64               // chunks per (b,h); chunk length 64

using s16x8 = __attribute__((ext_vector_type(8))) short;
using f32x4 = __attribute__((ext_vector_type(4))) float;

__device__ __forceinline__ float dot4(float4 a, float4 b) {
    return a.x * b.x + a.y * b.y + a.z * b.z + a.w * b.w;
}
__device__ __forceinline__ unsigned short f2bf(float v) {
    __hip_bfloat16 h = __float2bfloat16(v);
    unsigned short u;
    __builtin_memcpy(&u, &h, 2);
    return u;
}

// ---------------------------------------------------------------------------
// cast fp32 -> bf16, 4 elements per thread
// ---------------------------------------------------------------------------
__global__ __launch_bounds__(256) void cast_bf16(
    const float* __restrict__ src, unsigned short* __restrict__ dst, int n4)
{
    int i = blockIdx.x * 256 + threadIdx.x;
    if (i >= n4) return;
    float4 v = ((const float4*)src)[i];
    ushort4 o;
    o.x = f2bf(v.x); o.y = f2bf(v.y); o.z = f2bf(v.z); o.w = f2bf(v.w);
    ((ushort4*)dst)[i] = o;
}

// ---------------------------------------------------------------------------
// concat weights into stacked bf16 [1152][512]; fold q-scale; zero pad rows
// ---------------------------------------------------------------------------
__global__ __launch_bounds__(256) void concat_w_bf(
    const float* __restrict__ Wq, const float* __restrict__ Wk,
    const float* __restrict__ Wv, const float* __restrict__ Ww,
    const float* __restrict__ Wbeta, const float* __restrict__ Wg,
    unsigned short* __restrict__ dst)
{
    int o = blockIdx.x * 256 + threadIdx.x;   // < 1152*512
    if (o >= NPAD * HID) return;
    int r = o >> 9;                           // /512
    float v;
    if      (r < 256)  v = Wq[o] * QSCALE;
    else if (r < 512)  v = Wk[o - 256 * 512];
    else if (r < 768)  v = Wv[o - 512 * 512];
    else if (r < 1024) v = Ww[o - 768 * 512];
    else if (r < 1032) v = Wbeta[o - 1024 * 512];
    else if (r < 1040) v = Wg[o - 1032 * 512];
    else               v = 0.0f;
    dst[o] = f2bf(v);
}

// ---------------------------------------------------------------------------
// bf16 MFMA GEMM: C[M][ldc] (fp32) = A[M][K] * B[Npad][K]^T
// 128x128 block tile, BK=32, 256 threads (4 waves, each 64x64 = 4x4 frags of
// 16x16x32). mode==1: beta/g epilogue on cols >= 1024; store only col < N.
// ---------------------------------------------------------------------------
__global__ __launch_bounds__(256) void gemm_mfma(
    const unsigned short* __restrict__ A, const unsigned short* __restrict__ B,
    float* __restrict__ C, int M, int N, int K, int ldc, int mode,
    const float* __restrict__ bias_beta, const float* __restrict__ bias_g)
{
    __shared__ __align__(16) unsigned short As[128 * 32];
    __shared__ __align__(16) unsigned short Bs[128 * 32];
    const int tid = threadIdx.x;
    const int wave = tid >> 6, lane = tid & 63;
    const int quad = lane >> 4, l16 = lane & 15;
    const int wm = wave & 1, wn = wave >> 1;
    const int r0 = blockIdx.x * 128;
    const int c0 = blockIdx.y * 128;

    f32x4 acc[4][4] = {};

    for (int k0 = 0; k0 < K; k0 += 32) {
        s16x8 ra[2], rb[2];
        #pragma unroll
        for (int i = 0; i < 2; ++i) {
            int slot = wave * 128 + i * 64 + lane;
            int row = slot >> 2, kq = slot & 3;
            ra[i] = *(const s16x8*)&A[(size_t)(r0 + row) * K + k0 + kq * 8];
            rb[i] = *(const s16x8*)&B[(size_t)(c0 + row) * K + k0 + kq * 8];
        }
        __syncthreads();
        #pragma unroll
        for (int i = 0; i < 2; ++i) {
            int slot = wave * 128 + i * 64 + lane;
            *(s16x8*)&As[slot * 8] = ra[i];
            *(s16x8*)&Bs[slot * 8] = rb[i];
        }
        __syncthreads();
        s16x8 af[4], bf[4];
        #pragma unroll
        for (int mi = 0; mi < 4; ++mi)
            af[mi] = *(const s16x8*)&As[(wm * 64 + mi * 16 + l16) * 32 + quad * 8];
        #pragma unroll
        for (int ni = 0; ni < 4; ++ni)
            bf[ni] = *(const s16x8*)&Bs[(wn * 64 + ni * 16 + l16) * 32 + quad * 8];
        #pragma unroll
        for (int mi = 0; mi < 4; ++mi)
            #pragma unroll
            for (int ni = 0; ni < 4; ++ni)
                acc[mi][ni] = __builtin_amdgcn_mfma_f32_16x16x32_bf16(
                    af[mi], bf[ni], acc[mi][ni], 0, 0, 0);
    }

    #pragma unroll
    for (int mi = 0; mi < 4; ++mi) {
        #pragma unroll
        for (int ni = 0; ni < 4; ++ni) {
            int col = c0 + wn * 64 + ni * 16 + l16;
            if (col >= N) continue;
            #pragma unroll
            for (int r = 0; r < 4; ++r) {
                int row = r0 + wm * 64 + mi * 16 + quad * 4 + r;
                float v = acc[mi][ni][r];
                if (mode == 1 && col >= 1024) {
                    if (col < 1032) {
                        float z = v + bias_beta[col - 1024];
                        v = 2.0f / (1.0f + expf(-z));
                    } else {
                        float z = v + bias_g[col - 1032];
                        v = fminf(z, 0.0f) - log1pf(expf(-fabsf(z)));
                    }
                }
                C[(size_t)row * ldc + col] = v;
            }
        }
    }
}

// ---------------------------------------------------------------------------
// Kernel A (chunk_pre): per-chunk WY precompute. One block (512 thr) per chunk.
// ---------------------------------------------------------------------------
__global__ __launch_bounds__(512) void chunk_pre(
    const float* __restrict__ Y, float* __restrict__ res,
    float* __restrict__ Ubuf, float* __restrict__ D0buf,
    float* __restrict__ Pbuf)
{
    const int chunk = blockIdx.x;          // bh*64 + c
    const int bh = chunk >> 6, c = chunk & 63;
    const int b = bh >> 3, h = bh & 7;
    const int row0 = b * TT + c * 64;
    const int tid = threadIdx.x;

    __shared__ __align__(16) float Qc[64][36], Kc[64][36], Vc[64][36], Wc[64][36];
    __shared__ __align__(16) float G[64][68], P[64][68], X[64][68];
    __shared__ float betac[64], wnrm[64];

    const int lr = tid >> 3;               // 0..63
    const int lc4 = (tid & 7) << 2;        // 0,4,...,28

    {
        size_t base = ((size_t)row0 + lr) * NCOL + h * 32 + lc4;
        *(float4*)&Qc[lr][lc4] = *(const float4*)&Y[base];
        *(float4*)&Kc[lr][lc4] = *(const float4*)&Y[base + 256];
        *(float4*)&Vc[lr][lc4] = *(const float4*)&Y[base + 512];
        *(float4*)&Wc[lr][lc4] = *(const float4*)&Y[base + 768];
    }
    if (tid < 64) betac[tid] = Y[((size_t)row0 + tid) * NCOL + 1024 + h];
    __syncthreads();

    if (tid < 64) {
        float ss = 0.f;
        #pragma unroll
        for (int i = 0; i < 32; ++i) ss = fmaf(Wc[tid][i], Wc[tid][i], ss);
        wnrm[tid] = 1.f / (sqrtf(ss) + 1e-6f);
    }
    __syncthreads();
    {
        float s = wnrm[lr];
        float4 w = *(const float4*)&Wc[lr][lc4];
        w.x *= s; w.y *= s; w.z *= s; w.w *= s;
        *(float4*)&Wc[lr][lc4] = w;
    }
    __syncthreads();

    // ---- Phase 2: G = B W W^T, P = B W V^T. lanes walk consecutive rows ----
    {
        const int tr = tid >> 5;           // 0..15 -> t0 = 4*tr
        const int tc = tid & 31;           // j = tc, tc+32
        const int t0 = tr * 4;
        float accG[4][2] = {}, accP[4][2] = {};
        #pragma unroll
        for (int k = 0; k < 32; k += 4) {
            float4 a[4];
            #pragma unroll
            for (int i = 0; i < 4; ++i) a[i] = *(const float4*)&Wc[t0 + i][k];
            #pragma unroll
            for (int j = 0; j < 2; ++j) {
                int jj = tc + j * 32;
                float4 bw = *(const float4*)&Wc[jj][k];
                float4 bv = *(const float4*)&Vc[jj][k];
                #pragma unroll
                for (int i = 0; i < 4; ++i) {
                    accG[i][j] += dot4(a[i], bw);
                    accP[i][j] += dot4(a[i], bv);
                }
            }
        }
        #pragma unroll
        for (int i = 0; i < 4; ++i) {
            float bt = betac[t0 + i];
            #pragma unroll
            for (int j = 0; j < 2; ++j) {
                G[t0 + i][tc + j * 32] = bt * accG[i][j];
                P[t0 + i][tc + j * 32] = bt * accP[i][j];
            }
        }
    }
    __syncthreads();

    // ---- Phase 3: RHS. X[:,0:32] = B W ; X[:,32:64] = tril(P,-1) K ----
    {
        float bt = betac[lr];
        float4 w = *(const float4*)&Wc[lr][lc4];
        w.x *= bt; w.y *= bt; w.z *= bt; w.w *= bt;
        *(float4*)&X[lr][lc4] = w;
        float4 acc = make_float4(0.f, 0.f, 0.f, 0.f);
        for (int i = 0; i < lr; ++i) {
            float p = P[lr][i];
            float4 kv = *(const float4*)&Kc[i][lc4];
            acc.x = fmaf(p, kv.x, acc.x);
            acc.y = fmaf(p, kv.y, acc.y);
            acc.z = fmaf(p, kv.z, acc.z);
            acc.w = fmaf(p, kv.w, acc.w);
        }
        *(float4*)&X[lr][32 + lc4] = acc;
    }

    // ---- Phase 4: forward substitution (I + strict_lower(G)) X = RHS ----
    for (int t = 0; t < 63; ++t) {
        __syncthreads();
        int n4 = (63 - t) * 16;
        for (int idx = tid; idx < n4; idx += 512) {
            int tp = t + 1 + (idx >> 4);
            int cc = (idx & 15) << 2;
            float g = G[tp][t];
            float4 xs = *(const float4*)&X[t][cc];
            float4 xd = *(const float4*)&X[tp][cc];
            xd.x = fmaf(-g, xs.x, xd.x);
            xd.y = fmaf(-g, xs.y, xd.y);
            xd.z = fmaf(-g, xs.z, xd.z);
            xd.w = fmaf(-g, xs.w, xd.w);
            *(float4*)&X[tp][cc] = xd;
        }
    }
    __syncthreads();

    // ---- Phase 5: P := tril(Q K^T), G := tril(Q Rt^T); lanes walk rows ----
    {
        const int tr = tid >> 4;           // 0..31 -> t0 = 2*tr
        const int tc = tid & 15;           // j in {tc, tc+16, tc+32, tc+48}
        const int t0 = tr * 2;
        float accK[2][4] = {}, accR[2][4] = {};
        #pragma unroll
        for (int k = 0; k < 32; k += 4) {
            float4 q0 = *(const float4*)&Qc[t0][k];
            float4 q1 = *(const float4*)&Qc[t0 + 1][k];
            #pragma unroll
            for (int j = 0; j < 4; ++j) {
                int jj = tc + j * 16;
                float4 kk = *(const float4*)&Kc[jj][k];
                float4 rr = *(const float4*)&X[jj][32 + k];
                accK[0][j] += dot4(q0, kk);
                accK[1][j] += dot4(q1, kk);
                accR[0][j] += dot4(q0, rr);
                accR[1][j] += dot4(q1, rr);
            }
        }
        #pragma unroll
        for (int i = 0; i < 2; ++i)
            #pragma unroll
            for (int j = 0; j < 4; ++j) {
                int t = t0 + i, jj = tc + j * 16;
                bool keep = (jj <= t);
                P[t][jj] = keep ? accK[i][j] : 0.f;
                G[t][jj] = keep ? accR[i][j] : 0.f;
            }
    }
    __syncthreads();

    // ---- Phase 6: partial O -> res ; write U ----
    {
        float4 acc = make_float4(0.f, 0.f, 0.f, 0.f);
        #pragma unroll 4
        for (int i = 0; i < 64; ++i) {
            float p = P[lr][i], g = G[lr][i];
            float4 vv = *(const float4*)&Vc[i][lc4];
            float4 ww = *(const float4*)&Wc[i][lc4];
            acc.x += p * vv.x - g * ww.x;
            acc.y += p * vv.y - g * ww.y;
            acc.z += p * vv.z - g * ww.z;
            acc.w += p * vv.w - g * ww.w;
        }
        *(float4*)&res[(((size_t)row0 + lr) * NH + h) * HD + lc4] = acc;
        *(float4*)&Ubuf[(size_t)chunk * 2048 + lr * 32 + lc4] = *(const float4*)&X[lr][lc4];
    }

    // ---- Phase 7: D0 (threads 0-255) and Pmat (threads 256-511) ----
    if (tid < 256) {
        int m = tid >> 3, d4 = (tid & 7) << 2;
        float4 acc = make_float4(0.f, 0.f, 0.f, 0.f);
        #pragma unroll 4
        for (int i = 0; i < 64; ++i) {
            float vm = Vc[i][m], wm = Wc[i][m];
            float4 kk = *(const float4*)&Kc[i][d4];
            float4 rr = *(const float4*)&X[i][32 + d4];
            acc.x += vm * kk.x - wm * rr.x;
            acc.y += vm * kk.y - wm * rr.y;
            acc.z += vm * kk.z - wm * rr.z;
            acc.w += vm * kk.w - wm * rr.w;
        }
        *(float4*)&D0buf[(size_t)chunk * 1024 + m * 32 + d4] = acc;
    } else {
        int t2 = tid - 256;
        int m = t2 >> 3, p4 = (t2 & 7) << 2;
        float4 acc = make_float4(0.f, 0.f, 0.f, 0.f);
        #pragma unroll 4
        for (int j = 0; j < 64; ++j) {
            float wm = Wc[j][m];
            float4 uu = *(const float4*)&X[j][p4];
            acc.x = fmaf(-wm, uu.x, acc.x);
            acc.y = fmaf(-wm, uu.y, acc.y);
            acc.z = fmaf(-wm, uu.z, acc.z);
            acc.w = fmaf(-wm, uu.w, acc.w);
        }
        if (m >= p4 && m < p4 + 4) ((float*)&acc)[m - p4] += 1.f;
        *(float4*)&Pbuf[(size_t)chunk * 1024 + m * 32 + p4] = acc;
    }
}

// ---------------------------------------------------------------------------
// Kernel B1 (scan_states): per (b,h), sequential scan over 64 chunks
// ---------------------------------------------------------------------------
__global__ __launch_bounds__(256) void scan_states(
    const float* __restrict__ Pbuf, const float* __restrict__ D0buf,
    float* __restrict__ Z0buf)
{
    const int bh = blockIdx.x;
    const int tid = threadIdx.x;
    __shared__ float Zs[32][33];
    __shared__ float Pms[32][33];
    for (int idx = tid; idx < 1024; idx += 256)
        Zs[idx >> 5][idx & 31] = 0.f;

    for (int c = 0; c < NCHUNK; ++c) {
        size_t cb = ((size_t)bh * 64 + c) * 1024;
        __syncthreads();
        for (int idx = tid; idx < 1024; idx += 256)
            Pms[idx >> 5][idx & 31] = Pbuf[cb + idx];
        __syncthreads();
        float zn[4];
        #pragma unroll
        for (int k = 0; k < 4; ++k) {
            int idx = tid + k * 256;
            int m = idx >> 5, dd = idx & 31;
            float acc = D0buf[cb + idx];
            #pragma unroll 8
            for (int mp = 0; mp < 32; ++mp)
                acc = fmaf(Pms[m][mp], Zs[mp][dd], acc);
            zn[k] = acc;
            Z0buf[cb + idx] = Zs[m][dd];
        }
        __syncthreads();
        #pragma unroll
        for (int k = 0; k < 4; ++k) {
            int idx = tid + k * 256;
            Zs[idx >> 5][idx & 31] = zn[k];
        }
    }
}

// ---------------------------------------------------------------------------
// Kernel B2 (chunk_out): per chunk (512 thr), Z-dependent output; bf16 out
// ---------------------------------------------------------------------------
__global__ __launch_bounds__(512) void chunk_out(
    const float* __restrict__ Y, const float* __restrict__ Ubuf,
    const float* __restrict__ Z0buf, const float* __restrict__ res,
    unsigned short* __restrict__ res_bf)
{
    const int chunk = blockIdx.x;
    const int bh = chunk >> 6, c = chunk & 63;
    const int b = bh >> 3, h = bh & 7;
    const int row0 = b * TT + c * 64;
    const int tid = threadIdx.x;

    __shared__ __align__(16) float Qc[64][36], Wc[64][36], Uc[64][36], Pc[64][36];
    __shared__ __align__(16) float UZ[64][36], Zs[32][36];
    __shared__ __align__(16) float M2[64][68];
    __shared__ float gc[64], wnrm[64];

    const int lr = tid >> 3;
    const int lc4 = (tid & 7) << 2;

    {
        size_t base = ((size_t)row0 + lr) * NCOL + h * 32 + lc4;
        *(float4*)&Qc[lr][lc4] = *(const float4*)&Y[base];
        *(float4*)&Wc[lr][lc4] = *(const float4*)&Y[base + 768];
        *(float4*)&Uc[lr][lc4] = *(const float4*)&Ubuf[(size_t)chunk * 2048 + lr * 32 + lc4];
        *(float4*)&Pc[lr][lc4] = *(const float4*)&res[(((size_t)row0 + lr) * NH + h) * HD + lc4];
    }
    if (tid < 256) {
        int m = tid >> 3, d4 = (tid & 7) << 2;
        *(float4*)&Zs[m][d4] = *(const float4*)&Z0buf[(size_t)chunk * 1024 + m * 32 + d4];
    }
    if (tid < 64) gc[tid] = Y[((size_t)row0 + tid) * NCOL + 1032 + h];
    __syncthreads();

    if (tid < 64) {
        float ss = 0.f;
        #pragma unroll
        for (int i = 0; i < 32; ++i) ss = fmaf(Wc[tid][i], Wc[tid][i], ss);
        wnrm[tid] = 1.f / (sqrtf(ss) + 1e-6f);
    }
    __syncthreads();
    {
        float s = wnrm[lr];
        float4 w = *(const float4*)&Wc[lr][lc4];
        w.x *= s; w.y *= s; w.z *= s; w.w *= s;
        *(float4*)&Wc[lr][lc4] = w;
    }
    __syncthreads();

    // UZ[j][d] = sum_m Uc[j][m] * Zs[m][d]
    {
        float4 acc = make_float4(0.f, 0.f, 0.f, 0.f);
        #pragma unroll 8
        for (int m = 0; m < 32; ++m) {
            float u = Uc[lr][m];
            float4 z = *(const float4*)&Zs[m][lc4];
            acc.x = fmaf(u, z.x, acc.x);
            acc.y = fmaf(u, z.y, acc.y);
            acc.z = fmaf(u, z.z, acc.z);
            acc.w = fmaf(u, z.w, acc.w);
        }
        *(float4*)&UZ[lr][lc4] = acc;
    }
    // Pc[t][m] += sum_d Qc[t][d] * Zs[m][d]
    {
        float4 acc = *(const float4*)&Pc[lr][lc4];
        float* accp = (float*)&acc;
        #pragma unroll
        for (int dq = 0; dq < 32; dq += 4) {
            float4 q = *(const float4*)&Qc[lr][dq];
            #pragma unroll
            for (int j = 0; j < 4; ++j) {
                float4 z = *(const float4*)&Zs[lc4 + j][dq];
                accp[j] += dot4(q, z);
            }
        }
        *(float4*)&Pc[lr][lc4] = acc;
    }
    __syncthreads();

    // M2 = tril(Q UZ^T) incl diag; lanes walk rows (conflict-lean)
    {
        const int tr = tid >> 4, tc = tid & 15;
        const int t0 = tr * 2;
        float acc[2][4] = {};
        #pragma unroll
        for (int k = 0; k < 32; k += 4) {
            float4 q0 = *(const float4*)&Qc[t0][k];
            float4 q1 = *(const float4*)&Qc[t0 + 1][k];
            #pragma unroll
            for (int j = 0; j < 4; ++j) {
                int jj = tc + j * 16;
                float4 u = *(const float4*)&UZ[jj][k];
                acc[0][j] += dot4(q0, u);
                acc[1][j] += dot4(q1, u);
            }
        }
        #pragma unroll
        for (int i = 0; i < 2; ++i)
            #pragma unroll
            for (int j = 0; j < 4; ++j) {
                int t = t0 + i, jj = tc + j * 16;
                M2[t][jj] = (jj <= t) ? acc[i][j] : 0.f;
            }
    }
    __syncthreads();

    // final: res_bf = (Pc - M2 W) * exp(g)  (bf16)
    {
        float4 acc = *(const float4*)&Pc[lr][lc4];
        #pragma unroll 4
        for (int j = 0; j < 64; ++j) {
            float mm = M2[lr][j];
            float4 w = *(const float4*)&Wc[j][lc4];
            acc.x = fmaf(-mm, w.x, acc.x);
            acc.y = fmaf(-mm, w.y, acc.y);
            acc.z = fmaf(-mm, w.z, acc.z);
            acc.w = fmaf(-mm, w.w, acc.w);
        }
        float e = expf(gc[lr]);
        ushort4 o;
        o.x = f2bf(acc.x * e); o.y = f2bf(acc.y * e);
        o.z = f2bf(acc.z * e); o.w = f2bf(acc.w * e);
        *(ushort4*)&res_bf[(((size_t)row0 + lr) * NH + h) * HD + lc4] = o;
    }
}

// ---------------------------------------------------------------------------
extern "C" void kernel_launch(void* const* d_in, const int* in_sizes, int n_in,
                              void* d_out, int out_size, void* d_ws, size_t ws_size,
                              hipStream_t stream)
{
    const float* x     = (const float*)d_in[0];
    const float* Wq    = (const float*)d_in[1];
    const float* Wk    = (const float*)d_in[2];
    const float* Wv    = (const float*)d_in[3];
    const float* Ww    = (const float*)d_in[4];
    const float* Wbeta = (const float*)d_in[5];
    const float* bbeta = (const float*)d_in[6];
    const float* Wg    = (const float*)d_in[7];
    const float* bg    = (const float*)d_in[8];
    const float* Wo    = (const float*)d_in[9];
    float* out = (float*)d_out;

    float* ws      = (float*)d_ws;
    float* Y       = ws;                               // 17,039,360 f
    float* res     = Y + (size_t)NROW * NCOL;          // 4,194,304 f
    float* Ubuf    = res + (size_t)NROW * 256;         // 4,194,304 f
    float* D0buf   = Ubuf + (size_t)2048 * 2048;       // 2,097,152 f
    float* Pbuf    = D0buf + (size_t)2048 * 1024;      // 2,097,152 f
    float* Z0buf   = Pbuf + (size_t)2048 * 1024;       // 2,097,152 f
    unsigned short* x_bf       = (unsigned short*)(Z0buf + (size_t)2048 * 1024); // 8,388,608 us
    unsigned short* stacked_bf = x_bf + (size_t)NROW * HID;                      // 589,824 us
    unsigned short* Wo_bf      = stacked_bf + (size_t)NPAD * HID;                // 131,072 us
    unsigned short* res_bf     = Wo_bf + (size_t)HID * 256;                      // 4,194,304 us

    // 1. casts + weight concat (bf16)
    cast_bf16<<<(NROW * HID / 4 + 255) / 256, 256, 0, stream>>>(x, x_bf, NROW * HID / 4);
    cast_bf16<<<(HID * 256 / 4 + 255) / 256, 256, 0, stream>>>(Wo, Wo_bf, HID * 256 / 4);
    concat_w_bf<<<(NPAD * HID + 255) / 256, 256, 0, stream>>>(Wq, Wk, Wv, Ww, Wbeta, Wg, stacked_bf);

    // 2. projection GEMM (MFMA bf16) + beta/g epilogue
    gemm_mfma<<<dim3(NROW / 128, NPAD / 128), 256, 0, stream>>>(
        x_bf, stacked_bf, Y, NROW, NCOL, HID, NCOL, 1, bbeta, bg);

    // 3. chunked delta-rule precompute
    chunk_pre<<<2048, 512, 0, stream>>>(Y, res, Ubuf, D0buf, Pbuf);

    // 4. chunk-state scan
    scan_states<<<32, 256, 0, stream>>>(Pbuf, D0buf, Z0buf);

    // 5. Z-dependent output terms (writes bf16 res)
    chunk_out<<<2048, 512, 0, stream>>>(Y, Ubuf, Z0buf, res, res_bf);

    // 6. output GEMM (MFMA bf16): out = res @ Wo^T
    gemm_mfma<<<dim3(NROW / 128, HID / 128), 256, 0, stream>>>(
        res_bf, Wo_bf, out, NROW, HID, NH * HD, HID, 0, nullptr, nullptr);
}

// Round 5
// 450.994 us; speedup vs baseline: 5.8386x; 1.9646x over previous
//
#include <hip/hip_runtime.h>
#include <hip/hip_bf16.h>
#include <math.h>

// Problem constants
#define BATCH 4
#define TT 4096
#define HID 512
#define NH 8
#define HD 32
#define NROW (BATCH * TT)       // 16384
#define NPAD 1152               // padded col count for 128-wide MFMA tiles
#define QSCALE 0.17677669529663687f  // 32^-0.5
#define NCHUNK 64               // chunks per (b,h); chunk length 64

using s16x8 = __attribute__((ext_vector_type(8))) short;
using f32x4 = __attribute__((ext_vector_type(4))) float;

#define MFMA_BF16(a, b, c) __builtin_amdgcn_mfma_f32_16x16x32_bf16((a), (b), (c), 0, 0, 0)

__device__ __forceinline__ unsigned short f2bf(float v) {
    __hip_bfloat16 h = __float2bfloat16(v);
    unsigned short u;
    __builtin_memcpy(&u, &h, 2);
    return u;
}
__device__ __forceinline__ float bf2f(unsigned short u) {
    unsigned int x = ((unsigned int)u) << 16;
    float f;
    __builtin_memcpy(&f, &x, 4);
    return f;
}

// ---------------------------------------------------------------------------
// cast fp32 -> bf16, 4 elements per thread
// ---------------------------------------------------------------------------
__global__ __launch_bounds__(256) void cast_bf16(
    const float* __restrict__ src, unsigned short* __restrict__ dst, int n4)
{
    int i = blockIdx.x * 256 + threadIdx.x;
    if (i >= n4) return;
    float4 v = ((const float4*)src)[i];
    ushort4 o;
    o.x = f2bf(v.x); o.y = f2bf(v.y); o.z = f2bf(v.z); o.w = f2bf(v.w);
    ((ushort4*)dst)[i] = o;
}

// ---------------------------------------------------------------------------
// concat weights into stacked bf16 [1152][512]; fold q-scale; zero pad rows
// ---------------------------------------------------------------------------
__global__ __launch_bounds__(256) void concat_w_bf(
    const float* __restrict__ Wq, const float* __restrict__ Wk,
    const float* __restrict__ Wv, const float* __restrict__ Ww,
    const float* __restrict__ Wbeta, const float* __restrict__ Wg,
    unsigned short* __restrict__ dst)
{
    int o = blockIdx.x * 256 + threadIdx.x;   // < 1152*512
    if (o >= NPAD * HID) return;
    int r = o >> 9;                           // /512
    float v;
    if      (r < 256)  v = Wq[o] * QSCALE;
    else if (r < 512)  v = Wk[o - 256 * 512];
    else if (r < 768)  v = Wv[o - 512 * 512];
    else if (r < 1024) v = Ww[o - 768 * 512];
    else if (r < 1032) v = Wbeta[o - 1024 * 512];
    else if (r < 1040) v = Wg[o - 1032 * 512];
    else               v = 0.0f;
    dst[o] = f2bf(v);
}

// ---------------------------------------------------------------------------
// Projection GEMM (bf16 MFMA): [16384,512] x [1152,512]^T.
// Epilogue scatters to head-major bf16 q/k/v/w [bh][t][32] and fp32 beta/g
// [bh][t] with sigmoid / log-sigmoid applied.
// ---------------------------------------------------------------------------
__global__ __launch_bounds__(256) void gemm_proj(
    const unsigned short* __restrict__ A, const unsigned short* __restrict__ B,
    unsigned short* __restrict__ qb, unsigned short* __restrict__ kb,
    unsigned short* __restrict__ vb, unsigned short* __restrict__ wbv,
    float* __restrict__ betab, float* __restrict__ gb,
    const float* __restrict__ bbeta, const float* __restrict__ bg)
{
    __shared__ __align__(16) unsigned short As[128 * 32];
    __shared__ __align__(16) unsigned short Bs[128 * 32];
    const int tid = threadIdx.x;
    const int wave = tid >> 6, lane = tid & 63;
    const int quad = lane >> 4, l16 = lane & 15;
    const int wr = wave & 1, wc = wave >> 1;
    const int r0 = blockIdx.x * 128;
    const int c0 = blockIdx.y * 128;
    const int K = HID;

    f32x4 acc[4][4] = {};

    for (int k0 = 0; k0 < K; k0 += 32) {
        s16x8 ra[2], rb[2];
        #pragma unroll
        for (int i = 0; i < 2; ++i) {
            int slot = wave * 128 + i * 64 + lane;
            int row = slot >> 2, kq = slot & 3;
            ra[i] = *(const s16x8*)&A[(size_t)(r0 + row) * K + k0 + kq * 8];
            rb[i] = *(const s16x8*)&B[(size_t)(c0 + row) * K + k0 + kq * 8];
        }
        __syncthreads();
        #pragma unroll
        for (int i = 0; i < 2; ++i) {
            int slot = wave * 128 + i * 64 + lane;
            *(s16x8*)&As[slot * 8] = ra[i];
            *(s16x8*)&Bs[slot * 8] = rb[i];
        }
        __syncthreads();
        s16x8 af[4], bf[4];
        #pragma unroll
        for (int mi = 0; mi < 4; ++mi)
            af[mi] = *(const s16x8*)&As[(wr * 64 + mi * 16 + l16) * 32 + quad * 8];
        #pragma unroll
        for (int ni = 0; ni < 4; ++ni)
            bf[ni] = *(const s16x8*)&Bs[(wc * 64 + ni * 16 + l16) * 32 + quad * 8];
        #pragma unroll
        for (int mi = 0; mi < 4; ++mi)
            #pragma unroll
            for (int ni = 0; ni < 4; ++ni)
                acc[mi][ni] = MFMA_BF16(af[mi], bf[ni], acc[mi][ni]);
    }

    #pragma unroll
    for (int mi = 0; mi < 4; ++mi) {
        #pragma unroll
        for (int ni = 0; ni < 4; ++ni) {
            int col = c0 + wc * 64 + ni * 16 + l16;
            if (col >= 1040) continue;
            #pragma unroll
            for (int r = 0; r < 4; ++r) {
                int row = r0 + wr * 64 + mi * 16 + quad * 4 + r;
                int bb = row >> 12, t = row & 4095;
                float v = acc[mi][ni][r];
                if (col < 1024) {
                    int sub = col >> 8;
                    int hh = (col >> 5) & 7;
                    int d = col & 31;
                    unsigned short* dst = (sub == 0) ? qb : (sub == 1) ? kb
                                        : (sub == 2) ? vb : wbv;
                    dst[((size_t)(bb * 8 + hh) * 4096 + t) * 32 + d] = f2bf(v);
                } else if (col < 1032) {
                    float z = v + bbeta[col - 1024];
                    betab[(size_t)(bb * 8 + col - 1024) * 4096 + t] = 2.0f / (1.0f + expf(-z));
                } else {
                    float z = v + bg[col - 1032];
                    gb[(size_t)(bb * 8 + col - 1032) * 4096 + t] =
                        fminf(z, 0.0f) - log1pf(expf(-fabsf(z)));
                }
            }
        }
    }
}

// ---------------------------------------------------------------------------
// Output GEMM (bf16 MFMA): out[16384,512] = res_bf[16384,256] @ Wo_bf[512,256]^T
// ---------------------------------------------------------------------------
__global__ __launch_bounds__(256) void gemm_out(
    const unsigned short* __restrict__ A, const unsigned short* __restrict__ B,
    float* __restrict__ C)
{
    __shared__ __align__(16) unsigned short As[128 * 32];
    __shared__ __align__(16) unsigned short Bs[128 * 32];
    const int tid = threadIdx.x;
    const int wave = tid >> 6, lane = tid & 63;
    const int quad = lane >> 4, l16 = lane & 15;
    const int wr = wave & 1, wc = wave >> 1;
    const int r0 = blockIdx.x * 128;
    const int c0 = blockIdx.y * 128;
    const int K = 256;

    f32x4 acc[4][4] = {};

    for (int k0 = 0; k0 < K; k0 += 32) {
        s16x8 ra[2], rb[2];
        #pragma unroll
        for (int i = 0; i < 2; ++i) {
            int slot = wave * 128 + i * 64 + lane;
            int row = slot >> 2, kq = slot & 3;
            ra[i] = *(const s16x8*)&A[(size_t)(r0 + row) * K + k0 + kq * 8];
            rb[i] = *(const s16x8*)&B[(size_t)(c0 + row) * K + k0 + kq * 8];
        }
        __syncthreads();
        #pragma unroll
        for (int i = 0; i < 2; ++i) {
            int slot = wave * 128 + i * 64 + lane;
            *(s16x8*)&As[slot * 8] = ra[i];
            *(s16x8*)&Bs[slot * 8] = rb[i];
        }
        __syncthreads();
        s16x8 af[4], bf[4];
        #pragma unroll
        for (int mi = 0; mi < 4; ++mi)
            af[mi] = *(const s16x8*)&As[(wr * 64 + mi * 16 + l16) * 32 + quad * 8];
        #pragma unroll
        for (int ni = 0; ni < 4; ++ni)
            bf[ni] = *(const s16x8*)&Bs[(wc * 64 + ni * 16 + l16) * 32 + quad * 8];
        #pragma unroll
        for (int mi = 0; mi < 4; ++mi)
            #pragma unroll
            for (int ni = 0; ni < 4; ++ni)
                acc[mi][ni] = MFMA_BF16(af[mi], bf[ni], acc[mi][ni]);
    }

    #pragma unroll
    for (int mi = 0; mi < 4; ++mi)
        #pragma unroll
        for (int ni = 0; ni < 4; ++ni) {
            int col = c0 + wc * 64 + ni * 16 + l16;
            #pragma unroll
            for (int r = 0; r < 4; ++r) {
                int row = r0 + wr * 64 + mi * 16 + quad * 4 + r;
                C[(size_t)row * HID + col] = acc[mi][ni][r];
            }
        }
}

// ---------------------------------------------------------------------------
// chunk_pre: per-chunk WY precompute via MFMA. One block (256 thr) per chunk.
// Normalizes w (writes back to wb). Solves (I+tril(G,-1))[U|Rt]=[BW|tril(P,-1)K]
// with blocked-16 forward substitution. Writes U,Rt bf16; D0,Pmat fp32.
// ---------------------------------------------------------------------------
__global__ __launch_bounds__(256) void chunk_pre(
    const unsigned short* __restrict__ kb, const unsigned short* __restrict__ vb,
    unsigned short* __restrict__ wb, const float* __restrict__ betab,
    unsigned short* __restrict__ ub, unsigned short* __restrict__ rtb,
    float* __restrict__ D0buf, float* __restrict__ Pbuf)
{
    const int chunk = blockIdx.x;
    const int tid = threadIdx.x;
    const int wave = tid >> 6, lane = tid & 63;
    const int quad = lane >> 4, l16 = lane & 15;

    __shared__ __align__(16) unsigned short Kb[2048], Vb[2048], Wb[2048];
    __shared__ __align__(16) unsigned short KT[2048], VT[2048], WT[2048];
    __shared__ __align__(16) unsigned short Pbf[4096], nUT[2048], nRT[2048];
    __shared__ float G[64][66];
    __shared__ __align__(16) float X[64][68];
    __shared__ float betac[64], wn[64];

    const size_t cbase = (size_t)chunk * 2048;

    {
        int o = tid * 8;
        *(s16x8*)&Kb[o] = *(const s16x8*)&kb[cbase + o];
        *(s16x8*)&Vb[o] = *(const s16x8*)&vb[cbase + o];
        *(s16x8*)&Wb[o] = *(const s16x8*)&wb[cbase + o];
    }
    if (tid < 64) betac[tid] = betab[(size_t)chunk * 64 + tid];
    __syncthreads();

    // normalize w rows
    if (tid < 64) {
        float ss = 0.f;
        #pragma unroll
        for (int i = 0; i < 32; ++i) { float w = bf2f(Wb[tid * 32 + i]); ss = fmaf(w, w, ss); }
        wn[tid] = 1.f / (sqrtf(ss) + 1e-6f);
    }
    __syncthreads();
    {
        int o = tid * 8;
        float s = wn[tid >> 2];
        s16x8 wv = *(s16x8*)&Wb[o];
        s16x8 ov;
        #pragma unroll
        for (int j = 0; j < 8; ++j) ov[j] = (short)f2bf(bf2f((unsigned short)wv[j]) * s);
        *(s16x8*)&Wb[o] = ov;
        *(s16x8*)&wb[cbase + o] = ov;      // normalized w for chunk_out
    }
    __syncthreads();

    // transposed bf16 tiles KT/VT/WT [32][64]
    {
        int m = tid >> 3, i0 = (tid & 7) * 8;
        s16x8 a, b2, c2;
        #pragma unroll
        for (int j = 0; j < 8; ++j) {
            a[j]  = (short)Kb[(i0 + j) * 32 + m];
            b2[j] = (short)Vb[(i0 + j) * 32 + m];
            c2[j] = (short)Wb[(i0 + j) * 32 + m];
        }
        *(s16x8*)&KT[m * 64 + i0] = a;
        *(s16x8*)&VT[m * 64 + i0] = b2;
        *(s16x8*)&WT[m * 64 + i0] = c2;
    }
    // G = beta*W W^T (fp32); Pbf = strict-tril(beta*W V^T) (bf16)
    {
        s16x8 af = *(const s16x8*)&Wb[(wave * 16 + l16) * 32 + quad * 8];
        #pragma unroll
        for (int jt = 0; jt < 4; ++jt) {
            s16x8 bw = *(const s16x8*)&Wb[(jt * 16 + l16) * 32 + quad * 8];
            s16x8 bv = *(const s16x8*)&Vb[(jt * 16 + l16) * 32 + quad * 8];
            f32x4 z = {};
            f32x4 aG = MFMA_BF16(af, bw, z);
            f32x4 aP = MFMA_BF16(af, bv, z);
            #pragma unroll
            for (int r = 0; r < 4; ++r) {
                int t = wave * 16 + quad * 4 + r;
                int j = jt * 16 + l16;
                float bt = betac[t];
                G[t][j] = bt * aG[r];
                Pbf[t * 64 + j] = (j < t) ? f2bf(bt * aP[r]) : (unsigned short)0;
            }
        }
    }
    __syncthreads();

    // RHS: X[:,0:32] = beta*W ; X[:,32:64] = Pbf @ K  (via KT)
    {
        int r = tid >> 2, cc0 = (tid & 3) * 8;
        float bt = betac[r];
        s16x8 wv = *(const s16x8*)&Wb[r * 32 + cc0];
        #pragma unroll
        for (int j = 0; j < 8; ++j) X[r][cc0 + j] = bt * bf2f((unsigned short)wv[j]);
    }
    {
        s16x8 a0 = *(const s16x8*)&Pbf[(wave * 16 + l16) * 64 + quad * 8];
        s16x8 a1 = *(const s16x8*)&Pbf[(wave * 16 + l16) * 64 + 32 + quad * 8];
        #pragma unroll
        for (int dt = 0; dt < 2; ++dt) {
            s16x8 b0 = *(const s16x8*)&KT[(dt * 16 + l16) * 64 + quad * 8];
            s16x8 b1 = *(const s16x8*)&KT[(dt * 16 + l16) * 64 + 32 + quad * 8];
            f32x4 z = {};
            f32x4 acc = MFMA_BF16(a0, b0, z);
            acc = MFMA_BF16(a1, b1, acc);
            #pragma unroll
            for (int r = 0; r < 4; ++r)
                X[wave * 16 + quad * 4 + r][32 + dt * 16 + l16] = acc[r];
        }
    }

    // blocked forward substitution: 4 rounds of (wave-serial 16x16 diag + update)
    for (int tb = 0; tb < 64; tb += 16) {
        __syncthreads();
        if (tid < 64) {
            float xv[16];
            #pragma unroll
            for (int i = 0; i < 16; ++i) xv[i] = X[tb + i][tid];
            #pragma unroll
            for (int j = 1; j < 16; ++j)
                #pragma unroll
                for (int i = 0; i < j; ++i)
                    xv[j] = fmaf(-G[tb + j][tb + i], xv[i], xv[j]);
            #pragma unroll
            for (int i = 1; i < 16; ++i) X[tb + i][tid] = xv[i];
        }
        __syncthreads();
        if (tb < 48) {
            int n4 = (48 - tb) * 16;
            for (int idx = tid; idx < n4; idx += 256) {
                int t = tb + 16 + (idx >> 4);
                int cc = (idx & 15) * 4;
                float4 acc = *(float4*)&X[t][cc];
                #pragma unroll
                for (int i = 0; i < 16; ++i) {
                    float g = G[t][tb + i];
                    float4 xs = *(const float4*)&X[tb + i][cc];
                    acc.x = fmaf(-g, xs.x, acc.x);
                    acc.y = fmaf(-g, xs.y, acc.y);
                    acc.z = fmaf(-g, xs.z, acc.z);
                    acc.w = fmaf(-g, xs.w, acc.w);
                }
                *(float4*)&X[t][cc] = acc;
            }
        }
    }
    __syncthreads();

    // write U,Rt bf16 global; build negated transposed tiles nUT,nRT
    {
        int r = tid >> 2, c8 = (tid & 3) * 8;
        s16x8 uv, rv;
        #pragma unroll
        for (int j = 0; j < 8; ++j) {
            uv[j] = (short)f2bf(X[r][c8 + j]);
            rv[j] = (short)f2bf(X[r][32 + c8 + j]);
        }
        *(s16x8*)&ub[cbase + r * 32 + c8] = uv;
        *(s16x8*)&rtb[cbase + r * 32 + c8] = rv;
    }
    {
        int d = tid >> 3, i0 = (tid & 7) * 8;
        s16x8 u2, r2;
        #pragma unroll
        for (int j = 0; j < 8; ++j) {
            u2[j] = (short)f2bf(-X[i0 + j][d]);
            r2[j] = (short)f2bf(-X[i0 + j][32 + d]);
        }
        *(s16x8*)&nUT[d * 64 + i0] = u2;
        *(s16x8*)&nRT[d * 64 + i0] = r2;
    }
    __syncthreads();

    // D0 = V^T K - W^T Rt ; Pmat = I - W^T U   (one 16x16 tile per wave)
    {
        int mt = wave >> 1, nt = wave & 1;
        s16x8 va0 = *(const s16x8*)&VT[(mt * 16 + l16) * 64 + quad * 8];
        s16x8 va1 = *(const s16x8*)&VT[(mt * 16 + l16) * 64 + 32 + quad * 8];
        s16x8 wa0 = *(const s16x8*)&WT[(mt * 16 + l16) * 64 + quad * 8];
        s16x8 wa1 = *(const s16x8*)&WT[(mt * 16 + l16) * 64 + 32 + quad * 8];
        s16x8 kb0 = *(const s16x8*)&KT[(nt * 16 + l16) * 64 + quad * 8];
        s16x8 kb1 = *(const s16x8*)&KT[(nt * 16 + l16) * 64 + 32 + quad * 8];
        s16x8 rb0 = *(const s16x8*)&nRT[(nt * 16 + l16) * 64 + quad * 8];
        s16x8 rb1 = *(const s16x8*)&nRT[(nt * 16 + l16) * 64 + 32 + quad * 8];
        s16x8 ub0 = *(const s16x8*)&nUT[(nt * 16 + l16) * 64 + quad * 8];
        s16x8 ub1 = *(const s16x8*)&nUT[(nt * 16 + l16) * 64 + 32 + quad * 8];
        f32x4 z = {};
        f32x4 d0 = MFMA_BF16(va0, kb0, z);
        d0 = MFMA_BF16(va1, kb1, d0);
        d0 = MFMA_BF16(wa0, rb0, d0);
        d0 = MFMA_BF16(wa1, rb1, d0);
        f32x4 pm = MFMA_BF16(wa0, ub0, z);
        pm = MFMA_BF16(wa1, ub1, pm);
        int m0 = mt * 16 + quad * 4, dd = nt * 16 + l16;
        #pragma unroll
        for (int r = 0; r < 4; ++r) {
            D0buf[(size_t)chunk * 1024 + (m0 + r) * 32 + dd] = d0[r];
            Pbuf[(size_t)chunk * 1024 + (m0 + r) * 32 + dd] =
                pm[r] + ((m0 + r) == dd ? 1.f : 0.f);
        }
    }
}

// ---------------------------------------------------------------------------
// scan_states: per (b,h), sequential scan over 64 chunks (fp32)
// ---------------------------------------------------------------------------
__global__ __launch_bounds__(256) void scan_states(
    const float* __restrict__ Pbuf, const float* __restrict__ D0buf,
    float* __restrict__ Z0buf)
{
    const int bh = blockIdx.x;
    const int tid = threadIdx.x;
    __shared__ float Zs[32][33];
    __shared__ float Pms[32][33];
    for (int idx = tid; idx < 1024; idx += 256)
        Zs[idx >> 5][idx & 31] = 0.f;

    for (int c = 0; c < NCHUNK; ++c) {
        size_t cb = ((size_t)bh * 64 + c) * 1024;
        __syncthreads();
        for (int idx = tid; idx < 1024; idx += 256)
            Pms[idx >> 5][idx & 31] = Pbuf[cb + idx];
        __syncthreads();
        float zn[4];
        #pragma unroll
        for (int k = 0; k < 4; ++k) {
            int idx = tid + k * 256;
            int m = idx >> 5, dd = idx & 31;
            float acc = D0buf[cb + idx];
            #pragma unroll 8
            for (int mp = 0; mp < 32; ++mp)
                acc = fmaf(Pms[m][mp], Zs[mp][dd], acc);
            zn[k] = acc;
            Z0buf[cb + idx] = Zs[m][dd];
        }
        __syncthreads();
        #pragma unroll
        for (int k = 0; k < 4; ++k) {
            int idx = tid + k * 256;
            Zs[idx >> 5][idx & 31] = zn[k];
        }
    }
}

// ---------------------------------------------------------------------------
// chunk_out: O = (QZ0^T + tril(QK^T)V - tril(Q(Rt+UZ0)^T)W) * exp(g), bf16 out
// ---------------------------------------------------------------------------
__global__ __launch_bounds__(256) void chunk_out(
    const unsigned short* __restrict__ qb, const unsigned short* __restrict__ kb,
    const unsigned short* __restrict__ vb, const unsigned short* __restrict__ wb,
    const unsigned short* __restrict__ ub, const unsigned short* __restrict__ rtb,
    const float* __restrict__ Z0buf, const float* __restrict__ gb,
    unsigned short* __restrict__ res_bf)
{
    const int chunk = blockIdx.x;
    const int bh = chunk >> 6, c = chunk & 63;
    const int b = bh >> 3, h = bh & 7;
    const int row0 = b * TT + c * 64;
    const int tid = threadIdx.x;
    const int wave = tid >> 6, lane = tid & 63;
    const int quad = lane >> 4, l16 = lane & 15;

    __shared__ __align__(16) unsigned short Qb[2048], Kb[2048], Vb[2048], Wb[2048];
    __shared__ __align__(16) unsigned short Ub[2048], Rb[2048], S2[2048];
    __shared__ __align__(16) unsigned short A1m[4096], nA2m[4096];
    __shared__ __align__(16) unsigned short VT[2048], WT[2048];
    __shared__ __align__(16) unsigned short Z0b[1024], Z0T[1024];
    __shared__ float gc[64];

    const size_t cbase = (size_t)chunk * 2048;
    {
        int o = tid * 8;
        *(s16x8*)&Qb[o] = *(const s16x8*)&qb[cbase + o];
        *(s16x8*)&Kb[o] = *(const s16x8*)&kb[cbase + o];
        *(s16x8*)&Vb[o] = *(const s16x8*)&vb[cbase + o];
        *(s16x8*)&Wb[o] = *(const s16x8*)&wb[cbase + o];
        *(s16x8*)&Ub[o] = *(const s16x8*)&ub[cbase + o];
        *(s16x8*)&Rb[o] = *(const s16x8*)&rtb[cbase + o];
    }
    {
        #pragma unroll
        for (int j = 0; j < 4; ++j) {
            int e = tid * 4 + j;
            float z = Z0buf[(size_t)chunk * 1024 + e];
            unsigned short zb = f2bf(z);
            Z0b[e] = zb;
            Z0T[(e & 31) * 32 + (e >> 5)] = zb;
        }
    }
    if (tid < 64) gc[tid] = gb[(size_t)chunk * 64 + tid];
    __syncthreads();

    // transposes VT/WT [32][64]
    {
        int m = tid >> 3, i0 = (tid & 7) * 8;
        s16x8 a, b2;
        #pragma unroll
        for (int j = 0; j < 8; ++j) {
            a[j]  = (short)Vb[(i0 + j) * 32 + m];
            b2[j] = (short)Wb[(i0 + j) * 32 + m];
        }
        *(s16x8*)&VT[m * 64 + i0] = a;
        *(s16x8*)&WT[m * 64 + i0] = b2;
    }
    // S2 = Rt + U Z0
    {
        s16x8 af = *(const s16x8*)&Ub[(wave * 16 + l16) * 32 + quad * 8];
        #pragma unroll
        for (int dt = 0; dt < 2; ++dt) {
            s16x8 bf_ = *(const s16x8*)&Z0T[(dt * 16 + l16) * 32 + quad * 8];
            f32x4 z = {};
            f32x4 acc = MFMA_BF16(af, bf_, z);
            #pragma unroll
            for (int r = 0; r < 4; ++r) {
                int j = wave * 16 + quad * 4 + r;
                int d = dt * 16 + l16;
                float s2 = acc[r] + bf2f(Rb[j * 32 + d]);
                S2[j * 32 + d] = f2bf(s2);
            }
        }
    }
    __syncthreads();

    // A1 = tril(QK^T), nA2 = -tril(Q S2^T)   (inclusive diag)
    {
        s16x8 qf = *(const s16x8*)&Qb[(wave * 16 + l16) * 32 + quad * 8];
        #pragma unroll
        for (int jt = 0; jt < 4; ++jt) {
            s16x8 kf = *(const s16x8*)&Kb[(jt * 16 + l16) * 32 + quad * 8];
            s16x8 sf = *(const s16x8*)&S2[(jt * 16 + l16) * 32 + quad * 8];
            f32x4 z = {};
            f32x4 a1 = MFMA_BF16(qf, kf, z);
            f32x4 a2 = MFMA_BF16(qf, sf, z);
            #pragma unroll
            for (int r = 0; r < 4; ++r) {
                int t = wave * 16 + quad * 4 + r;
                int j = jt * 16 + l16;
                bool keep = (j <= t);
                A1m[t * 64 + j]  = keep ? f2bf(a1[r]) : (unsigned short)0;
                nA2m[t * 64 + j] = keep ? f2bf(-a2[r]) : (unsigned short)0;
            }
        }
    }
    __syncthreads();

    // O = Q Z0^T + A1m V + nA2m W ; scale exp(g); store bf16
    {
        s16x8 qf = *(const s16x8*)&Qb[(wave * 16 + l16) * 32 + quad * 8];
        s16x8 p0 = *(const s16x8*)&A1m[(wave * 16 + l16) * 64 + quad * 8];
        s16x8 p1 = *(const s16x8*)&A1m[(wave * 16 + l16) * 64 + 32 + quad * 8];
        s16x8 m0 = *(const s16x8*)&nA2m[(wave * 16 + l16) * 64 + quad * 8];
        s16x8 m1 = *(const s16x8*)&nA2m[(wave * 16 + l16) * 64 + 32 + quad * 8];
        #pragma unroll
        for (int mt = 0; mt < 2; ++mt) {
            s16x8 zf = *(const s16x8*)&Z0b[(mt * 16 + l16) * 32 + quad * 8];
            s16x8 v0 = *(const s16x8*)&VT[(mt * 16 + l16) * 64 + quad * 8];
            s16x8 v1 = *(const s16x8*)&VT[(mt * 16 + l16) * 64 + 32 + quad * 8];
            s16x8 w0 = *(const s16x8*)&WT[(mt * 16 + l16) * 64 + quad * 8];
            s16x8 w1 = *(const s16x8*)&WT[(mt * 16 + l16) * 64 + 32 + quad * 8];
            f32x4 z = {};
            f32x4 acc = MFMA_BF16(qf, zf, z);
            acc = MFMA_BF16(p0, v0, acc);
            acc = MFMA_BF16(p1, v1, acc);
            acc = MFMA_BF16(m0, w0, acc);
            acc = MFMA_BF16(m1, w1, acc);
            #pragma unroll
            for (int r = 0; r < 4; ++r) {
                int t = wave * 16 + quad * 4 + r;
                int m = mt * 16 + l16;
                float e = expf(gc[t]);
                res_bf[(size_t)(row0 + t) * 256 + h * 32 + m] = f2bf(acc[r] * e);
            }
        }
    }
}

// ---------------------------------------------------------------------------
extern "C" void kernel_launch(void* const* d_in, const int* in_sizes, int n_in,
                              void* d_out, int out_size, void* d_ws, size_t ws_size,
                              hipStream_t stream)
{
    const float* x     = (const float*)d_in[0];
    const float* Wq    = (const float*)d_in[1];
    const float* Wk    = (const float*)d_in[2];
    const float* Wv    = (const float*)d_in[3];
    const float* Ww    = (const float*)d_in[4];
    const float* Wbeta = (const float*)d_in[5];
    const float* bbeta = (const float*)d_in[6];
    const float* Wg    = (const float*)d_in[7];
    const float* bg    = (const float*)d_in[8];
    const float* Wo    = (const float*)d_in[9];
    float* out = (float*)d_out;

    unsigned short* x_bf       = (unsigned short*)d_ws;           // 8,388,608
    unsigned short* stacked_bf = x_bf + (size_t)NROW * HID;       // 589,824
    unsigned short* Wo_bf      = stacked_bf + (size_t)NPAD * HID; // 131,072
    unsigned short* qb  = Wo_bf + (size_t)HID * 256;              // 4,194,304 each
    unsigned short* kb  = qb + (size_t)NROW * 256;
    unsigned short* vb  = kb + (size_t)NROW * 256;
    unsigned short* wbv = vb + (size_t)NROW * 256;
    unsigned short* ub  = wbv + (size_t)NROW * 256;
    unsigned short* rtb = ub + (size_t)NROW * 256;
    unsigned short* res_bf = rtb + (size_t)NROW * 256;
    float* betab = (float*)(res_bf + (size_t)NROW * 256);         // 131,072 f
    float* gb    = betab + (size_t)NROW * 8;
    float* D0buf = gb + (size_t)NROW * 8;                         // 2,097,152 f each
    float* Pbuf  = D0buf + (size_t)2048 * 1024;
    float* Z0buf = Pbuf + (size_t)2048 * 1024;

    // 1. casts + weight concat
    cast_bf16<<<(NROW * HID / 4 + 255) / 256, 256, 0, stream>>>(x, x_bf, NROW * HID / 4);
    cast_bf16<<<(HID * 256 / 4 + 255) / 256, 256, 0, stream>>>(Wo, Wo_bf, HID * 256 / 4);
    concat_w_bf<<<(NPAD * HID + 255) / 256, 256, 0, stream>>>(Wq, Wk, Wv, Ww, Wbeta, Wg, stacked_bf);

    // 2. projection GEMM -> head-major bf16 q/k/v/w + fp32 beta/g
    gemm_proj<<<dim3(NROW / 128, NPAD / 128), 256, 0, stream>>>(
        x_bf, stacked_bf, qb, kb, vb, wbv, betab, gb, bbeta, bg);

    // 3. chunked delta-rule precompute (MFMA)
    chunk_pre<<<2048, 256, 0, stream>>>(kb, vb, wbv, betab, ub, rtb, D0buf, Pbuf);

    // 4. chunk-state scan
    scan_states<<<32, 256, 0, stream>>>(Pbuf, D0buf, Z0buf);

    // 5. Z-dependent output terms (MFMA, writes bf16 res)
    chunk_out<<<2048, 256, 0, stream>>>(qb, kb, vb, wbv, ub, rtb, Z0buf, gb, res_bf);

    // 6. output GEMM: out = res @ Wo^T
    gemm_out<<<dim3(NROW / 128, HID / 128), 256, 0, stream>>>(res_bf, Wo_bf, out);
}

// Round 6
// 293.116 us; speedup vs baseline: 8.9834x; 1.5386x over previous
//
#include <hip/hip_runtime.h>
#include <hip/hip_bf16.h>
#include <math.h>

// Problem constants
#define BATCH 4
#define TT 4096
#define HID 512
#define NH 8
#define HD 32
#define NROW (BATCH * TT)       // 16384
#define NPAD 1152               // padded col count for 128-wide MFMA tiles
#define QSCALE 0.17677669529663687f  // 32^-0.5
#define NCHUNK 64               // chunks per (b,h); chunk length 64

using s16x8 = __attribute__((ext_vector_type(8))) short;
using f32x4 = __attribute__((ext_vector_type(4))) float;

#define MFMA_BF16(a, b, c) __builtin_amdgcn_mfma_f32_16x16x32_bf16((a), (b), (c), 0, 0, 0)

__device__ __forceinline__ unsigned short f2bf(float v) {
    __hip_bfloat16 h = __float2bfloat16(v);
    unsigned short u;
    __builtin_memcpy(&u, &h, 2);
    return u;
}
__device__ __forceinline__ float bf2f(unsigned short u) {
    unsigned int x = ((unsigned int)u) << 16;
    float f;
    __builtin_memcpy(&f, &x, 4);
    return f;
}

// ---------------------------------------------------------------------------
// cast fp32 -> bf16, 4 elements per thread
// ---------------------------------------------------------------------------
__global__ __launch_bounds__(256) void cast_bf16(
    const float* __restrict__ src, unsigned short* __restrict__ dst, int n4)
{
    int i = blockIdx.x * 256 + threadIdx.x;
    if (i >= n4) return;
    float4 v = ((const float4*)src)[i];
    ushort4 o;
    o.x = f2bf(v.x); o.y = f2bf(v.y); o.z = f2bf(v.z); o.w = f2bf(v.w);
    ((ushort4*)dst)[i] = o;
}

// ---------------------------------------------------------------------------
// concat weights into stacked bf16 [1152][512]; fold q-scale; zero pad rows
// ---------------------------------------------------------------------------
__global__ __launch_bounds__(256) void concat_w_bf(
    const float* __restrict__ Wq, const float* __restrict__ Wk,
    const float* __restrict__ Wv, const float* __restrict__ Ww,
    const float* __restrict__ Wbeta, const float* __restrict__ Wg,
    unsigned short* __restrict__ dst)
{
    int o = blockIdx.x * 256 + threadIdx.x;   // < 1152*512
    if (o >= NPAD * HID) return;
    int r = o >> 9;                           // /512
    float v;
    if      (r < 256)  v = Wq[o] * QSCALE;
    else if (r < 512)  v = Wk[o - 256 * 512];
    else if (r < 768)  v = Wv[o - 512 * 512];
    else if (r < 1024) v = Ww[o - 768 * 512];
    else if (r < 1032) v = Wbeta[o - 1024 * 512];
    else if (r < 1040) v = Wg[o - 1032 * 512];
    else               v = 0.0f;
    dst[o] = f2bf(v);
}

// ---------------------------------------------------------------------------
// Projection GEMM (bf16 MFMA): [16384,512] x [1152,512]^T.
// Epilogue scatters to head-major bf16 q/k/v/w [bh][t][32] and fp32 beta/g
// [bh][t] with sigmoid / log-sigmoid applied.
// ---------------------------------------------------------------------------
__global__ __launch_bounds__(256) void gemm_proj(
    const unsigned short* __restrict__ A, const unsigned short* __restrict__ B,
    unsigned short* __restrict__ qb, unsigned short* __restrict__ kb,
    unsigned short* __restrict__ vb, unsigned short* __restrict__ wbv,
    float* __restrict__ betab, float* __restrict__ gb,
    const float* __restrict__ bbeta, const float* __restrict__ bg)
{
    __shared__ __align__(16) unsigned short As[128 * 32];
    __shared__ __align__(16) unsigned short Bs[128 * 32];
    const int tid = threadIdx.x;
    const int wave = tid >> 6, lane = tid & 63;
    const int quad = lane >> 4, l16 = lane & 15;
    const int wr = wave & 1, wc = wave >> 1;
    const int r0 = blockIdx.x * 128;
    const int c0 = blockIdx.y * 128;
    const int K = HID;

    f32x4 acc[4][4] = {};

    for (int k0 = 0; k0 < K; k0 += 32) {
        s16x8 ra[2], rb[2];
        #pragma unroll
        for (int i = 0; i < 2; ++i) {
            int slot = wave * 128 + i * 64 + lane;
            int row = slot >> 2, kq = slot & 3;
            ra[i] = *(const s16x8*)&A[(size_t)(r0 + row) * K + k0 + kq * 8];
            rb[i] = *(const s16x8*)&B[(size_t)(c0 + row) * K + k0 + kq * 8];
        }
        __syncthreads();
        #pragma unroll
        for (int i = 0; i < 2; ++i) {
            int slot = wave * 128 + i * 64 + lane;
            *(s16x8*)&As[slot * 8] = ra[i];
            *(s16x8*)&Bs[slot * 8] = rb[i];
        }
        __syncthreads();
        s16x8 af[4], bf[4];
        #pragma unroll
        for (int mi = 0; mi < 4; ++mi)
            af[mi] = *(const s16x8*)&As[(wr * 64 + mi * 16 + l16) * 32 + quad * 8];
        #pragma unroll
        for (int ni = 0; ni < 4; ++ni)
            bf[ni] = *(const s16x8*)&Bs[(wc * 64 + ni * 16 + l16) * 32 + quad * 8];
        #pragma unroll
        for (int mi = 0; mi < 4; ++mi)
            #pragma unroll
            for (int ni = 0; ni < 4; ++ni)
                acc[mi][ni] = MFMA_BF16(af[mi], bf[ni], acc[mi][ni]);
    }

    #pragma unroll
    for (int mi = 0; mi < 4; ++mi) {
        #pragma unroll
        for (int ni = 0; ni < 4; ++ni) {
            int col = c0 + wc * 64 + ni * 16 + l16;
            if (col >= 1040) continue;
            #pragma unroll
            for (int r = 0; r < 4; ++r) {
                int row = r0 + wr * 64 + mi * 16 + quad * 4 + r;
                int bb = row >> 12, t = row & 4095;
                float v = acc[mi][ni][r];
                if (col < 1024) {
                    int sub = col >> 8;
                    int hh = (col >> 5) & 7;
                    int d = col & 31;
                    unsigned short* dst = (sub == 0) ? qb : (sub == 1) ? kb
                                        : (sub == 2) ? vb : wbv;
                    dst[((size_t)(bb * 8 + hh) * 4096 + t) * 32 + d] = f2bf(v);
                } else if (col < 1032) {
                    float z = v + bbeta[col - 1024];
                    betab[(size_t)(bb * 8 + col - 1024) * 4096 + t] = 2.0f / (1.0f + expf(-z));
                } else {
                    float z = v + bg[col - 1032];
                    gb[(size_t)(bb * 8 + col - 1032) * 4096 + t] =
                        fminf(z, 0.0f) - log1pf(expf(-fabsf(z)));
                }
            }
        }
    }
}

// ---------------------------------------------------------------------------
// Output GEMM (bf16 MFMA): out[16384,512] = res_bf[16384,256] @ Wo_bf[512,256]^T
// ---------------------------------------------------------------------------
__global__ __launch_bounds__(256) void gemm_out(
    const unsigned short* __restrict__ A, const unsigned short* __restrict__ B,
    float* __restrict__ C)
{
    __shared__ __align__(16) unsigned short As[128 * 32];
    __shared__ __align__(16) unsigned short Bs[128 * 32];
    const int tid = threadIdx.x;
    const int wave = tid >> 6, lane = tid & 63;
    const int quad = lane >> 4, l16 = lane & 15;
    const int wr = wave & 1, wc = wave >> 1;
    const int r0 = blockIdx.x * 128;
    const int c0 = blockIdx.y * 128;
    const int K = 256;

    f32x4 acc[4][4] = {};

    for (int k0 = 0; k0 < K; k0 += 32) {
        s16x8 ra[2], rb[2];
        #pragma unroll
        for (int i = 0; i < 2; ++i) {
            int slot = wave * 128 + i * 64 + lane;
            int row = slot >> 2, kq = slot & 3;
            ra[i] = *(const s16x8*)&A[(size_t)(r0 + row) * K + k0 + kq * 8];
            rb[i] = *(const s16x8*)&B[(size_t)(c0 + row) * K + k0 + kq * 8];
        }
        __syncthreads();
        #pragma unroll
        for (int i = 0; i < 2; ++i) {
            int slot = wave * 128 + i * 64 + lane;
            *(s16x8*)&As[slot * 8] = ra[i];
            *(s16x8*)&Bs[slot * 8] = rb[i];
        }
        __syncthreads();
        s16x8 af[4], bf[4];
        #pragma unroll
        for (int mi = 0; mi < 4; ++mi)
            af[mi] = *(const s16x8*)&As[(wr * 64 + mi * 16 + l16) * 32 + quad * 8];
        #pragma unroll
        for (int ni = 0; ni < 4; ++ni)
            bf[ni] = *(const s16x8*)&Bs[(wc * 64 + ni * 16 + l16) * 32 + quad * 8];
        #pragma unroll
        for (int mi = 0; mi < 4; ++mi)
            #pragma unroll
            for (int ni = 0; ni < 4; ++ni)
                acc[mi][ni] = MFMA_BF16(af[mi], bf[ni], acc[mi][ni]);
    }

    #pragma unroll
    for (int mi = 0; mi < 4; ++mi)
        #pragma unroll
        for (int ni = 0; ni < 4; ++ni) {
            int col = c0 + wc * 64 + ni * 16 + l16;
            #pragma unroll
            for (int r = 0; r < 4; ++r) {
                int row = r0 + wr * 64 + mi * 16 + quad * 4 + r;
                C[(size_t)row * HID + col] = acc[mi][ni][r];
            }
        }
}

// ---------------------------------------------------------------------------
// chunk_pre: per-chunk WY precompute via MFMA. One block (256 thr) per chunk.
// ---------------------------------------------------------------------------
__global__ __launch_bounds__(256) void chunk_pre(
    const unsigned short* __restrict__ kb, const unsigned short* __restrict__ vb,
    unsigned short* __restrict__ wb, const float* __restrict__ betab,
    unsigned short* __restrict__ ub, unsigned short* __restrict__ rtb,
    float* __restrict__ D0buf, float* __restrict__ Pbuf)
{
    const int chunk = blockIdx.x;
    const int tid = threadIdx.x;
    const int wave = tid >> 6, lane = tid & 63;
    const int quad = lane >> 4, l16 = lane & 15;

    __shared__ __align__(16) unsigned short Kb[2048], Vb[2048], Wb[2048];
    __shared__ __align__(16) unsigned short KT[2048], VT[2048], WT[2048];
    __shared__ __align__(16) unsigned short Pbf[4096], nUT[2048], nRT[2048];
    __shared__ float G[64][66];
    __shared__ __align__(16) float X[64][68];
    __shared__ float betac[64], wn[64];

    const size_t cbase = (size_t)chunk * 2048;

    {
        int o = tid * 8;
        *(s16x8*)&Kb[o] = *(const s16x8*)&kb[cbase + o];
        *(s16x8*)&Vb[o] = *(const s16x8*)&vb[cbase + o];
        *(s16x8*)&Wb[o] = *(const s16x8*)&wb[cbase + o];
    }
    if (tid < 64) betac[tid] = betab[(size_t)chunk * 64 + tid];
    __syncthreads();

    // normalize w rows
    if (tid < 64) {
        float ss = 0.f;
        #pragma unroll
        for (int i = 0; i < 32; ++i) { float w = bf2f(Wb[tid * 32 + i]); ss = fmaf(w, w, ss); }
        wn[tid] = 1.f / (sqrtf(ss) + 1e-6f);
    }
    __syncthreads();
    {
        int o = tid * 8;
        float s = wn[tid >> 2];
        s16x8 wv = *(s16x8*)&Wb[o];
        s16x8 ov;
        #pragma unroll
        for (int j = 0; j < 8; ++j) ov[j] = (short)f2bf(bf2f((unsigned short)wv[j]) * s);
        *(s16x8*)&Wb[o] = ov;
        *(s16x8*)&wb[cbase + o] = ov;      // normalized w for chunk_out
    }
    __syncthreads();

    // transposed bf16 tiles KT/VT/WT [32][64]
    {
        int m = tid >> 3, i0 = (tid & 7) * 8;
        s16x8 a, b2, c2;
        #pragma unroll
        for (int j = 0; j < 8; ++j) {
            a[j]  = (short)Kb[(i0 + j) * 32 + m];
            b2[j] = (short)Vb[(i0 + j) * 32 + m];
            c2[j] = (short)Wb[(i0 + j) * 32 + m];
        }
        *(s16x8*)&KT[m * 64 + i0] = a;
        *(s16x8*)&VT[m * 64 + i0] = b2;
        *(s16x8*)&WT[m * 64 + i0] = c2;
    }
    // G = beta*W W^T (fp32); Pbf = strict-tril(beta*W V^T) (bf16)
    {
        s16x8 af = *(const s16x8*)&Wb[(wave * 16 + l16) * 32 + quad * 8];
        #pragma unroll
        for (int jt = 0; jt < 4; ++jt) {
            s16x8 bw = *(const s16x8*)&Wb[(jt * 16 + l16) * 32 + quad * 8];
            s16x8 bv = *(const s16x8*)&Vb[(jt * 16 + l16) * 32 + quad * 8];
            f32x4 z = {};
            f32x4 aG = MFMA_BF16(af, bw, z);
            f32x4 aP = MFMA_BF16(af, bv, z);
            #pragma unroll
            for (int r = 0; r < 4; ++r) {
                int t = wave * 16 + quad * 4 + r;
                int j = jt * 16 + l16;
                float bt = betac[t];
                G[t][j] = bt * aG[r];
                Pbf[t * 64 + j] = (j < t) ? f2bf(bt * aP[r]) : (unsigned short)0;
            }
        }
    }
    __syncthreads();

    // RHS: X[:,0:32] = beta*W ; X[:,32:64] = Pbf @ K  (via KT)
    {
        int r = tid >> 2, cc0 = (tid & 3) * 8;
        float bt = betac[r];
        s16x8 wv = *(const s16x8*)&Wb[r * 32 + cc0];
        #pragma unroll
        for (int j = 0; j < 8; ++j) X[r][cc0 + j] = bt * bf2f((unsigned short)wv[j]);
    }
    {
        s16x8 a0 = *(const s16x8*)&Pbf[(wave * 16 + l16) * 64 + quad * 8];
        s16x8 a1 = *(const s16x8*)&Pbf[(wave * 16 + l16) * 64 + 32 + quad * 8];
        #pragma unroll
        for (int dt = 0; dt < 2; ++dt) {
            s16x8 b0 = *(const s16x8*)&KT[(dt * 16 + l16) * 64 + quad * 8];
            s16x8 b1 = *(const s16x8*)&KT[(dt * 16 + l16) * 64 + 32 + quad * 8];
            f32x4 z = {};
            f32x4 acc = MFMA_BF16(a0, b0, z);
            acc = MFMA_BF16(a1, b1, acc);
            #pragma unroll
            for (int r = 0; r < 4; ++r)
                X[wave * 16 + quad * 4 + r][32 + dt * 16 + l16] = acc[r];
        }
    }

    // blocked forward substitution: 4 rounds of (wave-serial 16x16 diag + update)
    for (int tb = 0; tb < 64; tb += 16) {
        __syncthreads();
        if (tid < 64) {
            float xv[16];
            #pragma unroll
            for (int i = 0; i < 16; ++i) xv[i] = X[tb + i][tid];
            #pragma unroll
            for (int j = 1; j < 16; ++j)
                #pragma unroll
                for (int i = 0; i < j; ++i)
                    xv[j] = fmaf(-G[tb + j][tb + i], xv[i], xv[j]);
            #pragma unroll
            for (int i = 1; i < 16; ++i) X[tb + i][tid] = xv[i];
        }
        __syncthreads();
        if (tb < 48) {
            int n4 = (48 - tb) * 16;
            for (int idx = tid; idx < n4; idx += 256) {
                int t = tb + 16 + (idx >> 4);
                int cc = (idx & 15) * 4;
                float4 acc = *(float4*)&X[t][cc];
                #pragma unroll
                for (int i = 0; i < 16; ++i) {
                    float g = G[t][tb + i];
                    float4 xs = *(const float4*)&X[tb + i][cc];
                    acc.x = fmaf(-g, xs.x, acc.x);
                    acc.y = fmaf(-g, xs.y, acc.y);
                    acc.z = fmaf(-g, xs.z, acc.z);
                    acc.w = fmaf(-g, xs.w, acc.w);
                }
                *(float4*)&X[t][cc] = acc;
            }
        }
    }
    __syncthreads();

    // write U,Rt bf16 global; build negated transposed tiles nUT,nRT
    {
        int r = tid >> 2, c8 = (tid & 3) * 8;
        s16x8 uv, rv;
        #pragma unroll
        for (int j = 0; j < 8; ++j) {
            uv[j] = (short)f2bf(X[r][c8 + j]);
            rv[j] = (short)f2bf(X[r][32 + c8 + j]);
        }
        *(s16x8*)&ub[cbase + r * 32 + c8] = uv;
        *(s16x8*)&rtb[cbase + r * 32 + c8] = rv;
    }
    {
        int d = tid >> 3, i0 = (tid & 7) * 8;
        s16x8 u2, r2;
        #pragma unroll
        for (int j = 0; j < 8; ++j) {
            u2[j] = (short)f2bf(-X[i0 + j][d]);
            r2[j] = (short)f2bf(-X[i0 + j][32 + d]);
        }
        *(s16x8*)&nUT[d * 64 + i0] = u2;
        *(s16x8*)&nRT[d * 64 + i0] = r2;
    }
    __syncthreads();

    // D0 = V^T K - W^T Rt ; Pmat = I - W^T U   (one 16x16 tile per wave)
    {
        int mt = wave >> 1, nt = wave & 1;
        s16x8 va0 = *(const s16x8*)&VT[(mt * 16 + l16) * 64 + quad * 8];
        s16x8 va1 = *(const s16x8*)&VT[(mt * 16 + l16) * 64 + 32 + quad * 8];
        s16x8 wa0 = *(const s16x8*)&WT[(mt * 16 + l16) * 64 + quad * 8];
        s16x8 wa1 = *(const s16x8*)&WT[(mt * 16 + l16) * 64 + 32 + quad * 8];
        s16x8 kb0 = *(const s16x8*)&KT[(nt * 16 + l16) * 64 + quad * 8];
        s16x8 kb1 = *(const s16x8*)&KT[(nt * 16 + l16) * 64 + 32 + quad * 8];
        s16x8 rb0 = *(const s16x8*)&nRT[(nt * 16 + l16) * 64 + quad * 8];
        s16x8 rb1 = *(const s16x8*)&nRT[(nt * 16 + l16) * 64 + 32 + quad * 8];
        s16x8 ub0 = *(const s16x8*)&nUT[(nt * 16 + l16) * 64 + quad * 8];
        s16x8 ub1 = *(const s16x8*)&nUT[(nt * 16 + l16) * 64 + 32 + quad * 8];
        f32x4 z = {};
        f32x4 d0 = MFMA_BF16(va0, kb0, z);
        d0 = MFMA_BF16(va1, kb1, d0);
        d0 = MFMA_BF16(wa0, rb0, d0);
        d0 = MFMA_BF16(wa1, rb1, d0);
        f32x4 pm = MFMA_BF16(wa0, ub0, z);
        pm = MFMA_BF16(wa1, ub1, pm);
        int m0 = mt * 16 + quad * 4, dd = nt * 16 + l16;
        #pragma unroll
        for (int r = 0; r < 4; ++r) {
            D0buf[(size_t)chunk * 1024 + (m0 + r) * 32 + dd] = d0[r];
            Pbuf[(size_t)chunk * 1024 + (m0 + r) * 32 + dd] =
                pm[r] + ((m0 + r) == dd ? 1.f : 0.f);
        }
    }
}

// ---------------------------------------------------------------------------
// scan_states: per (b,h), sequential scan over 64 chunks (fp32).
// Thread (m, j4): owns Z[m][j4..j4+3]. P-row in registers, prefetched one
// chunk ahead; Zs read as ds_read_b128 (32 per thread per chunk).
// ---------------------------------------------------------------------------
__global__ __launch_bounds__(256) void scan_states(
    const float* __restrict__ Pbuf, const float* __restrict__ D0buf,
    float* __restrict__ Z0buf)
{
    const int bh = blockIdx.x;
    const int tid = threadIdx.x;
    const int m = tid >> 3;            // 0..31
    const int j4 = (tid & 7) << 2;     // 0,4,...,28
    __shared__ __align__(16) float Zs[32][36];

    float4 zcur = make_float4(0.f, 0.f, 0.f, 0.f);
    *(float4*)&Zs[m][j4] = zcur;

    // prefetch chunk 0
    size_t cb = (size_t)bh * 64 * 1024;
    float4 pnext[8];
    #pragma unroll
    for (int i = 0; i < 8; ++i)
        pnext[i] = *(const float4*)&Pbuf[cb + m * 32 + i * 4];
    float4 dnext = *(const float4*)&D0buf[cb + m * 32 + j4];
    __syncthreads();

    for (int c = 0; c < NCHUNK; ++c) {
        float4 pcur[8];
        #pragma unroll
        for (int i = 0; i < 8; ++i) pcur[i] = pnext[i];
        float4 dcur = dnext;
        size_t cbn = cb + 1024;
        if (c + 1 < NCHUNK) {
            #pragma unroll
            for (int i = 0; i < 8; ++i)
                pnext[i] = *(const float4*)&Pbuf[cbn + m * 32 + i * 4];
            dnext = *(const float4*)&D0buf[cbn + m * 32 + j4];
        }
        // Z0 (state BEFORE chunk c) from register
        *(float4*)&Z0buf[cb + m * 32 + j4] = zcur;

        // znew[m][j4..] = sum_mp P[m][mp] * Zs[mp][j4..] + D0
        float4 acc = dcur;
        #pragma unroll
        for (int i = 0; i < 8; ++i) {
            float pv[4] = {pcur[i].x, pcur[i].y, pcur[i].z, pcur[i].w};
            #pragma unroll
            for (int t = 0; t < 4; ++t) {
                float4 zrow = *(const float4*)&Zs[i * 4 + t][j4];
                acc.x = fmaf(pv[t], zrow.x, acc.x);
                acc.y = fmaf(pv[t], zrow.y, acc.y);
                acc.z = fmaf(pv[t], zrow.z, acc.z);
                acc.w = fmaf(pv[t], zrow.w, acc.w);
            }
        }
        __syncthreads();
        zcur = acc;
        *(float4*)&Zs[m][j4] = zcur;
        __syncthreads();
        cb = cbn;
    }
}

// ---------------------------------------------------------------------------
// chunk_out: O = (QZ0^T + tril(QK^T)V - tril(Q(Rt+UZ0)^T)W) * exp(g), bf16 out
// ---------------------------------------------------------------------------
__global__ __launch_bounds__(256) void chunk_out(
    const unsigned short* __restrict__ qb, const unsigned short* __restrict__ kb,
    const unsigned short* __restrict__ vb, const unsigned short* __restrict__ wb,
    const unsigned short* __restrict__ ub, const unsigned short* __restrict__ rtb,
    const float* __restrict__ Z0buf, const float* __restrict__ gb,
    unsigned short* __restrict__ res_bf)
{
    const int chunk = blockIdx.x;
    const int bh = chunk >> 6, c = chunk & 63;
    const int b = bh >> 3, h = bh & 7;
    const int row0 = b * TT + c * 64;
    const int tid = threadIdx.x;
    const int wave = tid >> 6, lane = tid & 63;
    const int quad = lane >> 4, l16 = lane & 15;

    __shared__ __align__(16) unsigned short Qb[2048], Kb[2048], Vb[2048], Wb[2048];
    __shared__ __align__(16) unsigned short Ub[2048], Rb[2048], S2[2048];
    __shared__ __align__(16) unsigned short A1m[4096], nA2m[4096];
    __shared__ __align__(16) unsigned short VT[2048], WT[2048];
    __shared__ __align__(16) unsigned short Z0b[1024], Z0T[1024];
    __shared__ float gc[64];

    const size_t cbase = (size_t)chunk * 2048;
    {
        int o = tid * 8;
        *(s16x8*)&Qb[o] = *(const s16x8*)&qb[cbase + o];
        *(s16x8*)&Kb[o] = *(const s16x8*)&kb[cbase + o];
        *(s16x8*)&Vb[o] = *(const s16x8*)&vb[cbase + o];
        *(s16x8*)&Wb[o] = *(const s16x8*)&wb[cbase + o];
        *(s16x8*)&Ub[o] = *(const s16x8*)&ub[cbase + o];
        *(s16x8*)&Rb[o] = *(const s16x8*)&rtb[cbase + o];
    }
    {
        #pragma unroll
        for (int j = 0; j < 4; ++j) {
            int e = tid * 4 + j;
            float z = Z0buf[(size_t)chunk * 1024 + e];
            unsigned short zb = f2bf(z);
            Z0b[e] = zb;
            Z0T[(e & 31) * 32 + (e >> 5)] = zb;
        }
    }
    if (tid < 64) gc[tid] = gb[(size_t)chunk * 64 + tid];
    __syncthreads();

    // transposes VT/WT [32][64]
    {
        int m = tid >> 3, i0 = (tid & 7) * 8;
        s16x8 a, b2;
        #pragma unroll
        for (int j = 0; j < 8; ++j) {
            a[j]  = (short)Vb[(i0 + j) * 32 + m];
            b2[j] = (short)Wb[(i0 + j) * 32 + m];
        }
        *(s16x8*)&VT[m * 64 + i0] = a;
        *(s16x8*)&WT[m * 64 + i0] = b2;
    }
    // S2 = Rt + U Z0
    {
        s16x8 af = *(const s16x8*)&Ub[(wave * 16 + l16) * 32 + quad * 8];
        #pragma unroll
        for (int dt = 0; dt < 2; ++dt) {
            s16x8 bf_ = *(const s16x8*)&Z0T[(dt * 16 + l16) * 32 + quad * 8];
            f32x4 z = {};
            f32x4 acc = MFMA_BF16(af, bf_, z);
            #pragma unroll
            for (int r = 0; r < 4; ++r) {
                int j = wave * 16 + quad * 4 + r;
                int d = dt * 16 + l16;
                float s2 = acc[r] + bf2f(Rb[j * 32 + d]);
                S2[j * 32 + d] = f2bf(s2);
            }
        }
    }
    __syncthreads();

    // A1 = tril(QK^T), nA2 = -tril(Q S2^T)   (inclusive diag)
    {
        s16x8 qf = *(const s16x8*)&Qb[(wave * 16 + l16) * 32 + quad * 8];
        #pragma unroll
        for (int jt = 0; jt < 4; ++jt) {
            s16x8 kf = *(const s16x8*)&Kb[(jt * 16 + l16) * 32 + quad * 8];
            s16x8 sf = *(const s16x8*)&S2[(jt * 16 + l16) * 32 + quad * 8];
            f32x4 z = {};
            f32x4 a1 = MFMA_BF16(qf, kf, z);
            f32x4 a2 = MFMA_BF16(qf, sf, z);
            #pragma unroll
            for (int r = 0; r < 4; ++r) {
                int t = wave * 16 + quad * 4 + r;
                int j = jt * 16 + l16;
                bool keep = (j <= t);
                A1m[t * 64 + j]  = keep ? f2bf(a1[r]) : (unsigned short)0;
                nA2m[t * 64 + j] = keep ? f2bf(-a2[r]) : (unsigned short)0;
            }
        }
    }
    __syncthreads();

    // O = Q Z0^T + A1m V + nA2m W ; scale exp(g); store bf16
    {
        s16x8 qf = *(const s16x8*)&Qb[(wave * 16 + l16) * 32 + quad * 8];
        s16x8 p0 = *(const s16x8*)&A1m[(wave * 16 + l16) * 64 + quad * 8];
        s16x8 p1 = *(const s16x8*)&A1m[(wave * 16 + l16) * 64 + 32 + quad * 8];
        s16x8 m0 = *(const s16x8*)&nA2m[(wave * 16 + l16) * 64 + quad * 8];
        s16x8 m1 = *(const s16x8*)&nA2m[(wave * 16 + l16) * 64 + 32 + quad * 8];
        #pragma unroll
        for (int mt = 0; mt < 2; ++mt) {
            s16x8 zf = *(const s16x8*)&Z0b[(mt * 16 + l16) * 32 + quad * 8];
            s16x8 v0 = *(const s16x8*)&VT[(mt * 16 + l16) * 64 + quad * 8];
            s16x8 v1 = *(const s16x8*)&VT[(mt * 16 + l16) * 64 + 32 + quad * 8];
            s16x8 w0 = *(const s16x8*)&WT[(mt * 16 + l16) * 64 + quad * 8];
            s16x8 w1 = *(const s16x8*)&WT[(mt * 16 + l16) * 64 + 32 + quad * 8];
            f32x4 z = {};
            f32x4 acc = MFMA_BF16(qf, zf, z);
            acc = MFMA_BF16(p0, v0, acc);
            acc = MFMA_BF16(p1, v1, acc);
            acc = MFMA_BF16(m0, w0, acc);
            acc = MFMA_BF16(m1, w1, acc);
            #pragma unroll
            for (int r = 0; r < 4; ++r) {
                int t = wave * 16 + quad * 4 + r;
                int m = mt * 16 + l16;
                float e = expf(gc[t]);
                res_bf[(size_t)(row0 + t) * 256 + h * 32 + m] = f2bf(acc[r] * e);
            }
        }
    }
}

// ---------------------------------------------------------------------------
extern "C" void kernel_launch(void* const* d_in, const int* in_sizes, int n_in,
                              void* d_out, int out_size, void* d_ws, size_t ws_size,
                              hipStream_t stream)
{
    const float* x     = (const float*)d_in[0];
    const float* Wq    = (const float*)d_in[1];
    const float* Wk    = (const float*)d_in[2];
    const float* Wv    = (const float*)d_in[3];
    const float* Ww    = (const float*)d_in[4];
    const float* Wbeta = (const float*)d_in[5];
    const float* bbeta = (const float*)d_in[6];
    const float* Wg    = (const float*)d_in[7];
    const float* bg    = (const float*)d_in[8];
    const float* Wo    = (const float*)d_in[9];
    float* out = (float*)d_out;

    unsigned short* x_bf       = (unsigned short*)d_ws;           // 8,388,608
    unsigned short* stacked_bf = x_bf + (size_t)NROW * HID;       // 589,824
    unsigned short* Wo_bf      = stacked_bf + (size_t)NPAD * HID; // 131,072
    unsigned short* qb  = Wo_bf + (size_t)HID * 256;              // 4,194,304 each
    unsigned short* kb  = qb + (size_t)NROW * 256;
    unsigned short* vb  = kb + (size_t)NROW * 256;
    unsigned short* wbv = vb + (size_t)NROW * 256;
    unsigned short* ub  = wbv + (size_t)NROW * 256;
    unsigned short* rtb = ub + (size_t)NROW * 256;
    unsigned short* res_bf = rtb + (size_t)NROW * 256;
    float* betab = (float*)(res_bf + (size_t)NROW * 256);         // 131,072 f
    float* gb    = betab + (size_t)NROW * 8;
    float* D0buf = gb + (size_t)NROW * 8;                         // 2,097,152 f each
    float* Pbuf  = D0buf + (size_t)2048 * 1024;
    float* Z0buf = Pbuf + (size_t)2048 * 1024;

    // 1. casts + weight concat
    cast_bf16<<<(NROW * HID / 4 + 255) / 256, 256, 0, stream>>>(x, x_bf, NROW * HID / 4);
    cast_bf16<<<(HID * 256 / 4 + 255) / 256, 256, 0, stream>>>(Wo, Wo_bf, HID * 256 / 4);
    concat_w_bf<<<(NPAD * HID + 255) / 256, 256, 0, stream>>>(Wq, Wk, Wv, Ww, Wbeta, Wg, stacked_bf);

    // 2. projection GEMM -> head-major bf16 q/k/v/w + fp32 beta/g
    gemm_proj<<<dim3(NROW / 128, NPAD / 128), 256, 0, stream>>>(
        x_bf, stacked_bf, qb, kb, vb, wbv, betab, gb, bbeta, bg);

    // 3. chunked delta-rule precompute (MFMA)
    chunk_pre<<<2048, 256, 0, stream>>>(kb, vb, wbv, betab, ub, rtb, D0buf, Pbuf);

    // 4. chunk-state scan (register-P, prefetched, b128 LDS reads)
    scan_states<<<32, 256, 0, stream>>>(Pbuf, D0buf, Z0buf);

    // 5. Z-dependent output terms (MFMA, writes bf16 res)
    chunk_out<<<2048, 256, 0, stream>>>(qb, kb, vb, wbv, ub, rtb, Z0buf, gb, res_bf);

    // 6. output GEMM: out = res @ Wo^T
    gemm_out<<<dim3(NROW / 128, HID / 128), 256, 0, stream>>>(res_bf, Wo_bf, out);
}

// Round 7
// 292.540 us; speedup vs baseline: 9.0011x; 1.0020x over previous
//
#include <hip/hip_runtime.h>
#include <hip/hip_bf16.h>
#include <math.h>

// Problem constants
#define BATCH 4
#define TT 4096
#define HID 512
#define NH 8
#define HD 32
#define NROW (BATCH * TT)       // 16384
#define NPAD 1152               // padded col count for 128-wide MFMA tiles
#define QSCALE 0.17677669529663687f  // 32^-0.5
#define NCHUNK 64               // chunks per (b,h); chunk length 64

using s16x8 = __attribute__((ext_vector_type(8))) short;
using f32x4 = __attribute__((ext_vector_type(4))) float;

#define MFMA_BF16(a, b, c) __builtin_amdgcn_mfma_f32_16x16x32_bf16((a), (b), (c), 0, 0, 0)

__device__ __forceinline__ unsigned short f2bf(float v) {
    __hip_bfloat16 h = __float2bfloat16(v);
    unsigned short u;
    __builtin_memcpy(&u, &h, 2);
    return u;
}
__device__ __forceinline__ float bf2f(unsigned short u) {
    unsigned int x = ((unsigned int)u) << 16;
    float f;
    __builtin_memcpy(&f, &x, 4);
    return f;
}
// async global->LDS, 16B per lane; LDS dest = wave-uniform base + lane*16
__device__ __forceinline__ void gload_lds16(const unsigned short* g, unsigned short* l) {
    __builtin_amdgcn_global_load_lds(
        (const __attribute__((address_space(1))) void*)g,
        (__attribute__((address_space(3))) void*)l, 16, 0, 0);
}

// ---------------------------------------------------------------------------
// cast fp32 -> bf16, 4 elements per thread
// ---------------------------------------------------------------------------
__global__ __launch_bounds__(256) void cast_bf16(
    const float* __restrict__ src, unsigned short* __restrict__ dst, int n4)
{
    int i = blockIdx.x * 256 + threadIdx.x;
    if (i >= n4) return;
    float4 v = ((const float4*)src)[i];
    ushort4 o;
    o.x = f2bf(v.x); o.y = f2bf(v.y); o.z = f2bf(v.z); o.w = f2bf(v.w);
    ((ushort4*)dst)[i] = o;
}

// ---------------------------------------------------------------------------
// concat weights into stacked bf16 [1152][512]; fold q-scale; zero pad rows
// ---------------------------------------------------------------------------
__global__ __launch_bounds__(256) void concat_w_bf(
    const float* __restrict__ Wq, const float* __restrict__ Wk,
    const float* __restrict__ Wv, const float* __restrict__ Ww,
    const float* __restrict__ Wbeta, const float* __restrict__ Wg,
    unsigned short* __restrict__ dst)
{
    int o = blockIdx.x * 256 + threadIdx.x;   // < 1152*512
    if (o >= NPAD * HID) return;
    int r = o >> 9;                           // /512
    float v;
    if      (r < 256)  v = Wq[o] * QSCALE;
    else if (r < 512)  v = Wk[o - 256 * 512];
    else if (r < 768)  v = Wv[o - 512 * 512];
    else if (r < 1024) v = Ww[o - 768 * 512];
    else if (r < 1032) v = Wbeta[o - 1024 * 512];
    else if (r < 1040) v = Wg[o - 1032 * 512];
    else               v = 0.0f;
    dst[o] = f2bf(v);
}

// ---------------------------------------------------------------------------
// Projection GEMM (bf16 MFMA): [16384,512] x [1152,512]^T.
// global_load_lds staging; LDS-transposed bf16 epilogue for q/k/v/w blocks,
// scalar beta/g epilogue for the last col-block.
// ---------------------------------------------------------------------------
__global__ __launch_bounds__(256) void gemm_proj(
    const unsigned short* __restrict__ A, const unsigned short* __restrict__ B,
    unsigned short* __restrict__ qb, unsigned short* __restrict__ kb,
    unsigned short* __restrict__ vb, unsigned short* __restrict__ wbv,
    float* __restrict__ betab, float* __restrict__ gb,
    const float* __restrict__ bbeta, const float* __restrict__ bg)
{
    __shared__ __align__(16) unsigned short smem[128 * 136];   // 34 KB (union)
    unsigned short* As = smem;            // 128*32 shorts
    unsigned short* Bs = smem + 4096;     // 128*32 shorts
    unsigned short* Cs = smem;            // epilogue tile, stride 136

    const int tid = threadIdx.x;
    const int wave = tid >> 6, lane = tid & 63;
    const int quad = lane >> 4, l16 = lane & 15;
    const int wr = wave & 1, wc = wave >> 1;
    const int r0 = blockIdx.x * 128;
    const int c0 = blockIdx.y * 128;
    const int K = HID;

    f32x4 acc[4][4] = {};

    for (int k0 = 0; k0 < K; k0 += 32) {
        __syncthreads();
        #pragma unroll
        for (int i = 0; i < 2; ++i) {
            int slot = wave * 128 + i * 64 + lane;
            int row = slot >> 2, kq = slot & 3;
            gload_lds16(&A[(size_t)(r0 + row) * K + k0 + kq * 8], &As[(wave * 128 + i * 64) * 8]);
            gload_lds16(&B[(size_t)(c0 + row) * K + k0 + kq * 8], &Bs[(wave * 128 + i * 64) * 8]);
        }
        __syncthreads();
        s16x8 af[4], bf[4];
        #pragma unroll
        for (int mi = 0; mi < 4; ++mi)
            af[mi] = *(const s16x8*)&As[(wr * 64 + mi * 16 + l16) * 32 + quad * 8];
        #pragma unroll
        for (int ni = 0; ni < 4; ++ni)
            bf[ni] = *(const s16x8*)&Bs[(wc * 64 + ni * 16 + l16) * 32 + quad * 8];
        #pragma unroll
        for (int mi = 0; mi < 4; ++mi)
            #pragma unroll
            for (int ni = 0; ni < 4; ++ni)
                acc[mi][ni] = MFMA_BF16(af[mi], bf[ni], acc[mi][ni]);
    }

    if (blockIdx.y < 8) {
        // ---- q/k/v/w: LDS transpose + coalesced 16B stores ----
        __syncthreads();
        #pragma unroll
        for (int mi = 0; mi < 4; ++mi)
            #pragma unroll
            for (int ni = 0; ni < 4; ++ni) {
                int col = wc * 64 + ni * 16 + l16;
                #pragma unroll
                for (int r = 0; r < 4; ++r) {
                    int row = wr * 64 + mi * 16 + quad * 4 + r;
                    Cs[row * 136 + col] = f2bf(acc[mi][ni][r]);
                }
            }
        __syncthreads();
        const int sub = blockIdx.y >> 1;
        unsigned short* dst = (sub == 0) ? qb : (sub == 1) ? kb : (sub == 2) ? vb : wbv;
        const int hh0 = (blockIdx.y & 1) * 4;
        const int bb = r0 >> 12, t0 = r0 & 4095;
        #pragma unroll
        for (int u = 0; u < 2; ++u) {
            int unit = tid + u * 256;          // 0..511
            int grp = unit >> 7, row = unit & 127;
            size_t gbase = ((size_t)(bb * 8 + hh0 + grp) * 4096 + t0 + row) * 32;
            #pragma unroll
            for (int i = 0; i < 4; ++i) {
                s16x8 v = *(const s16x8*)&Cs[row * 136 + grp * 32 + i * 8];
                *(s16x8*)&dst[gbase + i * 8] = v;
            }
        }
    } else {
        // ---- beta/g columns: scalar epilogue with transcendentals ----
        #pragma unroll
        for (int mi = 0; mi < 4; ++mi) {
            #pragma unroll
            for (int ni = 0; ni < 4; ++ni) {
                int col = c0 + wc * 64 + ni * 16 + l16;
                if (col >= 1040) continue;
                #pragma unroll
                for (int r = 0; r < 4; ++r) {
                    int row = r0 + wr * 64 + mi * 16 + quad * 4 + r;
                    int bb = row >> 12, t = row & 4095;
                    float v = acc[mi][ni][r];
                    if (col < 1032) {
                        float z = v + bbeta[col - 1024];
                        betab[(size_t)(bb * 8 + col - 1024) * 4096 + t] = 2.0f / (1.0f + expf(-z));
                    } else {
                        float z = v + bg[col - 1032];
                        gb[(size_t)(bb * 8 + col - 1032) * 4096 + t] =
                            fminf(z, 0.0f) - log1pf(expf(-fabsf(z)));
                    }
                }
            }
        }
    }
}

// ---------------------------------------------------------------------------
// Output GEMM (bf16 MFMA): out[16384,512] = res_bf[16384,256] @ Wo_bf[512,256]^T
// ---------------------------------------------------------------------------
__global__ __launch_bounds__(256) void gemm_out(
    const unsigned short* __restrict__ A, const unsigned short* __restrict__ B,
    float* __restrict__ C)
{
    __shared__ __align__(16) unsigned short As[128 * 32];
    __shared__ __align__(16) unsigned short Bs[128 * 32];
    const int tid = threadIdx.x;
    const int wave = tid >> 6, lane = tid & 63;
    const int quad = lane >> 4, l16 = lane & 15;
    const int wr = wave & 1, wc = wave >> 1;
    const int r0 = blockIdx.x * 128;
    const int c0 = blockIdx.y * 128;
    const int K = 256;

    f32x4 acc[4][4] = {};

    for (int k0 = 0; k0 < K; k0 += 32) {
        __syncthreads();
        #pragma unroll
        for (int i = 0; i < 2; ++i) {
            int slot = wave * 128 + i * 64 + lane;
            int row = slot >> 2, kq = slot & 3;
            gload_lds16(&A[(size_t)(r0 + row) * K + k0 + kq * 8], &As[(wave * 128 + i * 64) * 8]);
            gload_lds16(&B[(size_t)(c0 + row) * K + k0 + kq * 8], &Bs[(wave * 128 + i * 64) * 8]);
        }
        __syncthreads();
        s16x8 af[4], bf[4];
        #pragma unroll
        for (int mi = 0; mi < 4; ++mi)
            af[mi] = *(const s16x8*)&As[(wr * 64 + mi * 16 + l16) * 32 + quad * 8];
        #pragma unroll
        for (int ni = 0; ni < 4; ++ni)
            bf[ni] = *(const s16x8*)&Bs[(wc * 64 + ni * 16 + l16) * 32 + quad * 8];
        #pragma unroll
        for (int mi = 0; mi < 4; ++mi)
            #pragma unroll
            for (int ni = 0; ni < 4; ++ni)
                acc[mi][ni] = MFMA_BF16(af[mi], bf[ni], acc[mi][ni]);
    }

    #pragma unroll
    for (int mi = 0; mi < 4; ++mi)
        #pragma unroll
        for (int ni = 0; ni < 4; ++ni) {
            int col = c0 + wc * 64 + ni * 16 + l16;
            #pragma unroll
            for (int r = 0; r < 4; ++r) {
                int row = r0 + wr * 64 + mi * 16 + quad * 4 + r;
                C[(size_t)row * HID + col] = acc[mi][ni][r];
            }
        }
}

// ---------------------------------------------------------------------------
// chunk_pre: per-chunk WY precompute via MFMA. One block (256 thr) per chunk.
// ---------------------------------------------------------------------------
__global__ __launch_bounds__(256) void chunk_pre(
    const unsigned short* __restrict__ kb, const unsigned short* __restrict__ vb,
    unsigned short* __restrict__ wb, const float* __restrict__ betab,
    unsigned short* __restrict__ ub, unsigned short* __restrict__ rtb,
    float* __restrict__ D0buf, float* __restrict__ Pbuf)
{
    const int chunk = blockIdx.x;
    const int tid = threadIdx.x;
    const int wave = tid >> 6, lane = tid & 63;
    const int quad = lane >> 4, l16 = lane & 15;

    __shared__ __align__(16) unsigned short Kb[2048], Vb[2048], Wb[2048];
    __shared__ __align__(16) unsigned short KT[2048], VT[2048], WT[2048];
    __shared__ __align__(16) unsigned short Pbf[4096], nUT[2048], nRT[2048];
    __shared__ float G[64][66];
    __shared__ __align__(16) float X[64][68];
    __shared__ float betac[64], wn[64];

    const size_t cbase = (size_t)chunk * 2048;

    {
        int o = tid * 8;
        *(s16x8*)&Kb[o] = *(const s16x8*)&kb[cbase + o];
        *(s16x8*)&Vb[o] = *(const s16x8*)&vb[cbase + o];
        *(s16x8*)&Wb[o] = *(const s16x8*)&wb[cbase + o];
    }
    if (tid < 64) betac[tid] = betab[(size_t)chunk * 64 + tid];
    __syncthreads();

    // normalize w rows
    if (tid < 64) {
        float ss = 0.f;
        #pragma unroll
        for (int i = 0; i < 32; ++i) { float w = bf2f(Wb[tid * 32 + i]); ss = fmaf(w, w, ss); }
        wn[tid] = 1.f / (sqrtf(ss) + 1e-6f);
    }
    __syncthreads();
    {
        int o = tid * 8;
        float s = wn[tid >> 2];
        s16x8 wv = *(s16x8*)&Wb[o];
        s16x8 ov;
        #pragma unroll
        for (int j = 0; j < 8; ++j) ov[j] = (short)f2bf(bf2f((unsigned short)wv[j]) * s);
        *(s16x8*)&Wb[o] = ov;
        *(s16x8*)&wb[cbase + o] = ov;      // normalized w for chunk_out
    }
    __syncthreads();

    // transposed bf16 tiles KT/VT/WT [32][64]
    {
        int m = tid >> 3, i0 = (tid & 7) * 8;
        s16x8 a, b2, c2;
        #pragma unroll
        for (int j = 0; j < 8; ++j) {
            a[j]  = (short)Kb[(i0 + j) * 32 + m];
            b2[j] = (short)Vb[(i0 + j) * 32 + m];
            c2[j] = (short)Wb[(i0 + j) * 32 + m];
        }
        *(s16x8*)&KT[m * 64 + i0] = a;
        *(s16x8*)&VT[m * 64 + i0] = b2;
        *(s16x8*)&WT[m * 64 + i0] = c2;
    }
    // G = beta*W W^T (fp32); Pbf = strict-tril(beta*W V^T) (bf16)
    {
        s16x8 af = *(const s16x8*)&Wb[(wave * 16 + l16) * 32 + quad * 8];
        #pragma unroll
        for (int jt = 0; jt < 4; ++jt) {
            s16x8 bw = *(const s16x8*)&Wb[(jt * 16 + l16) * 32 + quad * 8];
            s16x8 bv = *(const s16x8*)&Vb[(jt * 16 + l16) * 32 + quad * 8];
            f32x4 z = {};
            f32x4 aG = MFMA_BF16(af, bw, z);
            f32x4 aP = MFMA_BF16(af, bv, z);
            #pragma unroll
            for (int r = 0; r < 4; ++r) {
                int t = wave * 16 + quad * 4 + r;
                int j = jt * 16 + l16;
                float bt = betac[t];
                G[t][j] = bt * aG[r];
                Pbf[t * 64 + j] = (j < t) ? f2bf(bt * aP[r]) : (unsigned short)0;
            }
        }
    }
    __syncthreads();

    // RHS: X[:,0:32] = beta*W ; X[:,32:64] = Pbf @ K  (via KT)
    {
        int r = tid >> 2, cc0 = (tid & 3) * 8;
        float bt = betac[r];
        s16x8 wv = *(const s16x8*)&Wb[r * 32 + cc0];
        #pragma unroll
        for (int j = 0; j < 8; ++j) X[r][cc0 + j] = bt * bf2f((unsigned short)wv[j]);
    }
    {
        s16x8 a0 = *(const s16x8*)&Pbf[(wave * 16 + l16) * 64 + quad * 8];
        s16x8 a1 = *(const s16x8*)&Pbf[(wave * 16 + l16) * 64 + 32 + quad * 8];
        #pragma unroll
        for (int dt = 0; dt < 2; ++dt) {
            s16x8 b0 = *(const s16x8*)&KT[(dt * 16 + l16) * 64 + quad * 8];
            s16x8 b1 = *(const s16x8*)&KT[(dt * 16 + l16) * 64 + 32 + quad * 8];
            f32x4 z = {};
            f32x4 acc = MFMA_BF16(a0, b0, z);
            acc = MFMA_BF16(a1, b1, acc);
            #pragma unroll
            for (int r = 0; r < 4; ++r)
                X[wave * 16 + quad * 4 + r][32 + dt * 16 + l16] = acc[r];
        }
    }

    // blocked forward substitution: 4 rounds of (wave-serial 16x16 diag + update)
    for (int tb = 0; tb < 64; tb += 16) {
        __syncthreads();
        if (tid < 64) {
            float xv[16];
            #pragma unroll
            for (int i = 0; i < 16; ++i) xv[i] = X[tb + i][tid];
            #pragma unroll
            for (int j = 1; j < 16; ++j)
                #pragma unroll
                for (int i = 0; i < j; ++i)
                    xv[j] = fmaf(-G[tb + j][tb + i], xv[i], xv[j]);
            #pragma unroll
            for (int i = 1; i < 16; ++i) X[tb + i][tid] = xv[i];
        }
        __syncthreads();
        if (tb < 48) {
            int n4 = (48 - tb) * 16;
            for (int idx = tid; idx < n4; idx += 256) {
                int t = tb + 16 + (idx >> 4);
                int cc = (idx & 15) * 4;
                float4 acc = *(float4*)&X[t][cc];
                #pragma unroll
                for (int i = 0; i < 16; ++i) {
                    float g = G[t][tb + i];
                    float4 xs = *(const float4*)&X[tb + i][cc];
                    acc.x = fmaf(-g, xs.x, acc.x);
                    acc.y = fmaf(-g, xs.y, acc.y);
                    acc.z = fmaf(-g, xs.z, acc.z);
                    acc.w = fmaf(-g, xs.w, acc.w);
                }
                *(float4*)&X[t][cc] = acc;
            }
        }
    }
    __syncthreads();

    // write U,Rt bf16 global; build negated transposed tiles nUT,nRT
    {
        int r = tid >> 2, c8 = (tid & 3) * 8;
        s16x8 uv, rv;
        #pragma unroll
        for (int j = 0; j < 8; ++j) {
            uv[j] = (short)f2bf(X[r][c8 + j]);
            rv[j] = (short)f2bf(X[r][32 + c8 + j]);
        }
        *(s16x8*)&ub[cbase + r * 32 + c8] = uv;
        *(s16x8*)&rtb[cbase + r * 32 + c8] = rv;
    }
    {
        int d = tid >> 3, i0 = (tid & 7) * 8;
        s16x8 u2, r2;
        #pragma unroll
        for (int j = 0; j < 8; ++j) {
            u2[j] = (short)f2bf(-X[i0 + j][d]);
            r2[j] = (short)f2bf(-X[i0 + j][32 + d]);
        }
        *(s16x8*)&nUT[d * 64 + i0] = u2;
        *(s16x8*)&nRT[d * 64 + i0] = r2;
    }
    __syncthreads();

    // D0 = V^T K - W^T Rt ; Pmat = I - W^T U   (one 16x16 tile per wave)
    {
        int mt = wave >> 1, nt = wave & 1;
        s16x8 va0 = *(const s16x8*)&VT[(mt * 16 + l16) * 64 + quad * 8];
        s16x8 va1 = *(const s16x8*)&VT[(mt * 16 + l16) * 64 + 32 + quad * 8];
        s16x8 wa0 = *(const s16x8*)&WT[(mt * 16 + l16) * 64 + quad * 8];
        s16x8 wa1 = *(const s16x8*)&WT[(mt * 16 + l16) * 64 + 32 + quad * 8];
        s16x8 kb0 = *(const s16x8*)&KT[(nt * 16 + l16) * 64 + quad * 8];
        s16x8 kb1 = *(const s16x8*)&KT[(nt * 16 + l16) * 64 + 32 + quad * 8];
        s16x8 rb0 = *(const s16x8*)&nRT[(nt * 16 + l16) * 64 + quad * 8];
        s16x8 rb1 = *(const s16x8*)&nRT[(nt * 16 + l16) * 64 + 32 + quad * 8];
        s16x8 ub0 = *(const s16x8*)&nUT[(nt * 16 + l16) * 64 + quad * 8];
        s16x8 ub1 = *(const s16x8*)&nUT[(nt * 16 + l16) * 64 + 32 + quad * 8];
        f32x4 z = {};
        f32x4 d0 = MFMA_BF16(va0, kb0, z);
        d0 = MFMA_BF16(va1, kb1, d0);
        d0 = MFMA_BF16(wa0, rb0, d0);
        d0 = MFMA_BF16(wa1, rb1, d0);
        f32x4 pm = MFMA_BF16(wa0, ub0, z);
        pm = MFMA_BF16(wa1, ub1, pm);
        int m0 = mt * 16 + quad * 4, dd = nt * 16 + l16;
        #pragma unroll
        for (int r = 0; r < 4; ++r) {
            D0buf[(size_t)chunk * 1024 + (m0 + r) * 32 + dd] = d0[r];
            Pbuf[(size_t)chunk * 1024 + (m0 + r) * 32 + dd] =
                pm[r] + ((m0 + r) == dd ? 1.f : 0.f);
        }
    }
}

// ---------------------------------------------------------------------------
// scan_states: per (b,h), sequential scan over 64 chunks (fp32).
// Thread (m, j4): owns Z[m][j4..j4+3]. P-row in registers, prefetched one
// chunk ahead; Zs read as ds_read_b128 (32 per thread per chunk).
// ---------------------------------------------------------------------------
__global__ __launch_bounds__(256) void scan_states(
    const float* __restrict__ Pbuf, const float* __restrict__ D0buf,
    float* __restrict__ Z0buf)
{
    const int bh = blockIdx.x;
    const int tid = threadIdx.x;
    const int m = tid >> 3;            // 0..31
    const int j4 = (tid & 7) << 2;     // 0,4,...,28
    __shared__ __align__(16) float Zs[32][36];

    float4 zcur = make_float4(0.f, 0.f, 0.f, 0.f);
    *(float4*)&Zs[m][j4] = zcur;

    // prefetch chunk 0
    size_t cb = (size_t)bh * 64 * 1024;
    float4 pnext[8];
    #pragma unroll
    for (int i = 0; i < 8; ++i)
        pnext[i] = *(const float4*)&Pbuf[cb + m * 32 + i * 4];
    float4 dnext = *(const float4*)&D0buf[cb + m * 32 + j4];
    __syncthreads();

    for (int c = 0; c < NCHUNK; ++c) {
        float4 pcur[8];
        #pragma unroll
        for (int i = 0; i < 8; ++i) pcur[i] = pnext[i];
        float4 dcur = dnext;
        size_t cbn = cb + 1024;
        if (c + 1 < NCHUNK) {
            #pragma unroll
            for (int i = 0; i < 8; ++i)
                pnext[i] = *(const float4*)&Pbuf[cbn + m * 32 + i * 4];
            dnext = *(const float4*)&D0buf[cbn + m * 32 + j4];
        }
        // Z0 (state BEFORE chunk c) from register
        *(float4*)&Z0buf[cb + m * 32 + j4] = zcur;

        // znew[m][j4..] = sum_mp P[m][mp] * Zs[mp][j4..] + D0
        float4 acc = dcur;
        #pragma unroll
        for (int i = 0; i < 8; ++i) {
            float pv[4] = {pcur[i].x, pcur[i].y, pcur[i].z, pcur[i].w};
            #pragma unroll
            for (int t = 0; t < 4; ++t) {
                float4 zrow = *(const float4*)&Zs[i * 4 + t][j4];
                acc.x = fmaf(pv[t], zrow.x, acc.x);
                acc.y = fmaf(pv[t], zrow.y, acc.y);
                acc.z = fmaf(pv[t], zrow.z, acc.z);
                acc.w = fmaf(pv[t], zrow.w, acc.w);
            }
        }
        __syncthreads();
        zcur = acc;
        *(float4*)&Zs[m][j4] = zcur;
        __syncthreads();
        cb = cbn;
    }
}

// ---------------------------------------------------------------------------
// chunk_out: O = (QZ0^T + tril(QK^T)V - tril(Q(Rt+UZ0)^T)W) * exp(g), bf16 out
// ---------------------------------------------------------------------------
__global__ __launch_bounds__(256) void chunk_out(
    const unsigned short* __restrict__ qb, const unsigned short* __restrict__ kb,
    const unsigned short* __restrict__ vb, const unsigned short* __restrict__ wb,
    const unsigned short* __restrict__ ub, const unsigned short* __restrict__ rtb,
    const float* __restrict__ Z0buf, const float* __restrict__ gb,
    unsigned short* __restrict__ res_bf)
{
    const int chunk = blockIdx.x;
    const int bh = chunk >> 6, c = chunk & 63;
    const int b = bh >> 3, h = bh & 7;
    const int row0 = b * TT + c * 64;
    const int tid = threadIdx.x;
    const int wave = tid >> 6, lane = tid & 63;
    const int quad = lane >> 4, l16 = lane & 15;

    __shared__ __align__(16) unsigned short Qb[2048], Kb[2048], Vb[2048], Wb[2048];
    __shared__ __align__(16) unsigned short Ub[2048], Rb[2048], S2[2048];
    __shared__ __align__(16) unsigned short A1m[4096], nA2m[4096];
    __shared__ __align__(16) unsigned short VT[2048], WT[2048];
    __shared__ __align__(16) unsigned short Z0b[1024], Z0T[1024];
    __shared__ float gc[64];

    const size_t cbase = (size_t)chunk * 2048;
    {
        int o = tid * 8;
        *(s16x8*)&Qb[o] = *(const s16x8*)&qb[cbase + o];
        *(s16x8*)&Kb[o] = *(const s16x8*)&kb[cbase + o];
        *(s16x8*)&Vb[o] = *(const s16x8*)&vb[cbase + o];
        *(s16x8*)&Wb[o] = *(const s16x8*)&wb[cbase + o];
        *(s16x8*)&Ub[o] = *(const s16x8*)&ub[cbase + o];
        *(s16x8*)&Rb[o] = *(const s16x8*)&rtb[cbase + o];
    }
    {
        #pragma unroll
        for (int j = 0; j < 4; ++j) {
            int e = tid * 4 + j;
            float z = Z0buf[(size_t)chunk * 1024 + e];
            unsigned short zb = f2bf(z);
            Z0b[e] = zb;
            Z0T[(e & 31) * 32 + (e >> 5)] = zb;
        }
    }
    if (tid < 64) gc[tid] = gb[(size_t)chunk * 64 + tid];
    __syncthreads();

    // transposes VT/WT [32][64]
    {
        int m = tid >> 3, i0 = (tid & 7) * 8;
        s16x8 a, b2;
        #pragma unroll
        for (int j = 0; j < 8; ++j) {
            a[j]  = (short)Vb[(i0 + j) * 32 + m];
            b2[j] = (short)Wb[(i0 + j) * 32 + m];
        }
        *(s16x8*)&VT[m * 64 + i0] = a;
        *(s16x8*)&WT[m * 64 + i0] = b2;
    }
    // S2 = Rt + U Z0
    {
        s16x8 af = *(const s16x8*)&Ub[(wave * 16 + l16) * 32 + quad * 8];
        #pragma unroll
        for (int dt = 0; dt < 2; ++dt) {
            s16x8 bf_ = *(const s16x8*)&Z0T[(dt * 16 + l16) * 32 + quad * 8];
            f32x4 z = {};
            f32x4 acc = MFMA_BF16(af, bf_, z);
            #pragma unroll
            for (int r = 0; r < 4; ++r) {
                int j = wave * 16 + quad * 4 + r;
                int d = dt * 16 + l16;
                float s2 = acc[r] + bf2f(Rb[j * 32 + d]);
                S2[j * 32 + d] = f2bf(s2);
            }
        }
    }
    __syncthreads();

    // A1 = tril(QK^T), nA2 = -tril(Q S2^T)   (inclusive diag)
    {
        s16x8 qf = *(const s16x8*)&Qb[(wave * 16 + l16) * 32 + quad * 8];
        #pragma unroll
        for (int jt = 0; jt < 4; ++jt) {
            s16x8 kf = *(const s16x8*)&Kb[(jt * 16 + l16) * 32 + quad * 8];
            s16x8 sf = *(const s16x8*)&S2[(jt * 16 + l16) * 32 + quad * 8];
            f32x4 z = {};
            f32x4 a1 = MFMA_BF16(qf, kf, z);
            f32x4 a2 = MFMA_BF16(qf, sf, z);
            #pragma unroll
            for (int r = 0; r < 4; ++r) {
                int t = wave * 16 + quad * 4 + r;
                int j = jt * 16 + l16;
                bool keep = (j <= t);
                A1m[t * 64 + j]  = keep ? f2bf(a1[r]) : (unsigned short)0;
                nA2m[t * 64 + j] = keep ? f2bf(-a2[r]) : (unsigned short)0;
            }
        }
    }
    __syncthreads();

    // O = Q Z0^T + A1m V + nA2m W ; scale exp(g); store bf16
    {
        s16x8 qf = *(const s16x8*)&Qb[(wave * 16 + l16) * 32 + quad * 8];
        s16x8 p0 = *(const s16x8*)&A1m[(wave * 16 + l16) * 64 + quad * 8];
        s16x8 p1 = *(const s16x8*)&A1m[(wave * 16 + l16) * 64 + 32 + quad * 8];
        s16x8 m0 = *(const s16x8*)&nA2m[(wave * 16 + l16) * 64 + quad * 8];
        s16x8 m1 = *(const s16x8*)&nA2m[(wave * 16 + l16) * 64 + 32 + quad * 8];
        #pragma unroll
        for (int mt = 0; mt < 2; ++mt) {
            s16x8 zf = *(const s16x8*)&Z0b[(mt * 16 + l16) * 32 + quad * 8];
            s16x8 v0 = *(const s16x8*)&VT[(mt * 16 + l16) * 64 + quad * 8];
            s16x8 v1 = *(const s16x8*)&VT[(mt * 16 + l16) * 64 + 32 + quad * 8];
            s16x8 w0 = *(const s16x8*)&WT[(mt * 16 + l16) * 64 + quad * 8];
            s16x8 w1 = *(const s16x8*)&WT[(mt * 16 + l16) * 64 + 32 + quad * 8];
            f32x4 z = {};
            f32x4 acc = MFMA_BF16(qf, zf, z);
            acc = MFMA_BF16(p0, v0, acc);
            acc = MFMA_BF16(p1, v1, acc);
            acc = MFMA_BF16(m0, w0, acc);
            acc = MFMA_BF16(m1, w1, acc);
            #pragma unroll
            for (int r = 0; r < 4; ++r) {
                int t = wave * 16 + quad * 4 + r;
                int m = mt * 16 + l16;
                float e = expf(gc[t]);
                res_bf[(size_t)(row0 + t) * 256 + h * 32 + m] = f2bf(acc[r] * e);
            }
        }
    }
}

// ---------------------------------------------------------------------------
extern "C" void kernel_launch(void* const* d_in, const int* in_sizes, int n_in,
                              void* d_out, int out_size, void* d_ws, size_t ws_size,
                              hipStream_t stream)
{
    const float* x     = (const float*)d_in[0];
    const float* Wq    = (const float*)d_in[1];
    const float* Wk    = (const float*)d_in[2];
    const float* Wv    = (const float*)d_in[3];
    const float* Ww    = (const float*)d_in[4];
    const float* Wbeta = (const float*)d_in[5];
    const float* bbeta = (const float*)d_in[6];
    const float* Wg    = (const float*)d_in[7];
    const float* bg    = (const float*)d_in[8];
    const float* Wo    = (const float*)d_in[9];
    float* out = (float*)d_out;

    unsigned short* x_bf       = (unsigned short*)d_ws;           // 8,388,608
    unsigned short* stacked_bf = x_bf + (size_t)NROW * HID;       // 589,824
    unsigned short* Wo_bf      = stacked_bf + (size_t)NPAD * HID; // 131,072
    unsigned short* qb  = Wo_bf + (size_t)HID * 256;              // 4,194,304 each
    unsigned short* kb  = qb + (size_t)NROW * 256;
    unsigned short* vb  = kb + (size_t)NROW * 256;
    unsigned short* wbv = vb + (size_t)NROW * 256;
    unsigned short* ub  = wbv + (size_t)NROW * 256;
    unsigned short* rtb = ub + (size_t)NROW * 256;
    unsigned short* res_bf = rtb + (size_t)NROW * 256;
    float* betab = (float*)(res_bf + (size_t)NROW * 256);         // 131,072 f
    float* gb    = betab + (size_t)NROW * 8;
    float* D0buf = gb + (size_t)NROW * 8;                         // 2,097,152 f each
    float* Pbuf  = D0buf + (size_t)2048 * 1024;
    float* Z0buf = Pbuf + (size_t)2048 * 1024;

    // 1. casts + weight concat
    cast_bf16<<<(NROW * HID / 4 + 255) / 256, 256, 0, stream>>>(x, x_bf, NROW * HID / 4);
    cast_bf16<<<(HID * 256 / 4 + 255) / 256, 256, 0, stream>>>(Wo, Wo_bf, HID * 256 / 4);
    concat_w_bf<<<(NPAD * HID + 255) / 256, 256, 0, stream>>>(Wq, Wk, Wv, Ww, Wbeta, Wg, stacked_bf);

    // 2. projection GEMM -> head-major bf16 q/k/v/w + fp32 beta/g
    gemm_proj<<<dim3(NROW / 128, NPAD / 128), 256, 0, stream>>>(
        x_bf, stacked_bf, qb, kb, vb, wbv, betab, gb, bbeta, bg);

    // 3. chunked delta-rule precompute (MFMA)
    chunk_pre<<<2048, 256, 0, stream>>>(kb, vb, wbv, betab, ub, rtb, D0buf, Pbuf);

    // 4. chunk-state scan (register-P, prefetched, b128 LDS reads)
    scan_states<<<32, 256, 0, stream>>>(Pbuf, D0buf, Z0buf);

    // 5. Z-dependent output terms (MFMA, writes bf16 res)
    chunk_out<<<2048, 256, 0, stream>>>(qb, kb, vb, wbv, ub, rtb, Z0buf, gb, res_bf);

    // 6. output GEMM: out = res @ Wo^T
    gemm_out<<<dim3(NROW / 128, HID / 128), 256, 0, stream>>>(res_bf, Wo_bf, out);
}

// Round 8
// 272.624 us; speedup vs baseline: 9.6586x; 1.0731x over previous
//
#include <hip/hip_runtime.h>
#include <hip/hip_bf16.h>
#include <math.h>

// Problem constants
#define BATCH 4
#define TT 4096
#define HID 512
#define NH 8
#define HD 32
#define NROW (BATCH * TT)       // 16384
#define NPAD 1152               // padded col count for 128-wide MFMA tiles
#define QSCALE 0.17677669529663687f  // 32^-0.5
#define NCHUNK 64               // chunks per (b,h); chunk length 64

using s16x8 = __attribute__((ext_vector_type(8))) short;
using f32x4 = __attribute__((ext_vector_type(4))) float;

#define MFMA_BF16(a, b, c) __builtin_amdgcn_mfma_f32_16x16x32_bf16((a), (b), (c), 0, 0, 0)

__device__ __forceinline__ unsigned short f2bf(float v) {
    __hip_bfloat16 h = __float2bfloat16(v);
    unsigned short u;
    __builtin_memcpy(&u, &h, 2);
    return u;
}
__device__ __forceinline__ float bf2f(unsigned short u) {
    unsigned int x = ((unsigned int)u) << 16;
    float f;
    __builtin_memcpy(&f, &x, 4);
    return f;
}
// async global->LDS, 16B per lane; LDS dest = wave-uniform base + lane*16
__device__ __forceinline__ void gload_lds16(const unsigned short* g, unsigned short* l) {
    __builtin_amdgcn_global_load_lds(
        (const __attribute__((address_space(1))) void*)g,
        (__attribute__((address_space(3))) void*)l, 16, 0, 0);
}

// ---------------------------------------------------------------------------
// cast fp32 -> bf16, 4 elements per thread
// ---------------------------------------------------------------------------
__global__ __launch_bounds__(256) void cast_bf16(
    const float* __restrict__ src, unsigned short* __restrict__ dst, int n4)
{
    int i = blockIdx.x * 256 + threadIdx.x;
    if (i >= n4) return;
    float4 v = ((const float4*)src)[i];
    ushort4 o;
    o.x = f2bf(v.x); o.y = f2bf(v.y); o.z = f2bf(v.z); o.w = f2bf(v.w);
    ((ushort4*)dst)[i] = o;
}

// ---------------------------------------------------------------------------
// concat weights into stacked bf16 [1152][512]; fold q-scale; zero pad rows
// ---------------------------------------------------------------------------
__global__ __launch_bounds__(256) void concat_w_bf(
    const float* __restrict__ Wq, const float* __restrict__ Wk,
    const float* __restrict__ Wv, const float* __restrict__ Ww,
    const float* __restrict__ Wbeta, const float* __restrict__ Wg,
    unsigned short* __restrict__ dst)
{
    int o = blockIdx.x * 256 + threadIdx.x;   // < 1152*512
    if (o >= NPAD * HID) return;
    int r = o >> 9;                           // /512
    float v;
    if      (r < 256)  v = Wq[o] * QSCALE;
    else if (r < 512)  v = Wk[o - 256 * 512];
    else if (r < 768)  v = Wv[o - 512 * 512];
    else if (r < 1024) v = Ww[o - 768 * 512];
    else if (r < 1032) v = Wbeta[o - 1024 * 512];
    else if (r < 1040) v = Wg[o - 1032 * 512];
    else               v = 0.0f;
    dst[o] = f2bf(v);
}

// ---------------------------------------------------------------------------
// Projection GEMM (bf16 MFMA): [16384,512] x [1152,512]^T.
// Double-buffered global_load_lds staging (1 barrier per K-step).
// LDS-transposed bf16 epilogue for q/k/v/w blocks; scalar beta/g epilogue.
// ---------------------------------------------------------------------------
__global__ __launch_bounds__(256) void gemm_proj(
    const unsigned short* __restrict__ A, const unsigned short* __restrict__ B,
    unsigned short* __restrict__ qb, unsigned short* __restrict__ kb,
    unsigned short* __restrict__ vb, unsigned short* __restrict__ wbv,
    float* __restrict__ betab, float* __restrict__ gb,
    const float* __restrict__ bbeta, const float* __restrict__ bg)
{
    // staging: 2 bufs x (A 4096 + B 4096) shorts = 32 KB; epilogue Cs 34.8 KB
    __shared__ __align__(16) unsigned short smem[128 * 136];
    unsigned short* Cs = smem;            // epilogue tile, stride 136

    const int tid = threadIdx.x;
    const int wave = tid >> 6, lane = tid & 63;
    const int quad = lane >> 4, l16 = lane & 15;
    const int wr = wave & 1, wc = wave >> 1;
    const int r0 = blockIdx.x * 128;
    const int c0 = blockIdx.y * 128;
    const int K = HID;

    f32x4 acc[4][4] = {};

    // issue one 32-wide K-slab into buffer b
    auto stage = [&](int k0, int b) {
        unsigned short* Ab = smem + b * 8192;
        unsigned short* Bb = Ab + 4096;
        #pragma unroll
        for (int i = 0; i < 2; ++i) {
            int slot = wave * 128 + i * 64 + lane;
            int row = slot >> 2, kq = slot & 3;
            gload_lds16(&A[(size_t)(r0 + row) * K + k0 + kq * 8], &Ab[(wave * 128 + i * 64) * 8]);
            gload_lds16(&B[(size_t)(c0 + row) * K + k0 + kq * 8], &Bb[(wave * 128 + i * 64) * 8]);
        }
    };

    stage(0, 0);
    for (int k0 = 0, it = 0; k0 < K; k0 += 32, ++it) {
        __syncthreads();                       // vmcnt(0): cur buf ready; prev reads done
        int cur = it & 1;
        if (k0 + 32 < K) stage(k0 + 32, cur ^ 1);
        const unsigned short* As = smem + cur * 8192;
        const unsigned short* Bs = As + 4096;
        s16x8 af[4], bf[4];
        #pragma unroll
        for (int mi = 0; mi < 4; ++mi)
            af[mi] = *(const s16x8*)&As[(wr * 64 + mi * 16 + l16) * 32 + quad * 8];
        #pragma unroll
        for (int ni = 0; ni < 4; ++ni)
            bf[ni] = *(const s16x8*)&Bs[(wc * 64 + ni * 16 + l16) * 32 + quad * 8];
        #pragma unroll
        for (int mi = 0; mi < 4; ++mi)
            #pragma unroll
            for (int ni = 0; ni < 4; ++ni)
                acc[mi][ni] = MFMA_BF16(af[mi], bf[ni], acc[mi][ni]);
    }

    if (blockIdx.y < 8) {
        // ---- q/k/v/w: LDS transpose + coalesced 16B stores ----
        __syncthreads();
        #pragma unroll
        for (int mi = 0; mi < 4; ++mi)
            #pragma unroll
            for (int ni = 0; ni < 4; ++ni) {
                int col = wc * 64 + ni * 16 + l16;
                #pragma unroll
                for (int r = 0; r < 4; ++r) {
                    int row = wr * 64 + mi * 16 + quad * 4 + r;
                    Cs[row * 136 + col] = f2bf(acc[mi][ni][r]);
                }
            }
        __syncthreads();
        const int sub = blockIdx.y >> 1;
        unsigned short* dst = (sub == 0) ? qb : (sub == 1) ? kb : (sub == 2) ? vb : wbv;
        const int hh0 = (blockIdx.y & 1) * 4;
        const int bb = r0 >> 12, t0 = r0 & 4095;
        #pragma unroll
        for (int u = 0; u < 2; ++u) {
            int unit = tid + u * 256;          // 0..511
            int grp = unit >> 7, row = unit & 127;
            size_t gbase = ((size_t)(bb * 8 + hh0 + grp) * 4096 + t0 + row) * 32;
            #pragma unroll
            for (int i = 0; i < 4; ++i) {
                s16x8 v = *(const s16x8*)&Cs[row * 136 + grp * 32 + i * 8];
                *(s16x8*)&dst[gbase + i * 8] = v;
            }
        }
    } else {
        // ---- beta/g columns: scalar epilogue with transcendentals ----
        #pragma unroll
        for (int mi = 0; mi < 4; ++mi) {
            #pragma unroll
            for (int ni = 0; ni < 4; ++ni) {
                int col = c0 + wc * 64 + ni * 16 + l16;
                if (col >= 1040) continue;
                #pragma unroll
                for (int r = 0; r < 4; ++r) {
                    int row = r0 + wr * 64 + mi * 16 + quad * 4 + r;
                    int bb = row >> 12, t = row & 4095;
                    float v = acc[mi][ni][r];
                    if (col < 1032) {
                        float z = v + bbeta[col - 1024];
                        betab[(size_t)(bb * 8 + col - 1024) * 4096 + t] = 2.0f / (1.0f + expf(-z));
                    } else {
                        float z = v + bg[col - 1032];
                        gb[(size_t)(bb * 8 + col - 1032) * 4096 + t] =
                            fminf(z, 0.0f) - log1pf(expf(-fabsf(z)));
                    }
                }
            }
        }
    }
}

// ---------------------------------------------------------------------------
// Output GEMM (bf16 MFMA): out[16384,512] = res_bf[16384,256] @ Wo_bf[512,256]^T
// Double-buffered global_load_lds staging (1 barrier per K-step).
// ---------------------------------------------------------------------------
__global__ __launch_bounds__(256) void gemm_out(
    const unsigned short* __restrict__ A, const unsigned short* __restrict__ B,
    float* __restrict__ C)
{
    __shared__ __align__(16) unsigned short smem[2 * 8192];
    const int tid = threadIdx.x;
    const int wave = tid >> 6, lane = tid & 63;
    const int quad = lane >> 4, l16 = lane & 15;
    const int wr = wave & 1, wc = wave >> 1;
    const int r0 = blockIdx.x * 128;
    const int c0 = blockIdx.y * 128;
    const int K = 256;

    f32x4 acc[4][4] = {};

    auto stage = [&](int k0, int b) {
        unsigned short* Ab = smem + b * 8192;
        unsigned short* Bb = Ab + 4096;
        #pragma unroll
        for (int i = 0; i < 2; ++i) {
            int slot = wave * 128 + i * 64 + lane;
            int row = slot >> 2, kq = slot & 3;
            gload_lds16(&A[(size_t)(r0 + row) * K + k0 + kq * 8], &Ab[(wave * 128 + i * 64) * 8]);
            gload_lds16(&B[(size_t)(c0 + row) * K + k0 + kq * 8], &Bb[(wave * 128 + i * 64) * 8]);
        }
    };

    stage(0, 0);
    for (int k0 = 0, it = 0; k0 < K; k0 += 32, ++it) {
        __syncthreads();
        int cur = it & 1;
        if (k0 + 32 < K) stage(k0 + 32, cur ^ 1);
        const unsigned short* As = smem + cur * 8192;
        const unsigned short* Bs = As + 4096;
        s16x8 af[4], bf[4];
        #pragma unroll
        for (int mi = 0; mi < 4; ++mi)
            af[mi] = *(const s16x8*)&As[(wr * 64 + mi * 16 + l16) * 32 + quad * 8];
        #pragma unroll
        for (int ni = 0; ni < 4; ++ni)
            bf[ni] = *(const s16x8*)&Bs[(wc * 64 + ni * 16 + l16) * 32 + quad * 8];
        #pragma unroll
        for (int mi = 0; mi < 4; ++mi)
            #pragma unroll
            for (int ni = 0; ni < 4; ++ni)
                acc[mi][ni] = MFMA_BF16(af[mi], bf[ni], acc[mi][ni]);
    }

    #pragma unroll
    for (int mi = 0; mi < 4; ++mi)
        #pragma unroll
        for (int ni = 0; ni < 4; ++ni) {
            int col = c0 + wc * 64 + ni * 16 + l16;
            #pragma unroll
            for (int r = 0; r < 4; ++r) {
                int row = r0 + wr * 64 + mi * 16 + quad * 4 + r;
                C[(size_t)row * HID + col] = acc[mi][ni][r];
            }
        }
}

// ---------------------------------------------------------------------------
// chunk_pre: per-chunk WY precompute via MFMA. One block (256 thr) per chunk.
// ---------------------------------------------------------------------------
__global__ __launch_bounds__(256) void chunk_pre(
    const unsigned short* __restrict__ kb, const unsigned short* __restrict__ vb,
    unsigned short* __restrict__ wb, const float* __restrict__ betab,
    unsigned short* __restrict__ ub, unsigned short* __restrict__ rtb,
    float* __restrict__ D0buf, float* __restrict__ Pbuf)
{
    const int chunk = blockIdx.x;
    const int tid = threadIdx.x;
    const int wave = tid >> 6, lane = tid & 63;
    const int quad = lane >> 4, l16 = lane & 15;

    __shared__ __align__(16) unsigned short Kb[2048], Vb[2048], Wb[2048];
    __shared__ __align__(16) unsigned short KT[2048], VT[2048], WT[2048];
    __shared__ __align__(16) unsigned short Pbf[4096], nUT[2048], nRT[2048];
    __shared__ float G[64][66];
    __shared__ __align__(16) float X[64][68];
    __shared__ float betac[64], wn[64];

    const size_t cbase = (size_t)chunk * 2048;

    {
        int o = tid * 8;
        *(s16x8*)&Kb[o] = *(const s16x8*)&kb[cbase + o];
        *(s16x8*)&Vb[o] = *(const s16x8*)&vb[cbase + o];
        *(s16x8*)&Wb[o] = *(const s16x8*)&wb[cbase + o];
    }
    if (tid < 64) betac[tid] = betab[(size_t)chunk * 64 + tid];
    __syncthreads();

    // normalize w rows
    if (tid < 64) {
        float ss = 0.f;
        #pragma unroll
        for (int i = 0; i < 32; ++i) { float w = bf2f(Wb[tid * 32 + i]); ss = fmaf(w, w, ss); }
        wn[tid] = 1.f / (sqrtf(ss) + 1e-6f);
    }
    __syncthreads();
    {
        int o = tid * 8;
        float s = wn[tid >> 2];
        s16x8 wv = *(s16x8*)&Wb[o];
        s16x8 ov;
        #pragma unroll
        for (int j = 0; j < 8; ++j) ov[j] = (short)f2bf(bf2f((unsigned short)wv[j]) * s);
        *(s16x8*)&Wb[o] = ov;
        *(s16x8*)&wb[cbase + o] = ov;      // normalized w for chunk_out
    }
    __syncthreads();

    // transposed bf16 tiles KT/VT/WT [32][64]
    {
        int m = tid >> 3, i0 = (tid & 7) * 8;
        s16x8 a, b2, c2;
        #pragma unroll
        for (int j = 0; j < 8; ++j) {
            a[j]  = (short)Kb[(i0 + j) * 32 + m];
            b2[j] = (short)Vb[(i0 + j) * 32 + m];
            c2[j] = (short)Wb[(i0 + j) * 32 + m];
        }
        *(s16x8*)&KT[m * 64 + i0] = a;
        *(s16x8*)&VT[m * 64 + i0] = b2;
        *(s16x8*)&WT[m * 64 + i0] = c2;
    }
    // G = beta*W W^T (fp32); Pbf = strict-tril(beta*W V^T) (bf16)
    {
        s16x8 af = *(const s16x8*)&Wb[(wave * 16 + l16) * 32 + quad * 8];
        #pragma unroll
        for (int jt = 0; jt < 4; ++jt) {
            s16x8 bw = *(const s16x8*)&Wb[(jt * 16 + l16) * 32 + quad * 8];
            s16x8 bv = *(const s16x8*)&Vb[(jt * 16 + l16) * 32 + quad * 8];
            f32x4 z = {};
            f32x4 aG = MFMA_BF16(af, bw, z);
            f32x4 aP = MFMA_BF16(af, bv, z);
            #pragma unroll
            for (int r = 0; r < 4; ++r) {
                int t = wave * 16 + quad * 4 + r;
                int j = jt * 16 + l16;
                float bt = betac[t];
                G[t][j] = bt * aG[r];
                Pbf[t * 64 + j] = (j < t) ? f2bf(bt * aP[r]) : (unsigned short)0;
            }
        }
    }
    __syncthreads();

    // RHS: X[:,0:32] = beta*W ; X[:,32:64] = Pbf @ K  (via KT)
    {
        int r = tid >> 2, cc0 = (tid & 3) * 8;
        float bt = betac[r];
        s16x8 wv = *(const s16x8*)&Wb[r * 32 + cc0];
        #pragma unroll
        for (int j = 0; j < 8; ++j) X[r][cc0 + j] = bt * bf2f((unsigned short)wv[j]);
    }
    {
        s16x8 a0 = *(const s16x8*)&Pbf[(wave * 16 + l16) * 64 + quad * 8];
        s16x8 a1 = *(const s16x8*)&Pbf[(wave * 16 + l16) * 64 + 32 + quad * 8];
        #pragma unroll
        for (int dt = 0; dt < 2; ++dt) {
            s16x8 b0 = *(const s16x8*)&KT[(dt * 16 + l16) * 64 + quad * 8];
            s16x8 b1 = *(const s16x8*)&KT[(dt * 16 + l16) * 64 + 32 + quad * 8];
            f32x4 z = {};
            f32x4 acc = MFMA_BF16(a0, b0, z);
            acc = MFMA_BF16(a1, b1, acc);
            #pragma unroll
            for (int r = 0; r < 4; ++r)
                X[wave * 16 + quad * 4 + r][32 + dt * 16 + l16] = acc[r];
        }
    }

    // blocked forward substitution: 4 rounds of (wave-serial 16x16 diag + update)
    for (int tb = 0; tb < 64; tb += 16) {
        __syncthreads();
        if (tid < 64) {
            float xv[16];
            #pragma unroll
            for (int i = 0; i < 16; ++i) xv[i] = X[tb + i][tid];
            #pragma unroll
            for (int j = 1; j < 16; ++j)
                #pragma unroll
                for (int i = 0; i < j; ++i)
                    xv[j] = fmaf(-G[tb + j][tb + i], xv[i], xv[j]);
            #pragma unroll
            for (int i = 1; i < 16; ++i) X[tb + i][tid] = xv[i];
        }
        __syncthreads();
        if (tb < 48) {
            int n4 = (48 - tb) * 16;
            for (int idx = tid; idx < n4; idx += 256) {
                int t = tb + 16 + (idx >> 4);
                int cc = (idx & 15) * 4;
                float4 acc = *(float4*)&X[t][cc];
                #pragma unroll
                for (int i = 0; i < 16; ++i) {
                    float g = G[t][tb + i];
                    float4 xs = *(const float4*)&X[tb + i][cc];
                    acc.x = fmaf(-g, xs.x, acc.x);
                    acc.y = fmaf(-g, xs.y, acc.y);
                    acc.z = fmaf(-g, xs.z, acc.z);
                    acc.w = fmaf(-g, xs.w, acc.w);
                }
                *(float4*)&X[t][cc] = acc;
            }
        }
    }
    __syncthreads();

    // write U,Rt bf16 global; build negated transposed tiles nUT,nRT
    {
        int r = tid >> 2, c8 = (tid & 3) * 8;
        s16x8 uv, rv;
        #pragma unroll
        for (int j = 0; j < 8; ++j) {
            uv[j] = (short)f2bf(X[r][c8 + j]);
            rv[j] = (short)f2bf(X[r][32 + c8 + j]);
        }
        *(s16x8*)&ub[cbase + r * 32 + c8] = uv;
        *(s16x8*)&rtb[cbase + r * 32 + c8] = rv;
    }
    {
        int d = tid >> 3, i0 = (tid & 7) * 8;
        s16x8 u2, r2;
        #pragma unroll
        for (int j = 0; j < 8; ++j) {
            u2[j] = (short)f2bf(-X[i0 + j][d]);
            r2[j] = (short)f2bf(-X[i0 + j][32 + d]);
        }
        *(s16x8*)&nUT[d * 64 + i0] = u2;
        *(s16x8*)&nRT[d * 64 + i0] = r2;
    }
    __syncthreads();

    // D0 = V^T K - W^T Rt ; Pmat = I - W^T U   (one 16x16 tile per wave)
    {
        int mt = wave >> 1, nt = wave & 1;
        s16x8 va0 = *(const s16x8*)&VT[(mt * 16 + l16) * 64 + quad * 8];
        s16x8 va1 = *(const s16x8*)&VT[(mt * 16 + l16) * 64 + 32 + quad * 8];
        s16x8 wa0 = *(const s16x8*)&WT[(mt * 16 + l16) * 64 + quad * 8];
        s16x8 wa1 = *(const s16x8*)&WT[(mt * 16 + l16) * 64 + 32 + quad * 8];
        s16x8 kb0 = *(const s16x8*)&KT[(nt * 16 + l16) * 64 + quad * 8];
        s16x8 kb1 = *(const s16x8*)&KT[(nt * 16 + l16) * 64 + 32 + quad * 8];
        s16x8 rb0 = *(const s16x8*)&nRT[(nt * 16 + l16) * 64 + quad * 8];
        s16x8 rb1 = *(const s16x8*)&nRT[(nt * 16 + l16) * 64 + 32 + quad * 8];
        s16x8 ub0 = *(const s16x8*)&nUT[(nt * 16 + l16) * 64 + quad * 8];
        s16x8 ub1 = *(const s16x8*)&nUT[(nt * 16 + l16) * 64 + 32 + quad * 8];
        f32x4 z = {};
        f32x4 d0 = MFMA_BF16(va0, kb0, z);
        d0 = MFMA_BF16(va1, kb1, d0);
        d0 = MFMA_BF16(wa0, rb0, d0);
        d0 = MFMA_BF16(wa1, rb1, d0);
        f32x4 pm = MFMA_BF16(wa0, ub0, z);
        pm = MFMA_BF16(wa1, ub1, pm);
        int m0 = mt * 16 + quad * 4, dd = nt * 16 + l16;
        #pragma unroll
        for (int r = 0; r < 4; ++r) {
            D0buf[(size_t)chunk * 1024 + (m0 + r) * 32 + dd] = d0[r];
            Pbuf[(size_t)chunk * 1024 + (m0 + r) * 32 + dd] =
                pm[r] + ((m0 + r) == dd ? 1.f : 0.f);
        }
    }
}

// ---------------------------------------------------------------------------
// scan_states: per (b,h), sequential scan over 64 chunks (fp32).
// ---------------------------------------------------------------------------
__global__ __launch_bounds__(256) void scan_states(
    const float* __restrict__ Pbuf, const float* __restrict__ D0buf,
    float* __restrict__ Z0buf)
{
    const int bh = blockIdx.x;
    const int tid = threadIdx.x;
    const int m = tid >> 3;            // 0..31
    const int j4 = (tid & 7) << 2;     // 0,4,...,28
    __shared__ __align__(16) float Zs[32][36];

    float4 zcur = make_float4(0.f, 0.f, 0.f, 0.f);
    *(float4*)&Zs[m][j4] = zcur;

    // prefetch chunk 0
    size_t cb = (size_t)bh * 64 * 1024;
    float4 pnext[8];
    #pragma unroll
    for (int i = 0; i < 8; ++i)
        pnext[i] = *(const float4*)&Pbuf[cb + m * 32 + i * 4];
    float4 dnext = *(const float4*)&D0buf[cb + m * 32 + j4];
    __syncthreads();

    for (int c = 0; c < NCHUNK; ++c) {
        float4 pcur[8];
        #pragma unroll
        for (int i = 0; i < 8; ++i) pcur[i] = pnext[i];
        float4 dcur = dnext;
        size_t cbn = cb + 1024;
        if (c + 1 < NCHUNK) {
            #pragma unroll
            for (int i = 0; i < 8; ++i)
                pnext[i] = *(const float4*)&Pbuf[cbn + m * 32 + i * 4];
            dnext = *(const float4*)&D0buf[cbn + m * 32 + j4];
        }
        // Z0 (state BEFORE chunk c) from register
        *(float4*)&Z0buf[cb + m * 32 + j4] = zcur;

        // znew[m][j4..] = sum_mp P[m][mp] * Zs[mp][j4..] + D0
        float4 acc = dcur;
        #pragma unroll
        for (int i = 0; i < 8; ++i) {
            float pv[4] = {pcur[i].x, pcur[i].y, pcur[i].z, pcur[i].w};
            #pragma unroll
            for (int t = 0; t < 4; ++t) {
                float4 zrow = *(const float4*)&Zs[i * 4 + t][j4];
                acc.x = fmaf(pv[t], zrow.x, acc.x);
                acc.y = fmaf(pv[t], zrow.y, acc.y);
                acc.z = fmaf(pv[t], zrow.z, acc.z);
                acc.w = fmaf(pv[t], zrow.w, acc.w);
            }
        }
        __syncthreads();
        zcur = acc;
        *(float4*)&Zs[m][j4] = zcur;
        __syncthreads();
        cb = cbn;
    }
}

// ---------------------------------------------------------------------------
// chunk_out: O = (QZ0^T + tril(QK^T)V - tril(Q(Rt+UZ0)^T)W) * exp(g), bf16 out
// ---------------------------------------------------------------------------
__global__ __launch_bounds__(256) void chunk_out(
    const unsigned short* __restrict__ qb, const unsigned short* __restrict__ kb,
    const unsigned short* __restrict__ vb, const unsigned short* __restrict__ wb,
    const unsigned short* __restrict__ ub, const unsigned short* __restrict__ rtb,
    const float* __restrict__ Z0buf, const float* __restrict__ gb,
    unsigned short* __restrict__ res_bf)
{
    const int chunk = blockIdx.x;
    const int bh = chunk >> 6, c = chunk & 63;
    const int b = bh >> 3, h = bh & 7;
    const int row0 = b * TT + c * 64;
    const int tid = threadIdx.x;
    const int wave = tid >> 6, lane = tid & 63;
    const int quad = lane >> 4, l16 = lane & 15;

    __shared__ __align__(16) unsigned short Qb[2048], Kb[2048], Vb[2048], Wb[2048];
    __shared__ __align__(16) unsigned short Ub[2048], Rb[2048], S2[2048];
    __shared__ __align__(16) unsigned short A1m[4096], nA2m[4096];
    __shared__ __align__(16) unsigned short VT[2048], WT[2048];
    __shared__ __align__(16) unsigned short Z0b[1024], Z0T[1024];
    __shared__ float gc[64];

    const size_t cbase = (size_t)chunk * 2048;
    {
        int o = tid * 8;
        *(s16x8*)&Qb[o] = *(const s16x8*)&qb[cbase + o];
        *(s16x8*)&Kb[o] = *(const s16x8*)&kb[cbase + o];
        *(s16x8*)&Vb[o] = *(const s16x8*)&vb[cbase + o];
        *(s16x8*)&Wb[o] = *(const s16x8*)&wb[cbase + o];
        *(s16x8*)&Ub[o] = *(const s16x8*)&ub[cbase + o];
        *(s16x8*)&Rb[o] = *(const s16x8*)&rtb[cbase + o];
    }
    {
        #pragma unroll
        for (int j = 0; j < 4; ++j) {
            int e = tid * 4 + j;
            float z = Z0buf[(size_t)chunk * 1024 + e];
            unsigned short zb = f2bf(z);
            Z0b[e] = zb;
            Z0T[(e & 31) * 32 + (e >> 5)] = zb;
        }
    }
    if (tid < 64) gc[tid] = gb[(size_t)chunk * 64 + tid];
    __syncthreads();

    // transposes VT/WT [32][64]
    {
        int m = tid >> 3, i0 = (tid & 7) * 8;
        s16x8 a, b2;
        #pragma unroll
        for (int j = 0; j < 8; ++j) {
            a[j]  = (short)Vb[(i0 + j) * 32 + m];
            b2[j] = (short)Wb[(i0 + j) * 32 + m];
        }
        *(s16x8*)&VT[m * 64 + i0] = a;
        *(s16x8*)&WT[m * 64 + i0] = b2;
    }
    // S2 = Rt + U Z0
    {
        s16x8 af = *(const s16x8*)&Ub[(wave * 16 + l16) * 32 + quad * 8];
        #pragma unroll
        for (int dt = 0; dt < 2; ++dt) {
            s16x8 bf_ = *(const s16x8*)&Z0T[(dt * 16 + l16) * 32 + quad * 8];
            f32x4 z = {};
            f32x4 acc = MFMA_BF16(af, bf_, z);
            #pragma unroll
            for (int r = 0; r < 4; ++r) {
                int j = wave * 16 + quad * 4 + r;
                int d = dt * 16 + l16;
                float s2 = acc[r] + bf2f(Rb[j * 32 + d]);
                S2[j * 32 + d] = f2bf(s2);
            }
        }
    }
    __syncthreads();

    // A1 = tril(QK^T), nA2 = -tril(Q S2^T)   (inclusive diag)
    {
        s16x8 qf = *(const s16x8*)&Qb[(wave * 16 + l16) * 32 + quad * 8];
        #pragma unroll
        for (int jt = 0; jt < 4; ++jt) {
            s16x8 kf = *(const s16x8*)&Kb[(jt * 16 + l16) * 32 + quad * 8];
            s16x8 sf = *(const s16x8*)&S2[(jt * 16 + l16) * 32 + quad * 8];
            f32x4 z = {};
            f32x4 a1 = MFMA_BF16(qf, kf, z);
            f32x4 a2 = MFMA_BF16(qf, sf, z);
            #pragma unroll
            for (int r = 0; r < 4; ++r) {
                int t = wave * 16 + quad * 4 + r;
                int j = jt * 16 + l16;
                bool keep = (j <= t);
                A1m[t * 64 + j]  = keep ? f2bf(a1[r]) : (unsigned short)0;
                nA2m[t * 64 + j] = keep ? f2bf(-a2[r]) : (unsigned short)0;
            }
        }
    }
    __syncthreads();

    // O = Q Z0^T + A1m V + nA2m W ; scale exp(g); store bf16
    {
        s16x8 qf = *(const s16x8*)&Qb[(wave * 16 + l16) * 32 + quad * 8];
        s16x8 p0 = *(const s16x8*)&A1m[(wave * 16 + l16) * 64 + quad * 8];
        s16x8 p1 = *(const s16x8*)&A1m[(wave * 16 + l16) * 64 + 32 + quad * 8];
        s16x8 m0 = *(const s16x8*)&nA2m[(wave * 16 + l16) * 64 + quad * 8];
        s16x8 m1 = *(const s16x8*)&nA2m[(wave * 16 + l16) * 64 + 32 + quad * 8];
        #pragma unroll
        for (int mt = 0; mt < 2; ++mt) {
            s16x8 zf = *(const s16x8*)&Z0b[(mt * 16 + l16) * 32 + quad * 8];
            s16x8 v0 = *(const s16x8*)&VT[(mt * 16 + l16) * 64 + quad * 8];
            s16x8 v1 = *(const s16x8*)&VT[(mt * 16 + l16) * 64 + 32 + quad * 8];
            s16x8 w0 = *(const s16x8*)&WT[(mt * 16 + l16) * 64 + quad * 8];
            s16x8 w1 = *(const s16x8*)&WT[(mt * 16 + l16) * 64 + 32 + quad * 8];
            f32x4 z = {};
            f32x4 acc = MFMA_BF16(qf, zf, z);
            acc = MFMA_BF16(p0, v0, acc);
            acc = MFMA_BF16(p1, v1, acc);
            acc = MFMA_BF16(m0, w0, acc);
            acc = MFMA_BF16(m1, w1, acc);
            #pragma unroll
            for (int r = 0; r < 4; ++r) {
                int t = wave * 16 + quad * 4 + r;
                int m = mt * 16 + l16;
                float e = expf(gc[t]);
                res_bf[(size_t)(row0 + t) * 256 + h * 32 + m] = f2bf(acc[r] * e);
            }
        }
    }
}

// ---------------------------------------------------------------------------
extern "C" void kernel_launch(void* const* d_in, const int* in_sizes, int n_in,
                              void* d_out, int out_size, void* d_ws, size_t ws_size,
                              hipStream_t stream)
{
    const float* x     = (const float*)d_in[0];
    const float* Wq    = (const float*)d_in[1];
    const float* Wk    = (const float*)d_in[2];
    const float* Wv    = (const float*)d_in[3];
    const float* Ww    = (const float*)d_in[4];
    const float* Wbeta = (const float*)d_in[5];
    const float* bbeta = (const float*)d_in[6];
    const float* Wg    = (const float*)d_in[7];
    const float* bg    = (const float*)d_in[8];
    const float* Wo    = (const float*)d_in[9];
    float* out = (float*)d_out;

    unsigned short* x_bf       = (unsigned short*)d_ws;           // 8,388,608
    unsigned short* stacked_bf = x_bf + (size_t)NROW * HID;       // 589,824
    unsigned short* Wo_bf      = stacked_bf + (size_t)NPAD * HID; // 131,072
    unsigned short* qb  = Wo_bf + (size_t)HID * 256;              // 4,194,304 each
    unsigned short* kb  = qb + (size_t)NROW * 256;
    unsigned short* vb  = kb + (size_t)NROW * 256;
    unsigned short* wbv = vb + (size_t)NROW * 256;
    unsigned short* ub  = wbv + (size_t)NROW * 256;
    unsigned short* rtb = ub + (size_t)NROW * 256;
    unsigned short* res_bf = rtb + (size_t)NROW * 256;
    float* betab = (float*)(res_bf + (size_t)NROW * 256);         // 131,072 f
    float* gb    = betab + (size_t)NROW * 8;
    float* D0buf = gb + (size_t)NROW * 8;                         // 2,097,152 f each
    float* Pbuf  = D0buf + (size_t)2048 * 1024;
    float* Z0buf = Pbuf + (size_t)2048 * 1024;

    // 1. casts + weight concat
    cast_bf16<<<(NROW * HID / 4 + 255) / 256, 256, 0, stream>>>(x, x_bf, NROW * HID / 4);
    cast_bf16<<<(HID * 256 / 4 + 255) / 256, 256, 0, stream>>>(Wo, Wo_bf, HID * 256 / 4);
    concat_w_bf<<<(NPAD * HID + 255) / 256, 256, 0, stream>>>(Wq, Wk, Wv, Ww, Wbeta, Wg, stacked_bf);

    // 2. projection GEMM -> head-major bf16 q/k/v/w + fp32 beta/g
    gemm_proj<<<dim3(NROW / 128, NPAD / 128), 256, 0, stream>>>(
        x_bf, stacked_bf, qb, kb, vb, wbv, betab, gb, bbeta, bg);

    // 3. chunked delta-rule precompute (MFMA)
    chunk_pre<<<2048, 256, 0, stream>>>(kb, vb, wbv, betab, ub, rtb, D0buf, Pbuf);

    // 4. chunk-state scan (register-P, prefetched, b128 LDS reads)
    scan_states<<<32, 256, 0, stream>>>(Pbuf, D0buf, Z0buf);

    // 5. Z-dependent output terms (MFMA, writes bf16 res)
    chunk_out<<<2048, 256, 0, stream>>>(qb, kb, vb, wbv, ub, rtb, Z0buf, gb, res_bf);

    // 6. output GEMM: out = res @ Wo^T
    gemm_out<<<dim3(NROW / 128, HID / 128), 256, 0, stream>>>(res_bf, Wo_bf, out);
}